// Round 4
// baseline (534.407 us; speedup 1.0000x reference)
//
#include <hip/hip_runtime.h>
#include <hip/hip_bf16.h>
#include <cstdint>
#include <cstddef>

#define N_TOK 50176      // B*H*W
#define HWSZ  3136       // 56*56
#define BATCH 16

#define GF_MUL     1
#define GF_ASCALE  2
#define GF_KVSPLIT 4

typedef __hip_bfloat16 bf16;
typedef __attribute__((ext_vector_type(8))) short bf16x8;
typedef __attribute__((ext_vector_type(4))) float f32x4;
typedef __attribute__((ext_vector_type(4))) unsigned short u16x4;

__device__ __forceinline__ void  stf(float* p, size_t i, float v) { p[i] = v; }
__device__ __forceinline__ void  stf(bf16* p, size_t i, float v) { p[i] = __float2bfloat16(v); }
__device__ __forceinline__ float bu2f(unsigned short u) {
    unsigned int x = ((unsigned int)u) << 16; float f; __builtin_memcpy(&f, &x, 4); return f;
}
__device__ __forceinline__ unsigned short f2bu(float f) {
    bf16 t = __float2bfloat16(f); unsigned short u; __builtin_memcpy(&u, &t, 2); return u;
}

// ---------------- batched weight prep: W[K][N] fp32 -> WT[N][K] bf16 (9 mats, 1 launch) ----------------
struct WtrDesc { const float* src; bf16* dst; int K; int N; int off; };
struct WtrPack { WtrDesc d[9]; int total; };
__global__ __launch_bounds__(256) void wtr_all(WtrPack p)
{
    int idx = blockIdx.x * 256 + threadIdx.x;
    if (idx >= p.total) return;
    #pragma unroll
    for (int s = 0; s < 9; s++) {
        int lo = p.d[s].off, hi = lo + p.d[s].K * p.d[s].N;
        if (idx >= lo && idx < hi) {
            int j = idx - lo;
            int k = j / p.d[s].N, n = j % p.d[s].N;
            p.d[s].dst[(size_t)n * p.d[s].K + k] = __float2bfloat16(p.d[s].src[j]);
        }
    }
}

// ---------------- LayerNorm: one wave per row (fp32 in -> bf16 out) ----------------
__global__ __launch_bounds__(256) void ln_kernel(const float* __restrict__ in,
    const float* __restrict__ w, const float* __restrict__ b,
    bf16* __restrict__ out, int rows, int Cdim)
{
    int wave = threadIdx.x >> 6, lane = threadIdx.x & 63;
    int row = blockIdx.x * 4 + wave;
    if (row >= rows) return;
    const float* p = in + (size_t)row * Cdim;
    int nj = Cdim >> 6;
    float v[4];
    float s = 0.f;
    for (int j = 0; j < nj; j++) { v[j] = p[lane + 64 * j]; s += v[j]; }
    for (int off = 32; off; off >>= 1) s += __shfl_xor(s, off, 64);
    float mean = s / (float)Cdim;
    float vs = 0.f;
    for (int j = 0; j < nj; j++) { float d = v[j] - mean; vs += d * d; }
    for (int off = 32; off; off >>= 1) vs += __shfl_xor(vs, off, 64);
    float rstd = 1.f / sqrtf(vs / (float)Cdim + 1e-6f);
    bf16* q = out + (size_t)row * Cdim;
    for (int j = 0; j < nj; j++) {
        int c = lane + 64 * j;
        q[c] = __float2bfloat16((v[j] - mean) * rstd * w[c] + b[c]);
    }
}

// ---------------- MFMA GEMM: C = A[M,K](bf16) @ WT[N,K]^T(bf16) + bias ----------------
// 128x128 tile, BK=32, 256 threads (4 waves 2x2), 16x16x32 MFMA, fp32 accum.
#define LDT 56   // padded LDS K-stride (112B: 16B-aligned, 2-way banks)
template<int FLAGS, typename OT>
__global__ __launch_bounds__(256) void gemm_mfma(
    const bf16* __restrict__ A, int lda,
    const bf16* __restrict__ WT,           // [N][K]
    const float* __restrict__ bias,
    OT* __restrict__ C, int ldc,
    int M, int K, int N,
    const bf16* __restrict__ mul, int mulld,
    const float* __restrict__ ascale,      // [BATCH][K]
    bf16* __restrict__ kout, bf16* __restrict__ vout)
{
    __shared__ bf16 As[128][LDT];
    __shared__ bf16 Bs[128][LDT];
    int ntile = N >> 7;
    int m0 = (blockIdx.x / ntile) * 128;
    int n0 = (blockIdx.x % ntile) * 128;
    int tid = threadIdx.x;
    int lane = tid & 63, wid = tid >> 6;
    int wr = (wid >> 1) * 64, wc = (wid & 1) * 64;
    int lrow = lane & 15, lko = (lane >> 4) * 8;

    f32x4 acc[4][4];
    #pragma unroll
    for (int i = 0; i < 4; i++)
        #pragma unroll
        for (int j = 0; j < 4; j++)
            acc[i][j] = (f32x4){0.f, 0.f, 0.f, 0.f};

    for (int k0 = 0; k0 < K; k0 += 32) {
        #pragma unroll
        for (int i = 0; i < 2; i++) {
            int idx = tid + i * 256;
            int r = idx >> 2, ko = (idx & 3) * 8;
            bf16x8 v = *reinterpret_cast<const bf16x8*>(A + (size_t)(m0 + r) * lda + k0 + ko);
            if (FLAGS & GF_ASCALE) {
                int bidx = (m0 + r) / HWSZ;
                const float* as = ascale + (size_t)bidx * K + k0 + ko;
                #pragma unroll
                for (int e = 0; e < 8; e++)
                    v[e] = (short)f2bu(bu2f((unsigned short)v[e]) * as[e]);
            }
            *reinterpret_cast<bf16x8*>(&As[r][ko]) = v;
            bf16x8 wv = *reinterpret_cast<const bf16x8*>(WT + (size_t)(n0 + r) * K + k0 + ko);
            *reinterpret_cast<bf16x8*>(&Bs[r][ko]) = wv;
        }
        __syncthreads();
        bf16x8 af[4], br[4];
        #pragma unroll
        for (int i = 0; i < 4; i++)
            af[i] = *reinterpret_cast<const bf16x8*>(&As[wr + i * 16 + lrow][lko]);
        #pragma unroll
        for (int j = 0; j < 4; j++)
            br[j] = *reinterpret_cast<const bf16x8*>(&Bs[wc + j * 16 + lrow][lko]);
        #pragma unroll
        for (int i = 0; i < 4; i++)
            #pragma unroll
            for (int j = 0; j < 4; j++)
                acc[i][j] = __builtin_amdgcn_mfma_f32_16x16x32_bf16(af[i], br[j], acc[i][j], 0, 0, 0);
        __syncthreads();
    }

    int orow = (lane >> 4) * 4;
    int ocol = lane & 15;
    #pragma unroll
    for (int i = 0; i < 4; i++) {
        #pragma unroll
        for (int j = 0; j < 4; j++) {
            #pragma unroll
            for (int p = 0; p < 4; p++) {
                int gm = m0 + wr + i * 16 + orow + p;
                int gn = n0 + wc + j * 16 + ocol;
                float v = acc[i][j][p] + bias[gn];
                if (FLAGS & GF_KVSPLIT) {
                    int bb = gm / HWSZ, n = gm % HWSZ;
                    if (gn < 128)
                        kout[(((size_t)bb * 8 + (gn >> 4)) * HWSZ + n) * 16 + (gn & 15)] = __float2bfloat16(v);
                    else {
                        int hh = (gn - 128) >> 4, dd = (gn - 128) & 15;
                        // V stored TRANSPOSED: [bh][d][pos]
                        vout[(((size_t)bb * 8 + hh) * 16 + dd) * HWSZ + n] = __float2bfloat16(v);
                    }
                } else {
                    if (FLAGS & GF_MUL) v *= __bfloat162float(mul[(size_t)gm * mulld + gn]);
                    stf(C, (size_t)gm * ldc + gn, v);
                }
            }
        }
    }
}

// ---------------- fp32 vector GEMM (small q projection only) ----------------
__global__ __launch_bounds__(256) void gemm_k(
    const float* __restrict__ A, int lda,
    const float* __restrict__ Wt, const float* __restrict__ bias,
    float* __restrict__ Cc, int ldc, int M, int K, int Nc)
{
    __shared__ float As[16][68];
    __shared__ float Ws[16][64];
    int ntile = Nc >> 6;
    int tile_n = blockIdx.x % ntile;
    int tile_m = blockIdx.x / ntile;
    int m0 = tile_m * 64, n0 = tile_n * 64;
    int tid = threadIdx.x;
    int tx = tid & 15, ty = tid >> 4;
    float acc[4][4] = {};
    for (int k0 = 0; k0 < K; k0 += 16) {
        int ks = tid & 15, ms = tid >> 4;
        #pragma unroll
        for (int i = 0; i < 4; i++) {
            int gm = m0 + ms + i * 16;
            As[ks][ms + i * 16] = (gm < M) ? A[(size_t)gm * lda + k0 + ks] : 0.f;
        }
        #pragma unroll
        for (int j = 0; j < 4; j++) {
            int k = (tid >> 6) * 4 + j;
            Ws[k][tid & 63] = Wt[(size_t)(k0 + k) * Nc + n0 + (tid & 63)];
        }
        __syncthreads();
        #pragma unroll
        for (int k = 0; k < 16; k++) {
            float a[4], w[4];
            #pragma unroll
            for (int i = 0; i < 4; i++) a[i] = As[k][ty * 4 + i];
            #pragma unroll
            for (int j = 0; j < 4; j++) w[j] = Ws[k][tx * 4 + j];
            #pragma unroll
            for (int i = 0; i < 4; i++)
                #pragma unroll
                for (int j = 0; j < 4; j++)
                    acc[i][j] += a[i] * w[j];
        }
        __syncthreads();
    }
    #pragma unroll
    for (int i = 0; i < 4; i++) {
        int gm = m0 + ty * 4 + i;
        if (gm >= M) continue;
        #pragma unroll
        for (int j = 0; j < 4; j++) {
            int gn = n0 + tx * 4 + j;
            Cc[(size_t)gm * ldc + gn] = acc[i][j] + bias[gn];
        }
    }
}

// ---------------- direct-global depthwise 7x7 conv with x-register reuse ----------------
// No LDS, no barrier. Thread: 4 consecutive x positions x 8 channels, one (b,y) row.
// Per ky: load 10 overlapping 16B cells once, convert to f32 once (80 cvt),
// feed all 7 kx taps x 4 outputs from registers (224 FMA).
// Wave: lanes 0-31 = all 32 ch-groups of one pos-group -> each cell load is one
// contiguous 512B wave-segment (perfectly coalesced); L1/L2 serve halo re-reads.
__global__ __launch_bounds__(256) void dwconv_reg(const bf16* __restrict__ in,
    bf16* __restrict__ out,
    const float* __restrict__ w0, const float* __restrict__ b0,
    const float* __restrict__ w1, const float* __restrict__ b1, int split)
{
    int tid = threadIdx.x;
    int chg = tid & 31;                      // 8-channel group
    int pg  = blockIdx.x * 8 + (tid >> 5);   // pos-group = 4 consecutive x
    int xg = pg % 14;
    int y  = (pg / 14) % 56;
    int b  = pg / (14 * 56);
    int c0 = chg * 8;
    int x0 = xg * 4;

    const float* wp; const float* bp; int ws, cw;
    if (c0 < split) { wp = w0; bp = b0; ws = split;       cw = c0; }
    else            { wp = w1; bp = b1; ws = 256 - split; cw = c0 - split; }

    float acc[4][8];
    #pragma unroll
    for (int o = 0; o < 4; o++)
        #pragma unroll
        for (int e = 0; e < 8; e++) acc[o][e] = 0.f;

    const bf16* base = in + (size_t)b * HWSZ * 256 + c0;
    const float* wbase = wp + cw;
    #pragma unroll
    for (int ky = 0; ky < 7; ky++) {
        int gy = y + ky - 3;
        if (gy < 0 || gy >= 56) continue;
        const bf16* rowp = base + (size_t)gy * 56 * 256;
        float cf[10][8];
        #pragma unroll
        for (int j = 0; j < 10; j++) {
            int gx = x0 + j - 3;
            bf16x8 v = {0, 0, 0, 0, 0, 0, 0, 0};
            if ((unsigned)gx < 56u)
                v = *reinterpret_cast<const bf16x8*>(rowp + (size_t)gx * 256);
            #pragma unroll
            for (int e = 0; e < 8; e++) cf[j][e] = bu2f((unsigned short)v[e]);
        }
        const float* wrow = wbase + ky * 7 * ws;
        #pragma unroll
        for (int kx = 0; kx < 7; kx++) {
            float4 wa = *reinterpret_cast<const float4*>(wrow + kx * ws);
            float4 wb = *reinterpret_cast<const float4*>(wrow + kx * ws + 4);
            #pragma unroll
            for (int o = 0; o < 4; o++) {
                acc[o][0] += cf[o + kx][0] * wa.x;
                acc[o][1] += cf[o + kx][1] * wa.y;
                acc[o][2] += cf[o + kx][2] * wa.z;
                acc[o][3] += cf[o + kx][3] * wa.w;
                acc[o][4] += cf[o + kx][4] * wb.x;
                acc[o][5] += cf[o + kx][5] * wb.y;
                acc[o][6] += cf[o + kx][6] * wb.z;
                acc[o][7] += cf[o + kx][7] * wb.w;
            }
        }
    }

    float4 ba = *reinterpret_cast<const float4*>(bp + cw);
    float4 bb = *reinterpret_cast<const float4*>(bp + cw + 4);
    bf16* obase = out + (((size_t)b * HWSZ + (size_t)y * 56 + x0) * 256) + c0;
    #pragma unroll
    for (int o = 0; o < 4; o++) {
        bf16x8 ov;
        ov[0] = (short)f2bu(acc[o][0] + ba.x);
        ov[1] = (short)f2bu(acc[o][1] + ba.y);
        ov[2] = (short)f2bu(acc[o][2] + ba.z);
        ov[3] = (short)f2bu(acc[o][3] + ba.w);
        ov[4] = (short)f2bu(acc[o][4] + bb.x);
        ov[5] = (short)f2bu(acc[o][5] + bb.y);
        ov[6] = (short)f2bu(acc[o][6] + bb.z);
        ov[7] = (short)f2bu(acc[o][7] + bb.w);
        *reinterpret_cast<bf16x8*>(obase + (size_t)o * 256) = ov;
    }
}

// ---------------- rgb/t elementwise -> codin[N,256] ----------------
__global__ void rgbt_k(const bf16* __restrict__ rgb, const bf16* __restrict__ t,
                       bf16* __restrict__ codin, int total /* N*128 */)
{
    int i = blockIdx.x * blockDim.x + threadIdx.x;
    if (i >= total) return;
    int n = i >> 7, c = i & 127;
    float a = __bfloat162float(rgb[i]), bb = __bfloat162float(t[i]);
    codin[(size_t)n * 256 + c] = __float2bfloat16(a * bb);
    codin[(size_t)n * 256 + 128 + c] = __float2bfloat16(fabsf(a - bb));
}

// ---------------- cosine-gate partial reductions ----------------
__global__ __launch_bounds__(256) void cosred_k(const bf16* __restrict__ codi,
    float* __restrict__ part)   // [B][64][513]
{
    int b = blockIdx.x >> 4;
    int bi = blockIdx.x & 15;
    int wave = threadIdx.x >> 6, lane = threadIdx.x & 63;
    int slot = bi * 4 + wave;
    float dloc[4] = {0,0,0,0}, n2loc[4] = {0,0,0,0};
    float n1loc = 0.f;
    for (int i = 0; i < 49; i++) {
        int p = slot * 49 + i;
        const bf16* row = codi + ((size_t)b * HWSZ + p) * 256;
        float v[4]; float sum = 0.f;
        #pragma unroll
        for (int j = 0; j < 4; j++) { v[j] = __bfloat162float(row[lane + 64 * j]); sum += v[j]; }
        for (int off = 32; off; off >>= 1) sum += __shfl_xor(sum, off, 64);
        float amap = sum * (1.f / 256.f);
        #pragma unroll
        for (int j = 0; j < 4; j++) { dloc[j] += amap * v[j]; n2loc[j] += v[j] * v[j]; }
        n1loc += amap * amap;
    }
    float* dst = part + ((size_t)b * 64 + slot) * 513;
    #pragma unroll
    for (int j = 0; j < 4; j++) {
        dst[lane + 64 * j] = dloc[j];
        dst[256 + lane + 64 * j] = n2loc[j];
    }
    if (lane == 0) dst[512] = n1loc;
}

// ---------------- cos_sim + MLP + sigmoid -> attn_c[B,256] fp32 ----------------
__global__ __launch_bounds__(256) void mlp_kernel(const float* __restrict__ part,
    const float* __restrict__ fc1w, const float* __restrict__ fc2w,
    float* __restrict__ attnc)
{
    int b = blockIdx.x;
    int tid = threadIdx.x;
    __shared__ float cosb[256];
    __shared__ float hbuf[32];
    const float* pb = part + (size_t)b * 64 * 513;
    float dot = 0.f, n2 = 0.f, n1 = 0.f;
    for (int s = 0; s < 64; s++) {
        dot += pb[s * 513 + tid];
        n2  += pb[s * 513 + 256 + tid];
        n1  += pb[s * 513 + 512];
    }
    float cs = dot / (sqrtf(n1) * sqrtf(n2) + 1e-6f);
    cosb[tid] = cs;
    __syncthreads();
    if (tid < 32) {
        float h = 0.f;
        for (int c = 0; c < 256; c++) h += cosb[c] * fc1w[c * 32 + tid];
        h = 0.5f * h * (1.f + erff(h * 0.70710678f));
        hbuf[tid] = h;
    }
    __syncthreads();
    float o = 0.f;
    for (int j = 0; j < 32; j++) o += hbuf[j] * fc2w[j * 256 + tid];
    attnc[b * 256 + tid] = 1.f / (1.f + expf(-o));
}

// ---------------- 8x8 mean-pool of concat(xn, xen) -> rx_pool[B,49,384] fp32 ----------------
__global__ __launch_bounds__(384) void pool_kernel(const bf16* __restrict__ xn,
    const bf16* __restrict__ xen, float* __restrict__ rxpool)
{
    int bij = blockIdx.x;
    int b = bij / 49; int ij = bij % 49; int i = ij / 7, j = ij % 7;
    int c = threadIdx.x;
    float s = 0.f;
    for (int dy = 0; dy < 8; dy++)
        for (int dx = 0; dx < 8; dx++) {
            size_t n = ((size_t)b * 56 + (i * 8 + dy)) * 56 + (j * 8 + dx);
            s += (c < 256) ? __bfloat162float(xn[n * 256 + c])
                           : __bfloat162float(xen[n * 128 + (c - 256)]);
        }
    rxpool[(size_t)bij * 384 + c] = s * (1.f / 64.f);
}

// ---------------- MFMA flash attention over pooled q ----------------
#define NSPLIT 14
#define POSB   224   // 3136/14, multiple of 32
__global__ __launch_bounds__(256) void attn_mfma(const float* __restrict__ qbuf,
    const bf16* __restrict__ kbuf, const bf16* __restrict__ vtbuf,
    float* __restrict__ osplit, float* __restrict__ mlbuf)
{
    int bh = blockIdx.x & 127;
    int split = blockIdx.x >> 7;
    int b = bh >> 3, h = bh & 7;
    int tid = threadIdx.x;
    int qt = tid >> 6;
    int lane = tid & 63;
    int lo = lane & 15, hi = lane >> 4;

    bf16x8 qf = {0, 0, 0, 0, 0, 0, 0, 0};
    int q = qt * 16 + lo;
    if (hi < 2 && q < 49) {
        const float* qp = qbuf + ((size_t)b * 49 + q) * 128 + h * 16 + hi * 8;
        #pragma unroll
        for (int j = 0; j < 8; j++) qf[j] = (short)f2bu(qp[j] * 0.25f);
    }
    const bf16* kbase = kbuf + (size_t)bh * HWSZ * 16;
    const bf16* vbase = vtbuf + ((size_t)bh * 16 + lo) * HWSZ;

    float m_run = -1e30f, l_run = 0.f;
    f32x4 oacc = {0.f, 0.f, 0.f, 0.f};
    int pos1 = 8 * (lo >> 2) + (lo & 3);
    const f32x4 zz = {0.f, 0.f, 0.f, 0.f};

    for (int t = 0; t < POSB / 32; t++) {
        int base = split * POSB + t * 32;
        bf16x8 kf1 = {0, 0, 0, 0, 0, 0, 0, 0}, kf2 = kf1;
        if (hi < 2) {
            kf1 = *reinterpret_cast<const bf16x8*>(kbase + (size_t)(base + pos1) * 16 + hi * 8);
            kf2 = *reinterpret_cast<const bf16x8*>(kbase + (size_t)(base + pos1 + 4) * 16 + hi * 8);
        }
        bf16x8 vf = *reinterpret_cast<const bf16x8*>(vbase + base + hi * 8);
        f32x4 s1 = __builtin_amdgcn_mfma_f32_16x16x32_bf16(kf1, qf, zz, 0, 0, 0);
        f32x4 s2 = __builtin_amdgcn_mfma_f32_16x16x32_bf16(kf2, qf, zz, 0, 0, 0);
        float pmax = fmaxf(fmaxf(fmaxf(s1[0], s1[1]), fmaxf(s1[2], s1[3])),
                           fmaxf(fmaxf(s2[0], s2[1]), fmaxf(s2[2], s2[3])));
        pmax = fmaxf(pmax, __shfl_xor(pmax, 16, 64));
        pmax = fmaxf(pmax, __shfl_xor(pmax, 32, 64));
        float mnew = fmaxf(m_run, pmax);
        float esc = __expf(m_run - mnew);
        l_run *= esc;
        float e0 = __shfl(esc, 4 * hi + 0, 64);
        float e1 = __shfl(esc, 4 * hi + 1, 64);
        float e2 = __shfl(esc, 4 * hi + 2, 64);
        float e3 = __shfl(esc, 4 * hi + 3, 64);
        oacc[0] *= e0; oacc[1] *= e1; oacc[2] *= e2; oacc[3] *= e3;
        float p0 = __expf(s1[0] - mnew), p1 = __expf(s1[1] - mnew);
        float p2 = __expf(s1[2] - mnew), p3 = __expf(s1[3] - mnew);
        float p4 = __expf(s2[0] - mnew), p5 = __expf(s2[1] - mnew);
        float p6 = __expf(s2[2] - mnew), p7 = __expf(s2[3] - mnew);
        float rs = ((p0 + p1) + (p2 + p3)) + ((p4 + p5) + (p6 + p7));
        rs += __shfl_xor(rs, 16, 64);
        rs += __shfl_xor(rs, 32, 64);
        l_run += rs;
        m_run = mnew;
        bf16x8 pf;
        pf[0] = (short)f2bu(p0); pf[1] = (short)f2bu(p1);
        pf[2] = (short)f2bu(p2); pf[3] = (short)f2bu(p3);
        pf[4] = (short)f2bu(p4); pf[5] = (short)f2bu(p5);
        pf[6] = (short)f2bu(p6); pf[7] = (short)f2bu(p7);
        oacc = __builtin_amdgcn_mfma_f32_16x16x32_bf16(pf, vf, oacc, 0, 0, 0);
    }

    float* ob = osplit + ((size_t)bh * NSPLIT + split) * 64 * 16;
    #pragma unroll
    for (int r = 0; r < 4; r++) {
        int qq = qt * 16 + 4 * hi + r;
        ob[(size_t)qq * 16 + lo] = oacc[r];
    }
    if (hi == 0) {
        float* mlb = mlbuf + (((size_t)bh * NSPLIT + split) * 64 + qt * 16 + lo) * 2;
        mlb[0] = m_run; mlb[1] = l_run;
    }
}

// ---------------- merge split partials -> gs[bh][49][16] ----------------
__global__ __launch_bounds__(256) void attn_combine(const float* __restrict__ osplit,
    const float* __restrict__ mlbuf, float* __restrict__ gs)
{
    int idx = blockIdx.x * 256 + threadIdx.x;   // over 128*49*16
    if (idx >= 128 * 49 * 16) return;
    int d = idx & 15;
    int pq = idx >> 4;
    int bh = pq / 49, q = pq % 49;
    float m[NSPLIT], l[NSPLIT];
    float M = -1e30f;
    #pragma unroll
    for (int s = 0; s < NSPLIT; s++) {
        const float* mlb = mlbuf + (((size_t)bh * NSPLIT + s) * 64 + q) * 2;
        m[s] = mlb[0]; l[s] = mlb[1];
        M = fmaxf(M, m[s]);
    }
    float L = 0.f, O = 0.f;
    #pragma unroll
    for (int s = 0; s < NSPLIT; s++) {
        float e = __expf(m[s] - M);
        L += l[s] * e;
        O += osplit[(((size_t)bh * NSPLIT + s) * 64 + q) * 16 + d] * e;
    }
    gs[(size_t)pq * 16 + d] = O / L;
}

// ---------------- bilinear 7->56 upsample into cat[:, 384:512] ----------------
__global__ void upsample_kernel(const float* __restrict__ gs, bf16* __restrict__ cat)
{
    int idx = blockIdx.x * blockDim.x + threadIdx.x;  // over N*128
    if (idx >= N_TOK * 128) return;
    int c = idx & 127;
    int pos = idx >> 7;
    int h = c >> 4, d = c & 15;
    int x = pos % 56;
    int y = (pos / 56) % 56;
    int b = pos / HWSZ;
    float sy = (y + 0.5f) * 0.125f - 0.5f;
    float sx = (x + 0.5f) * 0.125f - 0.5f;
    int y0f = (int)floorf(sy); float wy = sy - (float)y0f;
    int x0f = (int)floorf(sx); float wx = sx - (float)x0f;
    int y0 = max(0, min(6, y0f)), y1 = max(0, min(6, y0f + 1));
    int x0 = max(0, min(6, x0f)), x1 = max(0, min(6, x0f + 1));
    const float* g0 = gs + ((size_t)(b * 8 + h) * 49) * 16 + d;
    float v00 = g0[(y0 * 7 + x0) * 16], v01 = g0[(y0 * 7 + x1) * 16];
    float v10 = g0[(y1 * 7 + x0) * 16], v11 = g0[(y1 * 7 + x1) * 16];
    float v0 = v00 + (v01 - v00) * wx;
    float v1 = v10 + (v11 - v10) * wx;
    float v = v0 + (v1 - v0) * wy;
    cat[(size_t)pos * 512 + 384 + c] = __float2bfloat16(v);
}

extern "C" void kernel_launch(void* const* d_in, const int* in_sizes, int n_in,
                              void* d_out, int out_size, void* d_ws, size_t ws_size,
                              hipStream_t stream)
{
    const float* x      = (const float*)d_in[0];
    const float* x_e    = (const float*)d_in[1];
    const float* norm_w = (const float*)d_in[2];
    const float* norm_b = (const float*)d_in[3];
    const float* norme_w= (const float*)d_in[4];
    const float* norme_b= (const float*)d_in[5];
    const float* rr1_w  = (const float*)d_in[6];
    const float* rr1_b  = (const float*)d_in[7];
    const float* rr2_w  = (const float*)d_in[8];
    const float* rr2_b  = (const float*)d_in[9];
    const float* rr3_w  = (const float*)d_in[10];
    const float* rr3_b  = (const float*)d_in[11];
    const float* conv_w = (const float*)d_in[12];
    const float* conv_b = (const float*)d_in[13];
    const float* l1_w   = (const float*)d_in[14];
    const float* l1_b   = (const float*)d_in[15];
    const float* l2_w   = (const float*)d_in[16];
    const float* l2_b   = (const float*)d_in[17];
    const float* c1_w   = (const float*)d_in[18];
    const float* c1_b   = (const float*)d_in[19];
    const float* c2_w   = (const float*)d_in[20];
    const float* c2_b   = (const float*)d_in[21];
    const float* fc1_w  = (const float*)d_in[22];
    const float* fc2_w  = (const float*)d_in[23];
    const float* l3_w   = (const float*)d_in[24];
    const float* l3_b   = (const float*)d_in[25];
    const float* kv_w   = (const float*)d_in[26];
    const float* kv_b   = (const float*)d_in[27];
    const float* q_w    = (const float*)d_in[28];
    const float* q_b    = (const float*)d_in[29];
    const float* proj_w = (const float*)d_in[30];
    const float* proj_b = (const float*)d_in[31];
    const float* proje_w= (const float*)d_in[32];
    const float* proje_b= (const float*)d_in[33];

    // ---- workspace: fp32 smalls, bf16 transposed weights, bf16 slabs ----
    float* part   = (float*)d_ws;                 // 16*64*513
    float* attnc  = part   + (size_t)525312;      // 16*256
    float* gs     = attnc  + 4096;                // 16*8*49*16
    float* rxpool = gs     + 100352;              // 784*384
    float* qbuf   = rxpool + 301056;              // 784*128
    bf16* wt      = (bf16*)(qbuf + 100352);
    bf16* rr1_t  = wt;              // 256x256
    bf16* rr2_t  = rr1_t + 65536;
    bf16* rr3_t  = rr2_t + 65536;
    bf16* kv_t   = rr3_t + 65536;
    bf16* l1_t   = kv_t  + 65536;   // 128x256
    bf16* l2_t   = l1_t  + 32768;   // 128x128
    bf16* l3_t   = l2_t  + 16384;   // 128x256
    bf16* proj_t = l3_t  + 32768;   // 256x512
    bf16* proje_t= proj_t + 131072; // 128x512
    bf16* xn     = proje_t + 65536;
    bf16* xen    = xn   + (size_t)N_TOK * 256;
    bf16* bufC   = xen  + (size_t)N_TOK * 128;   // rr1 / codin / K|V head-major
    bf16* bufD   = bufC + (size_t)N_TOK * 256;   // rr2pre / rgb|t / attn partials
    bf16* bufE   = bufD + (size_t)N_TOK * 256;   // conv out / co_di
    bf16* cat    = bufE + (size_t)N_TOK * 256;   // [N,512]
    size_t need = (size_t)((char*)(cat + (size_t)N_TOK * 512) - (char*)d_ws);
    if (ws_size < need) return;

    bf16* kbuf = bufC;                       // [B*8][HWSZ][16]
    bf16* vbuf = bufC + (size_t)N_TOK * 128; // [B*8][16][HWSZ] (transposed)

    // attn split partials live in bufD (free during phase 4): 8.26 MB
    float* osplit = (float*)bufD;                          // [128][NSPLIT][64][16]
    float* mlbuf  = osplit + (size_t)128 * NSPLIT * 64 * 16; // [128][NSPLIT][64][2]

    float* xout  = (float*)d_out;
    float* xeout = xout + (size_t)N_TOK * 256;

    const int nthr = 256;
    auto mgrid = [](int M, int N) { return dim3((M / 128) * (N / 128)); };

    // 0. weight prep (one launch)
    {
        WtrPack p;
        const float* srcs[9] = {rr1_w, rr2_w, rr3_w, kv_w, l1_w, l2_w, l3_w, proj_w, proje_w};
        bf16* dsts[9] = {rr1_t, rr2_t, rr3_t, kv_t, l1_t, l2_t, l3_t, proj_t, proje_t};
        int Ks[9] = {256, 256, 256, 256, 256, 128, 256, 512, 512};
        int Ns[9] = {256, 256, 256, 256, 128, 128, 128, 256, 128};
        int off = 0;
        for (int s = 0; s < 9; s++) {
            p.d[s] = {srcs[s], dsts[s], Ks[s], Ns[s], off};
            off += Ks[s] * Ns[s];
        }
        p.total = off;
        wtr_all<<<dim3((off + 255) / 256), dim3(256), 0, stream>>>(p);
    }

    // 1. LayerNorms
    ln_kernel<<<dim3(N_TOK / 4), dim3(nthr), 0, stream>>>(x, norm_w, norm_b, xn, N_TOK, 256);
    ln_kernel<<<dim3(N_TOK / 4), dim3(nthr), 0, stream>>>(x_e, norme_w, norme_b, xen, N_TOK, 128);

    // 2. local_rr -> cat[:, 0:256]
    gemm_mfma<0, bf16><<<mgrid(N_TOK, 256), dim3(nthr), 0, stream>>>(
        xn, 256, rr1_t, rr1_b, bufC, 256, N_TOK, 256, 256, nullptr, 0, nullptr, nullptr, nullptr);
    gemm_mfma<0, bf16><<<mgrid(N_TOK, 256), dim3(nthr), 0, stream>>>(
        xn, 256, rr2_t, rr2_b, bufD, 256, N_TOK, 256, 256, nullptr, 0, nullptr, nullptr, nullptr);
    dwconv_reg<<<dim3(N_TOK / 32), dim3(nthr), 0, stream>>>(
        bufD, bufE, conv_w, conv_b, conv_w, conv_b, 256);
    gemm_mfma<GF_MUL, bf16><<<mgrid(N_TOK, 256), dim3(nthr), 0, stream>>>(
        bufE, 256, rr3_t, rr3_b, cat, 512, N_TOK, 256, 256, bufC, 256, nullptr, nullptr, nullptr);

    // 3. LocalAttentionRGBT -> cat[:, 256:384]
    gemm_mfma<0, bf16><<<mgrid(N_TOK, 128), dim3(nthr), 0, stream>>>(
        xn, 256, l1_t, l1_b, bufD, 128, N_TOK, 256, 128, nullptr, 0, nullptr, nullptr, nullptr);
    gemm_mfma<0, bf16><<<mgrid(N_TOK, 128), dim3(nthr), 0, stream>>>(
        xen, 128, l2_t, l2_b, bufD + (size_t)N_TOK * 128, 128, N_TOK, 128, 128, nullptr, 0, nullptr, nullptr, nullptr);
    rgbt_k<<<dim3((N_TOK * 128) / nthr), dim3(nthr), 0, stream>>>(
        bufD, bufD + (size_t)N_TOK * 128, bufC, N_TOK * 128);
    dwconv_reg<<<dim3(N_TOK / 32), dim3(nthr), 0, stream>>>(
        bufC, bufE, c1_w, c1_b, c2_w, c2_b, 128);
    cosred_k<<<dim3(BATCH * 16), dim3(nthr), 0, stream>>>(bufE, part);
    mlp_kernel<<<dim3(BATCH), dim3(nthr), 0, stream>>>(part, fc1_w, fc2_w, attnc);
    gemm_mfma<GF_ASCALE, bf16><<<mgrid(N_TOK, 128), dim3(nthr), 0, stream>>>(
        bufE, 256, l3_t, l3_b, cat + 256, 512, N_TOK, 256, 128, nullptr, 0, attnc, nullptr, nullptr);

    // 4. global pooled attention -> cat[:, 384:512]
    gemm_mfma<GF_KVSPLIT, bf16><<<mgrid(N_TOK, 256), dim3(nthr), 0, stream>>>(
        xn, 256, kv_t, kv_b, (bf16*)nullptr, 0, N_TOK, 256, 256, nullptr, 0, nullptr, kbuf, vbuf);
    pool_kernel<<<dim3(BATCH * 49), dim3(384), 0, stream>>>(xn, xen, rxpool);
    gemm_k<<<dim3(((784 + 63) / 64) * 2), dim3(nthr), 0, stream>>>(
        rxpool, 384, q_w, q_b, qbuf, 128, 784, 384, 128);
    attn_mfma<<<dim3(128 * NSPLIT), dim3(nthr), 0, stream>>>(qbuf, kbuf, vbuf, osplit, mlbuf);
    attn_combine<<<dim3(392), dim3(nthr), 0, stream>>>(osplit, mlbuf, gs);
    upsample_kernel<<<dim3((N_TOK * 128) / nthr), dim3(nthr), 0, stream>>>(gs, cat);

    // 5. output projections (fp32 out)
    gemm_mfma<0, float><<<mgrid(N_TOK, 256), dim3(nthr), 0, stream>>>(
        cat, 512, proj_t, proj_b, xout, 256, N_TOK, 512, 256, nullptr, 0, nullptr, nullptr, nullptr);
    gemm_mfma<0, float><<<mgrid(N_TOK, 128), dim3(nthr), 0, stream>>>(
        cat, 512, proje_t, proje_b, xeout, 128, N_TOK, 512, 128, nullptr, 0, nullptr, nullptr, nullptr);
}

// Round 6
// 478.279 us; speedup vs baseline: 1.1174x; 1.1174x over previous
//
#include <hip/hip_runtime.h>
#include <hip/hip_bf16.h>
#include <cstdint>
#include <cstddef>

#define N_TOK 50176      // B*H*W
#define HWSZ  3136       // 56*56
#define BATCH 16

#define GF_MUL     1
#define GF_ASCALE  2
#define GF_KVSPLIT 4

typedef __hip_bfloat16 bf16;
typedef __attribute__((ext_vector_type(8))) short bf16x8;
typedef __attribute__((ext_vector_type(4))) float f32x4;
typedef __attribute__((ext_vector_type(4))) unsigned short u16x4;

__device__ __forceinline__ void  stf(float* p, size_t i, float v) { p[i] = v; }
__device__ __forceinline__ void  stf(bf16* p, size_t i, float v) { p[i] = __float2bfloat16(v); }
__device__ __forceinline__ float bu2f(unsigned short u) {
    unsigned int x = ((unsigned int)u) << 16; float f; __builtin_memcpy(&f, &x, 4); return f;
}
__device__ __forceinline__ unsigned short f2bu(float f) {
    bf16 t = __float2bfloat16(f); unsigned short u; __builtin_memcpy(&u, &t, 2); return u;
}

// ---------------- batched weight prep: W[K][N] fp32 -> WT[N][K] bf16 (9 mats, 1 launch) ----------------
struct WtrDesc { const float* src; bf16* dst; int K; int N; int off; };
struct WtrPack { WtrDesc d[9]; int total; };
__global__ __launch_bounds__(256) void wtr_all(WtrPack p)
{
    int idx = blockIdx.x * 256 + threadIdx.x;
    if (idx >= p.total) return;
    #pragma unroll
    for (int s = 0; s < 9; s++) {
        int lo = p.d[s].off, hi = lo + p.d[s].K * p.d[s].N;
        if (idx >= lo && idx < hi) {
            int j = idx - lo;
            int k = j / p.d[s].N, n = j % p.d[s].N;
            p.d[s].dst[(size_t)n * p.d[s].K + k] = __float2bfloat16(p.d[s].src[j]);
        }
    }
}

// ---------------- LayerNorm: one wave per row (fp32 in -> bf16 out) ----------------
__global__ __launch_bounds__(256) void ln_kernel(const float* __restrict__ in,
    const float* __restrict__ w, const float* __restrict__ b,
    bf16* __restrict__ out, int rows, int Cdim)
{
    int wave = threadIdx.x >> 6, lane = threadIdx.x & 63;
    int row = blockIdx.x * 4 + wave;
    if (row >= rows) return;
    const float* p = in + (size_t)row * Cdim;
    int nj = Cdim >> 6;
    float v[4];
    float s = 0.f;
    for (int j = 0; j < nj; j++) { v[j] = p[lane + 64 * j]; s += v[j]; }
    for (int off = 32; off; off >>= 1) s += __shfl_xor(s, off, 64);
    float mean = s / (float)Cdim;
    float vs = 0.f;
    for (int j = 0; j < nj; j++) { float d = v[j] - mean; vs += d * d; }
    for (int off = 32; off; off >>= 1) vs += __shfl_xor(vs, off, 64);
    float rstd = 1.f / sqrtf(vs / (float)Cdim + 1e-6f);
    bf16* q = out + (size_t)row * Cdim;
    for (int j = 0; j < nj; j++) {
        int c = lane + 64 * j;
        q[c] = __float2bfloat16((v[j] - mean) * rstd * w[c] + b[c]);
    }
}

// ---------------- MFMA GEMM: C = A[M,K](bf16) @ WT[N,K]^T(bf16) + bias ----------------
// 128x128 tile, BK=32, 256 threads (4 waves 2x2), 16x16x32 MFMA, fp32 accum.
#define LDT 56   // padded LDS K-stride (112B: 16B-aligned, 2-way banks)
template<int FLAGS, typename OT>
__global__ __launch_bounds__(256) void gemm_mfma(
    const bf16* __restrict__ A, int lda,
    const bf16* __restrict__ WT,           // [N][K]
    const float* __restrict__ bias,
    OT* __restrict__ C, int ldc,
    int M, int K, int N,
    const bf16* __restrict__ mul, int mulld,
    const float* __restrict__ ascale,      // [BATCH][K]
    bf16* __restrict__ kout, bf16* __restrict__ vout)
{
    __shared__ bf16 As[128][LDT];
    __shared__ bf16 Bs[128][LDT];
    int ntile = N >> 7;
    int m0 = (blockIdx.x / ntile) * 128;
    int n0 = (blockIdx.x % ntile) * 128;
    int tid = threadIdx.x;
    int lane = tid & 63, wid = tid >> 6;
    int wr = (wid >> 1) * 64, wc = (wid & 1) * 64;
    int lrow = lane & 15, lko = (lane >> 4) * 8;

    f32x4 acc[4][4];
    #pragma unroll
    for (int i = 0; i < 4; i++)
        #pragma unroll
        for (int j = 0; j < 4; j++)
            acc[i][j] = (f32x4){0.f, 0.f, 0.f, 0.f};

    for (int k0 = 0; k0 < K; k0 += 32) {
        #pragma unroll
        for (int i = 0; i < 2; i++) {
            int idx = tid + i * 256;
            int r = idx >> 2, ko = (idx & 3) * 8;
            bf16x8 v = *reinterpret_cast<const bf16x8*>(A + (size_t)(m0 + r) * lda + k0 + ko);
            if (FLAGS & GF_ASCALE) {
                int bidx = (m0 + r) / HWSZ;
                const float* as = ascale + (size_t)bidx * K + k0 + ko;
                #pragma unroll
                for (int e = 0; e < 8; e++)
                    v[e] = (short)f2bu(bu2f((unsigned short)v[e]) * as[e]);
            }
            *reinterpret_cast<bf16x8*>(&As[r][ko]) = v;
            bf16x8 wv = *reinterpret_cast<const bf16x8*>(WT + (size_t)(n0 + r) * K + k0 + ko);
            *reinterpret_cast<bf16x8*>(&Bs[r][ko]) = wv;
        }
        __syncthreads();
        bf16x8 af[4], br[4];
        #pragma unroll
        for (int i = 0; i < 4; i++)
            af[i] = *reinterpret_cast<const bf16x8*>(&As[wr + i * 16 + lrow][lko]);
        #pragma unroll
        for (int j = 0; j < 4; j++)
            br[j] = *reinterpret_cast<const bf16x8*>(&Bs[wc + j * 16 + lrow][lko]);
        #pragma unroll
        for (int i = 0; i < 4; i++)
            #pragma unroll
            for (int j = 0; j < 4; j++)
                acc[i][j] = __builtin_amdgcn_mfma_f32_16x16x32_bf16(af[i], br[j], acc[i][j], 0, 0, 0);
        __syncthreads();
    }

    int orow = (lane >> 4) * 4;
    int ocol = lane & 15;
    #pragma unroll
    for (int i = 0; i < 4; i++) {
        #pragma unroll
        for (int j = 0; j < 4; j++) {
            #pragma unroll
            for (int p = 0; p < 4; p++) {
                int gm = m0 + wr + i * 16 + orow + p;
                int gn = n0 + wc + j * 16 + ocol;
                float v = acc[i][j][p] + bias[gn];
                if (FLAGS & GF_KVSPLIT) {
                    int bb = gm / HWSZ, n = gm % HWSZ;
                    if (gn < 128)
                        kout[(((size_t)bb * 8 + (gn >> 4)) * HWSZ + n) * 16 + (gn & 15)] = __float2bfloat16(v);
                    else {
                        int hh = (gn - 128) >> 4, dd = (gn - 128) & 15;
                        // V stored TRANSPOSED: [bh][d][pos]
                        vout[(((size_t)bb * 8 + hh) * 16 + dd) * HWSZ + n] = __float2bfloat16(v);
                    }
                } else {
                    if (FLAGS & GF_MUL) v *= __bfloat162float(mul[(size_t)gm * mulld + gn]);
                    stf(C, (size_t)gm * ldc + gn, v);
                }
            }
        }
    }
}

// ---------------- fp32 vector GEMM (small q projection only) ----------------
__global__ __launch_bounds__(256) void gemm_k(
    const float* __restrict__ A, int lda,
    const float* __restrict__ Wt, const float* __restrict__ bias,
    float* __restrict__ Cc, int ldc, int M, int K, int Nc)
{
    __shared__ float As[16][68];
    __shared__ float Ws[16][64];
    int ntile = Nc >> 6;
    int tile_n = blockIdx.x % ntile;
    int tile_m = blockIdx.x / ntile;
    int m0 = tile_m * 64, n0 = tile_n * 64;
    int tid = threadIdx.x;
    int tx = tid & 15, ty = tid >> 4;
    float acc[4][4] = {};
    for (int k0 = 0; k0 < K; k0 += 16) {
        int ks = tid & 15, ms = tid >> 4;
        #pragma unroll
        for (int i = 0; i < 4; i++) {
            int gm = m0 + ms + i * 16;
            As[ks][ms + i * 16] = (gm < M) ? A[(size_t)gm * lda + k0 + ks] : 0.f;
        }
        #pragma unroll
        for (int j = 0; j < 4; j++) {
            int k = (tid >> 6) * 4 + j;
            Ws[k][tid & 63] = Wt[(size_t)(k0 + k) * Nc + n0 + (tid & 63)];
        }
        __syncthreads();
        #pragma unroll
        for (int k = 0; k < 16; k++) {
            float a[4], w[4];
            #pragma unroll
            for (int i = 0; i < 4; i++) a[i] = As[k][ty * 4 + i];
            #pragma unroll
            for (int j = 0; j < 4; j++) w[j] = Ws[k][tx * 4 + j];
            #pragma unroll
            for (int i = 0; i < 4; i++)
                #pragma unroll
                for (int j = 0; j < 4; j++)
                    acc[i][j] += a[i] * w[j];
        }
        __syncthreads();
    }
    #pragma unroll
    for (int i = 0; i < 4; i++) {
        int gm = m0 + ty * 4 + i;
        if (gm >= M) continue;
        #pragma unroll
        for (int j = 0; j < 4; j++) {
            int gn = n0 + tx * 4 + j;
            Cc[(size_t)gm * ldc + gn] = acc[i][j] + bias[gn];
        }
    }
}

// ---------------- direct-global depthwise 7x7 conv with x-register reuse ----------------
// Round-4 body (known-good) + XCD-aware block swizzle ONLY.
// Thread: 4 consecutive x positions x 8 channels, one (b,y) row.
// Per ky: load 10 overlapping 16B cells once, convert to f32 once,
// feed all 7 kx taps x 4 outputs from registers.
// Swizzle: grid 1568 = 8 x 196; each XCD gets a contiguous run of 196 blocks
// (= 2 whole batch images) so y-halo re-reads hit its private L2.
__global__ __launch_bounds__(256) void dwconv_reg(const bf16* __restrict__ in,
    bf16* __restrict__ out,
    const float* __restrict__ w0, const float* __restrict__ b0,
    const float* __restrict__ w1, const float* __restrict__ b1, int split)
{
    int tid = threadIdx.x;
    int chg = tid & 31;                      // 8-channel group
    int bsw = (blockIdx.x & 7) * 196 + (blockIdx.x >> 3);  // bijective XCD remap
    int pg  = bsw * 8 + (tid >> 5);          // pos-group = 4 consecutive x
    int xg = pg % 14;
    int y  = (pg / 14) % 56;
    int b  = pg / (14 * 56);
    int c0 = chg * 8;
    int x0 = xg * 4;

    const float* wp; const float* bp; int ws, cw;
    if (c0 < split) { wp = w0; bp = b0; ws = split;       cw = c0; }
    else            { wp = w1; bp = b1; ws = 256 - split; cw = c0 - split; }

    float acc[4][8];
    #pragma unroll
    for (int o = 0; o < 4; o++)
        #pragma unroll
        for (int e = 0; e < 8; e++) acc[o][e] = 0.f;

    const bf16* base = in + (size_t)b * HWSZ * 256 + c0;
    const float* wbase = wp + cw;
    #pragma unroll
    for (int ky = 0; ky < 7; ky++) {
        int gy = y + ky - 3;
        if (gy < 0 || gy >= 56) continue;
        const bf16* rowp = base + (size_t)gy * 56 * 256;
        float cf[10][8];
        #pragma unroll
        for (int j = 0; j < 10; j++) {
            int gx = x0 + j - 3;
            bf16x8 v = {0, 0, 0, 0, 0, 0, 0, 0};
            if ((unsigned)gx < 56u)
                v = *reinterpret_cast<const bf16x8*>(rowp + (size_t)gx * 256);
            #pragma unroll
            for (int e = 0; e < 8; e++) cf[j][e] = bu2f((unsigned short)v[e]);
        }
        const float* wrow = wbase + ky * 7 * ws;
        #pragma unroll
        for (int kx = 0; kx < 7; kx++) {
            float4 wa = *reinterpret_cast<const float4*>(wrow + kx * ws);
            float4 wb = *reinterpret_cast<const float4*>(wrow + kx * ws + 4);
            #pragma unroll
            for (int o = 0; o < 4; o++) {
                acc[o][0] += cf[o + kx][0] * wa.x;
                acc[o][1] += cf[o + kx][1] * wa.y;
                acc[o][2] += cf[o + kx][2] * wa.z;
                acc[o][3] += cf[o + kx][3] * wa.w;
                acc[o][4] += cf[o + kx][4] * wb.x;
                acc[o][5] += cf[o + kx][5] * wb.y;
                acc[o][6] += cf[o + kx][6] * wb.z;
                acc[o][7] += cf[o + kx][7] * wb.w;
            }
        }
    }

    float4 ba = *reinterpret_cast<const float4*>(bp + cw);
    float4 bb = *reinterpret_cast<const float4*>(bp + cw + 4);
    bf16* obase = out + (((size_t)b * HWSZ + (size_t)y * 56 + x0) * 256) + c0;
    #pragma unroll
    for (int o = 0; o < 4; o++) {
        bf16x8 ov;
        ov[0] = (short)f2bu(acc[o][0] + ba.x);
        ov[1] = (short)f2bu(acc[o][1] + ba.y);
        ov[2] = (short)f2bu(acc[o][2] + ba.z);
        ov[3] = (short)f2bu(acc[o][3] + ba.w);
        ov[4] = (short)f2bu(acc[o][4] + bb.x);
        ov[5] = (short)f2bu(acc[o][5] + bb.y);
        ov[6] = (short)f2bu(acc[o][6] + bb.z);
        ov[7] = (short)f2bu(acc[o][7] + bb.w);
        *reinterpret_cast<bf16x8*>(obase + (size_t)o * 256) = ov;
    }
}

// ---------------- rgb/t elementwise -> codin[N,256] ----------------
__global__ void rgbt_k(const bf16* __restrict__ rgb, const bf16* __restrict__ t,
                       bf16* __restrict__ codin, int total /* N*128 */)
{
    int i = blockIdx.x * blockDim.x + threadIdx.x;
    if (i >= total) return;
    int n = i >> 7, c = i & 127;
    float a = __bfloat162float(rgb[i]), bb = __bfloat162float(t[i]);
    codin[(size_t)n * 256 + c] = __float2bfloat16(a * bb);
    codin[(size_t)n * 256 + 128 + c] = __float2bfloat16(fabsf(a - bb));
}

// ---------------- cosine-gate partial reductions ----------------
__global__ __launch_bounds__(256) void cosred_k(const bf16* __restrict__ codi,
    float* __restrict__ part)   // [B][64][513]
{
    int b = blockIdx.x >> 4;
    int bi = blockIdx.x & 15;
    int wave = threadIdx.x >> 6, lane = threadIdx.x & 63;
    int slot = bi * 4 + wave;
    float dloc[4] = {0,0,0,0}, n2loc[4] = {0,0,0,0};
    float n1loc = 0.f;
    for (int i = 0; i < 49; i++) {
        int p = slot * 49 + i;
        const bf16* row = codi + ((size_t)b * HWSZ + p) * 256;
        float v[4]; float sum = 0.f;
        #pragma unroll
        for (int j = 0; j < 4; j++) { v[j] = __bfloat162float(row[lane + 64 * j]); sum += v[j]; }
        for (int off = 32; off; off >>= 1) sum += __shfl_xor(sum, off, 64);
        float amap = sum * (1.f / 256.f);
        #pragma unroll
        for (int j = 0; j < 4; j++) { dloc[j] += amap * v[j]; n2loc[j] += v[j] * v[j]; }
        n1loc += amap * amap;
    }
    float* dst = part + ((size_t)b * 64 + slot) * 513;
    #pragma unroll
    for (int j = 0; j < 4; j++) {
        dst[lane + 64 * j] = dloc[j];
        dst[256 + lane + 64 * j] = n2loc[j];
    }
    if (lane == 0) dst[512] = n1loc;
}

// ---------------- cos_sim + MLP + sigmoid -> attn_c[B,256] fp32 ----------------
__global__ __launch_bounds__(256) void mlp_kernel(const float* __restrict__ part,
    const float* __restrict__ fc1w, const float* __restrict__ fc2w,
    float* __restrict__ attnc)
{
    int b = blockIdx.x;
    int tid = threadIdx.x;
    __shared__ float cosb[256];
    __shared__ float hbuf[32];
    const float* pb = part + (size_t)b * 64 * 513;
    float dot = 0.f, n2 = 0.f, n1 = 0.f;
    for (int s = 0; s < 64; s++) {
        dot += pb[s * 513 + tid];
        n2  += pb[s * 513 + 256 + tid];
        n1  += pb[s * 513 + 512];
    }
    float cs = dot / (sqrtf(n1) * sqrtf(n2) + 1e-6f);
    cosb[tid] = cs;
    __syncthreads();
    if (tid < 32) {
        float h = 0.f;
        for (int c = 0; c < 256; c++) h += cosb[c] * fc1w[c * 32 + tid];
        h = 0.5f * h * (1.f + erff(h * 0.70710678f));
        hbuf[tid] = h;
    }
    __syncthreads();
    float o = 0.f;
    for (int j = 0; j < 32; j++) o += hbuf[j] * fc2w[j * 256 + tid];
    attnc[b * 256 + tid] = 1.f / (1.f + expf(-o));
}

// ---------------- 8x8 mean-pool of concat(xn, xen) -> rx_pool[B,49,384] fp32 ----------------
__global__ __launch_bounds__(384) void pool_kernel(const bf16* __restrict__ xn,
    const bf16* __restrict__ xen, float* __restrict__ rxpool)
{
    int bij = blockIdx.x;
    int b = bij / 49; int ij = bij % 49; int i = ij / 7, j = ij % 7;
    int c = threadIdx.x;
    float s = 0.f;
    for (int dy = 0; dy < 8; dy++)
        for (int dx = 0; dx < 8; dx++) {
            size_t n = ((size_t)b * 56 + (i * 8 + dy)) * 56 + (j * 8 + dx);
            s += (c < 256) ? __bfloat162float(xn[n * 256 + c])
                           : __bfloat162float(xen[n * 128 + (c - 256)]);
        }
    rxpool[(size_t)bij * 384 + c] = s * (1.f / 64.f);
}

// ---------------- MFMA flash attention over pooled q ----------------
#define NSPLIT 14
#define POSB   224   // 3136/14, multiple of 32
__global__ __launch_bounds__(256) void attn_mfma(const float* __restrict__ qbuf,
    const bf16* __restrict__ kbuf, const bf16* __restrict__ vtbuf,
    float* __restrict__ osplit, float* __restrict__ mlbuf)
{
    int bh = blockIdx.x & 127;
    int split = blockIdx.x >> 7;
    int b = bh >> 3, h = bh & 7;
    int tid = threadIdx.x;
    int qt = tid >> 6;
    int lane = tid & 63;
    int lo = lane & 15, hi = lane >> 4;

    bf16x8 qf = {0, 0, 0, 0, 0, 0, 0, 0};
    int q = qt * 16 + lo;
    if (hi < 2 && q < 49) {
        const float* qp = qbuf + ((size_t)b * 49 + q) * 128 + h * 16 + hi * 8;
        #pragma unroll
        for (int j = 0; j < 8; j++) qf[j] = (short)f2bu(qp[j] * 0.25f);
    }
    const bf16* kbase = kbuf + (size_t)bh * HWSZ * 16;
    const bf16* vbase = vtbuf + ((size_t)bh * 16 + lo) * HWSZ;

    float m_run = -1e30f, l_run = 0.f;
    f32x4 oacc = {0.f, 0.f, 0.f, 0.f};
    int pos1 = 8 * (lo >> 2) + (lo & 3);
    const f32x4 zz = {0.f, 0.f, 0.f, 0.f};

    for (int t = 0; t < POSB / 32; t++) {
        int base = split * POSB + t * 32;
        bf16x8 kf1 = {0, 0, 0, 0, 0, 0, 0, 0}, kf2 = kf1;
        if (hi < 2) {
            kf1 = *reinterpret_cast<const bf16x8*>(kbase + (size_t)(base + pos1) * 16 + hi * 8);
            kf2 = *reinterpret_cast<const bf16x8*>(kbase + (size_t)(base + pos1 + 4) * 16 + hi * 8);
        }
        bf16x8 vf = *reinterpret_cast<const bf16x8*>(vbase + base + hi * 8);
        f32x4 s1 = __builtin_amdgcn_mfma_f32_16x16x32_bf16(kf1, qf, zz, 0, 0, 0);
        f32x4 s2 = __builtin_amdgcn_mfma_f32_16x16x32_bf16(kf2, qf, zz, 0, 0, 0);
        float pmax = fmaxf(fmaxf(fmaxf(s1[0], s1[1]), fmaxf(s1[2], s1[3])),
                           fmaxf(fmaxf(s2[0], s2[1]), fmaxf(s2[2], s2[3])));
        pmax = fmaxf(pmax, __shfl_xor(pmax, 16, 64));
        pmax = fmaxf(pmax, __shfl_xor(pmax, 32, 64));
        float mnew = fmaxf(m_run, pmax);
        float esc = __expf(m_run - mnew);
        l_run *= esc;
        float e0 = __shfl(esc, 4 * hi + 0, 64);
        float e1 = __shfl(esc, 4 * hi + 1, 64);
        float e2 = __shfl(esc, 4 * hi + 2, 64);
        float e3 = __shfl(esc, 4 * hi + 3, 64);
        oacc[0] *= e0; oacc[1] *= e1; oacc[2] *= e2; oacc[3] *= e3;
        float p0 = __expf(s1[0] - mnew), p1 = __expf(s1[1] - mnew);
        float p2 = __expf(s1[2] - mnew), p3 = __expf(s1[3] - mnew);
        float p4 = __expf(s2[0] - mnew), p5 = __expf(s2[1] - mnew);
        float p6 = __expf(s2[2] - mnew), p7 = __expf(s2[3] - mnew);
        float rs = ((p0 + p1) + (p2 + p3)) + ((p4 + p5) + (p6 + p7));
        rs += __shfl_xor(rs, 16, 64);
        rs += __shfl_xor(rs, 32, 64);
        l_run += rs;
        m_run = mnew;
        bf16x8 pf;
        pf[0] = (short)f2bu(p0); pf[1] = (short)f2bu(p1);
        pf[2] = (short)f2bu(p2); pf[3] = (short)f2bu(p3);
        pf[4] = (short)f2bu(p4); pf[5] = (short)f2bu(p5);
        pf[6] = (short)f2bu(p6); pf[7] = (short)f2bu(p7);
        oacc = __builtin_amdgcn_mfma_f32_16x16x32_bf16(pf, vf, oacc, 0, 0, 0);
    }

    float* ob = osplit + ((size_t)bh * NSPLIT + split) * 64 * 16;
    #pragma unroll
    for (int r = 0; r < 4; r++) {
        int qq = qt * 16 + 4 * hi + r;
        ob[(size_t)qq * 16 + lo] = oacc[r];
    }
    if (hi == 0) {
        float* mlb = mlbuf + (((size_t)bh * NSPLIT + split) * 64 + qt * 16 + lo) * 2;
        mlb[0] = m_run; mlb[1] = l_run;
    }
}

// ---------------- merge split partials -> gs[bh][49][16] ----------------
__global__ __launch_bounds__(256) void attn_combine(const float* __restrict__ osplit,
    const float* __restrict__ mlbuf, float* __restrict__ gs)
{
    int idx = blockIdx.x * 256 + threadIdx.x;   // over 128*49*16
    if (idx >= 128 * 49 * 16) return;
    int d = idx & 15;
    int pq = idx >> 4;
    int bh = pq / 49, q = pq % 49;
    float m[NSPLIT], l[NSPLIT];
    float M = -1e30f;
    #pragma unroll
    for (int s = 0; s < NSPLIT; s++) {
        const float* mlb = mlbuf + (((size_t)bh * NSPLIT + s) * 64 + q) * 2;
        m[s] = mlb[0]; l[s] = mlb[1];
        M = fmaxf(M, m[s]);
    }
    float L = 0.f, O = 0.f;
    #pragma unroll
    for (int s = 0; s < NSPLIT; s++) {
        float e = __expf(m[s] - M);
        L += l[s] * e;
        O += osplit[(((size_t)bh * NSPLIT + s) * 64 + q) * 16 + d] * e;
    }
    gs[(size_t)pq * 16 + d] = O / L;
}

// ---------------- bilinear 7->56 upsample into cat[:, 384:512] ----------------
__global__ void upsample_kernel(const float* __restrict__ gs, bf16* __restrict__ cat)
{
    int idx = blockIdx.x * blockDim.x + threadIdx.x;  // over N*128
    if (idx >= N_TOK * 128) return;
    int c = idx & 127;
    int pos = idx >> 7;
    int h = c >> 4, d = c & 15;
    int x = pos % 56;
    int y = (pos / 56) % 56;
    int b = pos / HWSZ;
    float sy = (y + 0.5f) * 0.125f - 0.5f;
    float sx = (x + 0.5f) * 0.125f - 0.5f;
    int y0f = (int)floorf(sy); float wy = sy - (float)y0f;
    int x0f = (int)floorf(sx); float wx = sx - (float)x0f;
    int y0 = max(0, min(6, y0f)), y1 = max(0, min(6, y0f + 1));
    int x0 = max(0, min(6, x0f)), x1 = max(0, min(6, x0f + 1));
    const float* g0 = gs + ((size_t)(b * 8 + h) * 49) * 16 + d;
    float v00 = g0[(y0 * 7 + x0) * 16], v01 = g0[(y0 * 7 + x1) * 16];
    float v10 = g0[(y1 * 7 + x0) * 16], v11 = g0[(y1 * 7 + x1) * 16];
    float v0 = v00 + (v01 - v00) * wx;
    float v1 = v10 + (v11 - v10) * wx;
    float v = v0 + (v1 - v0) * wy;
    cat[(size_t)pos * 512 + 384 + c] = __float2bfloat16(v);
}

extern "C" void kernel_launch(void* const* d_in, const int* in_sizes, int n_in,
                              void* d_out, int out_size, void* d_ws, size_t ws_size,
                              hipStream_t stream)
{
    const float* x      = (const float*)d_in[0];
    const float* x_e    = (const float*)d_in[1];
    const float* norm_w = (const float*)d_in[2];
    const float* norm_b = (const float*)d_in[3];
    const float* norme_w= (const float*)d_in[4];
    const float* norme_b= (const float*)d_in[5];
    const float* rr1_w  = (const float*)d_in[6];
    const float* rr1_b  = (const float*)d_in[7];
    const float* rr2_w  = (const float*)d_in[8];
    const float* rr2_b  = (const float*)d_in[9];
    const float* rr3_w  = (const float*)d_in[10];
    const float* rr3_b  = (const float*)d_in[11];
    const float* conv_w = (const float*)d_in[12];
    const float* conv_b = (const float*)d_in[13];
    const float* l1_w   = (const float*)d_in[14];
    const float* l1_b   = (const float*)d_in[15];
    const float* l2_w   = (const float*)d_in[16];
    const float* l2_b   = (const float*)d_in[17];
    const float* c1_w   = (const float*)d_in[18];
    const float* c1_b   = (const float*)d_in[19];
    const float* c2_w   = (const float*)d_in[20];
    const float* c2_b   = (const float*)d_in[21];
    const float* fc1_w  = (const float*)d_in[22];
    const float* fc2_w  = (const float*)d_in[23];
    const float* l3_w   = (const float*)d_in[24];
    const float* l3_b   = (const float*)d_in[25];
    const float* kv_w   = (const float*)d_in[26];
    const float* kv_b   = (const float*)d_in[27];
    const float* q_w    = (const float*)d_in[28];
    const float* q_b    = (const float*)d_in[29];
    const float* proj_w = (const float*)d_in[30];
    const float* proj_b = (const float*)d_in[31];
    const float* proje_w= (const float*)d_in[32];
    const float* proje_b= (const float*)d_in[33];

    // ---- workspace: fp32 smalls, bf16 transposed weights, bf16 slabs ----
    float* part   = (float*)d_ws;                 // 16*64*513
    float* attnc  = part   + (size_t)525312;      // 16*256
    float* gs     = attnc  + 4096;                // 16*8*49*16
    float* rxpool = gs     + 100352;              // 784*384
    float* qbuf   = rxpool + 301056;              // 784*128
    bf16* wt      = (bf16*)(qbuf + 100352);
    bf16* rr1_t  = wt;              // 256x256
    bf16* rr2_t  = rr1_t + 65536;
    bf16* rr3_t  = rr2_t + 65536;
    bf16* kv_t   = rr3_t + 65536;
    bf16* l1_t   = kv_t  + 65536;   // 128x256
    bf16* l2_t   = l1_t  + 32768;   // 128x128
    bf16* l3_t   = l2_t  + 16384;   // 128x256
    bf16* proj_t = l3_t  + 32768;   // 256x512
    bf16* proje_t= proj_t + 131072; // 128x512
    bf16* xn     = proje_t + 65536;
    bf16* xen    = xn   + (size_t)N_TOK * 256;
    bf16* bufC   = xen  + (size_t)N_TOK * 128;   // rr1 / codin / K|V head-major
    bf16* bufD   = bufC + (size_t)N_TOK * 256;   // rr2pre / rgb|t / attn partials
    bf16* bufE   = bufD + (size_t)N_TOK * 256;   // conv out / co_di
    bf16* cat    = bufE + (size_t)N_TOK * 256;   // [N,512]
    size_t need = (size_t)((char*)(cat + (size_t)N_TOK * 512) - (char*)d_ws);
    if (ws_size < need) return;

    bf16* kbuf = bufC;                       // [B*8][HWSZ][16]
    bf16* vbuf = bufC + (size_t)N_TOK * 128; // [B*8][16][HWSZ] (transposed)

    // attn split partials live in bufD (free during phase 4): 8.26 MB
    float* osplit = (float*)bufD;                          // [128][NSPLIT][64][16]
    float* mlbuf  = osplit + (size_t)128 * NSPLIT * 64 * 16; // [128][NSPLIT][64][2]

    float* xout  = (float*)d_out;
    float* xeout = xout + (size_t)N_TOK * 256;

    const int nthr = 256;
    auto mgrid = [](int M, int N) { return dim3((M / 128) * (N / 128)); };

    // 0. weight prep (one launch)
    {
        WtrPack p;
        const float* srcs[9] = {rr1_w, rr2_w, rr3_w, kv_w, l1_w, l2_w, l3_w, proj_w, proje_w};
        bf16* dsts[9] = {rr1_t, rr2_t, rr3_t, kv_t, l1_t, l2_t, l3_t, proj_t, proje_t};
        int Ks[9] = {256, 256, 256, 256, 256, 128, 256, 512, 512};
        int Ns[9] = {256, 256, 256, 256, 128, 128, 128, 256, 128};
        int off = 0;
        for (int s = 0; s < 9; s++) {
            p.d[s] = {srcs[s], dsts[s], Ks[s], Ns[s], off};
            off += Ks[s] * Ns[s];
        }
        p.total = off;
        wtr_all<<<dim3((off + 255) / 256), dim3(256), 0, stream>>>(p);
    }

    // 1. LayerNorms
    ln_kernel<<<dim3(N_TOK / 4), dim3(nthr), 0, stream>>>(x, norm_w, norm_b, xn, N_TOK, 256);
    ln_kernel<<<dim3(N_TOK / 4), dim3(nthr), 0, stream>>>(x_e, norme_w, norme_b, xen, N_TOK, 128);

    // 2. local_rr -> cat[:, 0:256]
    gemm_mfma<0, bf16><<<mgrid(N_TOK, 256), dim3(nthr), 0, stream>>>(
        xn, 256, rr1_t, rr1_b, bufC, 256, N_TOK, 256, 256, nullptr, 0, nullptr, nullptr, nullptr);
    gemm_mfma<0, bf16><<<mgrid(N_TOK, 256), dim3(nthr), 0, stream>>>(
        xn, 256, rr2_t, rr2_b, bufD, 256, N_TOK, 256, 256, nullptr, 0, nullptr, nullptr, nullptr);
    dwconv_reg<<<dim3(N_TOK / 32), dim3(nthr), 0, stream>>>(
        bufD, bufE, conv_w, conv_b, conv_w, conv_b, 256);
    gemm_mfma<GF_MUL, bf16><<<mgrid(N_TOK, 256), dim3(nthr), 0, stream>>>(
        bufE, 256, rr3_t, rr3_b, cat, 512, N_TOK, 256, 256, bufC, 256, nullptr, nullptr, nullptr);

    // 3. LocalAttentionRGBT -> cat[:, 256:384]
    gemm_mfma<0, bf16><<<mgrid(N_TOK, 128), dim3(nthr), 0, stream>>>(
        xn, 256, l1_t, l1_b, bufD, 128, N_TOK, 256, 128, nullptr, 0, nullptr, nullptr, nullptr);
    gemm_mfma<0, bf16><<<mgrid(N_TOK, 128), dim3(nthr), 0, stream>>>(
        xen, 128, l2_t, l2_b, bufD + (size_t)N_TOK * 128, 128, N_TOK, 128, 128, nullptr, 0, nullptr, nullptr, nullptr);
    rgbt_k<<<dim3((N_TOK * 128) / nthr), dim3(nthr), 0, stream>>>(
        bufD, bufD + (size_t)N_TOK * 128, bufC, N_TOK * 128);
    dwconv_reg<<<dim3(N_TOK / 32), dim3(nthr), 0, stream>>>(
        bufC, bufE, c1_w, c1_b, c2_w, c2_b, 128);
    cosred_k<<<dim3(BATCH * 16), dim3(nthr), 0, stream>>>(bufE, part);
    mlp_kernel<<<dim3(BATCH), dim3(nthr), 0, stream>>>(part, fc1_w, fc2_w, attnc);
    gemm_mfma<GF_ASCALE, bf16><<<mgrid(N_TOK, 128), dim3(nthr), 0, stream>>>(
        bufE, 256, l3_t, l3_b, cat + 256, 512, N_TOK, 256, 128, nullptr, 0, attnc, nullptr, nullptr);

    // 4. global pooled attention -> cat[:, 384:512]
    gemm_mfma<GF_KVSPLIT, bf16><<<mgrid(N_TOK, 256), dim3(nthr), 0, stream>>>(
        xn, 256, kv_t, kv_b, (bf16*)nullptr, 0, N_TOK, 256, 256, nullptr, 0, nullptr, kbuf, vbuf);
    pool_kernel<<<dim3(BATCH * 49), dim3(384), 0, stream>>>(xn, xen, rxpool);
    gemm_k<<<dim3(((784 + 63) / 64) * 2), dim3(nthr), 0, stream>>>(
        rxpool, 384, q_w, q_b, qbuf, 128, 784, 384, 128);
    attn_mfma<<<dim3(128 * NSPLIT), dim3(nthr), 0, stream>>>(qbuf, kbuf, vbuf, osplit, mlbuf);
    attn_combine<<<dim3(392), dim3(nthr), 0, stream>>>(osplit, mlbuf, gs);
    upsample_kernel<<<dim3((N_TOK * 128) / nthr), dim3(nthr), 0, stream>>>(gs, cat);

    // 5. output projections (fp32 out)
    gemm_mfma<0, float><<<mgrid(N_TOK, 256), dim3(nthr), 0, stream>>>(
        cat, 512, proj_t, proj_b, xout, 256, N_TOK, 512, 256, nullptr, 0, nullptr, nullptr, nullptr);
    gemm_mfma<0, float><<<mgrid(N_TOK, 128), dim3(nthr), 0, stream>>>(
        cat, 512, proje_t, proje_b, xeout, 128, N_TOK, 512, 128, nullptr, 0, nullptr, nullptr, nullptr);
}

// Round 7
// 451.152 us; speedup vs baseline: 1.1845x; 1.0601x over previous
//
#include <hip/hip_runtime.h>
#include <hip/hip_bf16.h>
#include <cstdint>
#include <cstddef>

#define N_TOK 50176      // B*H*W
#define HWSZ  3136       // 56*56
#define BATCH 16

#define GF_MUL     1
#define GF_ASCALE  2
#define GF_KVSPLIT 4
#define GF_DUAL    8

typedef __hip_bfloat16 bf16;
typedef __attribute__((ext_vector_type(8))) short bf16x8;
typedef __attribute__((ext_vector_type(4))) float f32x4;
typedef __attribute__((ext_vector_type(4))) unsigned short u16x4;

__device__ __forceinline__ void  stf(float* p, size_t i, float v) { p[i] = v; }
__device__ __forceinline__ void  stf(bf16* p, size_t i, float v) { p[i] = __float2bfloat16(v); }
__device__ __forceinline__ float bu2f(unsigned short u) {
    unsigned int x = ((unsigned int)u) << 16; float f; __builtin_memcpy(&f, &x, 4); return f;
}
__device__ __forceinline__ unsigned short f2bu(float f) {
    bf16 t = __float2bfloat16(f); unsigned short u; __builtin_memcpy(&u, &t, 2); return u;
}

// ---------------- batched weight prep: W[K][N] fp32 -> WT[N][K] bf16 (9 mats, 1 launch) ----------------
struct WtrDesc { const float* src; bf16* dst; int K; int N; int off; };
struct WtrPack { WtrDesc d[9]; int total; };
__global__ __launch_bounds__(256) void wtr_all(WtrPack p)
{
    int idx = blockIdx.x * 256 + threadIdx.x;
    if (idx >= p.total) return;
    #pragma unroll
    for (int s = 0; s < 9; s++) {
        int lo = p.d[s].off, hi = lo + p.d[s].K * p.d[s].N;
        if (idx >= lo && idx < hi) {
            int j = idx - lo;
            int k = j / p.d[s].N, n = j % p.d[s].N;
            p.d[s].dst[(size_t)n * p.d[s].K + k] = __float2bfloat16(p.d[s].src[j]);
        }
    }
}

// ---------------- LayerNorm: one wave per row (fp32 in -> bf16 out) ----------------
__global__ __launch_bounds__(256) void ln_kernel(const float* __restrict__ in,
    const float* __restrict__ w, const float* __restrict__ b,
    bf16* __restrict__ out, int rows, int Cdim)
{
    int wave = threadIdx.x >> 6, lane = threadIdx.x & 63;
    int row = blockIdx.x * 4 + wave;
    if (row >= rows) return;
    const float* p = in + (size_t)row * Cdim;
    int nj = Cdim >> 6;
    float v[4];
    float s = 0.f;
    for (int j = 0; j < nj; j++) { v[j] = p[lane + 64 * j]; s += v[j]; }
    for (int off = 32; off; off >>= 1) s += __shfl_xor(s, off, 64);
    float mean = s / (float)Cdim;
    float vs = 0.f;
    for (int j = 0; j < nj; j++) { float d = v[j] - mean; vs += d * d; }
    for (int off = 32; off; off >>= 1) vs += __shfl_xor(vs, off, 64);
    float rstd = 1.f / sqrtf(vs / (float)Cdim + 1e-6f);
    bf16* q = out + (size_t)row * Cdim;
    for (int j = 0; j < nj; j++) {
        int c = lane + 64 * j;
        q[c] = __float2bfloat16((v[j] - mean) * rstd * w[c] + b[c]);
    }
}

// ---------------- MFMA GEMM: C = A[M,K](bf16) @ WT[N,K]^T(bf16) + bias ----------------
// 128x128 tile, BK=32, 256 threads (4 waves 2x2), 16x16x32 MFMA, fp32 accum.
// Software-pipelined: tile k staged to LDS from regs, next-tile global loads issued
// before the compute phase so HBM latency hides under ds_read+MFMA.
// GF_DUAL: N-range [0,N1) -> C/bias, [N1,N) -> C2/bias2 (fused shared-A GEMMs).
#define LDT 56   // padded LDS K-stride (112B: 16B-aligned, 2-way banks)
template<int FLAGS, typename OT>
__global__ __launch_bounds__(256) void gemm_mfma(
    const bf16* __restrict__ A, int lda,
    const bf16* __restrict__ WT,           // [N][K]
    const float* __restrict__ bias,
    OT* __restrict__ C, int ldc,
    int M, int K, int N,
    const bf16* __restrict__ mul, int mulld,
    const float* __restrict__ ascale,      // [BATCH][K]
    bf16* __restrict__ kout, bf16* __restrict__ vout,
    OT* __restrict__ C2, int ldc2, const float* __restrict__ bias2, int N1)
{
    __shared__ bf16 As[128][LDT];
    __shared__ bf16 Bs[128][LDT];
    int ntile = N >> 7;
    int m0 = (blockIdx.x / ntile) * 128;
    int n0 = (blockIdx.x % ntile) * 128;
    int tid = threadIdx.x;
    int lane = tid & 63, wid = tid >> 6;
    int wr = (wid >> 1) * 64, wc = (wid & 1) * 64;
    int lrow = lane & 15, lko = (lane >> 4) * 8;
    int sr = tid >> 2, sko = (tid & 3) * 8;

    f32x4 acc[4][4];
    #pragma unroll
    for (int i = 0; i < 4; i++)
        #pragma unroll
        for (int j = 0; j < 4; j++)
            acc[i][j] = (f32x4){0.f, 0.f, 0.f, 0.f};

    // prologue: load tile 0 into regs
    bf16x8 ra[2], rb[2];
    #pragma unroll
    for (int i = 0; i < 2; i++) {
        int r = sr + i * 64;
        bf16x8 v = *reinterpret_cast<const bf16x8*>(A + (size_t)(m0 + r) * lda + sko);
        if (FLAGS & GF_ASCALE) {
            int bidx = (m0 + r) / HWSZ;
            const float* as = ascale + (size_t)bidx * K + sko;
            #pragma unroll
            for (int e = 0; e < 8; e++)
                v[e] = (short)f2bu(bu2f((unsigned short)v[e]) * as[e]);
        }
        ra[i] = v;
        rb[i] = *reinterpret_cast<const bf16x8*>(WT + (size_t)(n0 + r) * K + sko);
    }

    for (int k0 = 0; k0 < K; k0 += 32) {
        #pragma unroll
        for (int i = 0; i < 2; i++) {
            *reinterpret_cast<bf16x8*>(&As[sr + i * 64][sko]) = ra[i];
            *reinterpret_cast<bf16x8*>(&Bs[sr + i * 64][sko]) = rb[i];
        }
        __syncthreads();
        int kn = k0 + 32;
        if (kn < K) {
            #pragma unroll
            for (int i = 0; i < 2; i++) {
                int r = sr + i * 64;
                bf16x8 v = *reinterpret_cast<const bf16x8*>(A + (size_t)(m0 + r) * lda + kn + sko);
                if (FLAGS & GF_ASCALE) {
                    int bidx = (m0 + r) / HWSZ;
                    const float* as = ascale + (size_t)bidx * K + kn + sko;
                    #pragma unroll
                    for (int e = 0; e < 8; e++)
                        v[e] = (short)f2bu(bu2f((unsigned short)v[e]) * as[e]);
                }
                ra[i] = v;
                rb[i] = *reinterpret_cast<const bf16x8*>(WT + (size_t)(n0 + r) * K + kn + sko);
            }
        }
        bf16x8 af[4], br[4];
        #pragma unroll
        for (int i = 0; i < 4; i++)
            af[i] = *reinterpret_cast<const bf16x8*>(&As[wr + i * 16 + lrow][lko]);
        #pragma unroll
        for (int j = 0; j < 4; j++)
            br[j] = *reinterpret_cast<const bf16x8*>(&Bs[wc + j * 16 + lrow][lko]);
        #pragma unroll
        for (int i = 0; i < 4; i++)
            #pragma unroll
            for (int j = 0; j < 4; j++)
                acc[i][j] = __builtin_amdgcn_mfma_f32_16x16x32_bf16(af[i], br[j], acc[i][j], 0, 0, 0);
        __syncthreads();
    }

    int orow = (lane >> 4) * 4;
    int ocol = lane & 15;
    #pragma unroll
    for (int i = 0; i < 4; i++) {
        #pragma unroll
        for (int j = 0; j < 4; j++) {
            #pragma unroll
            for (int p = 0; p < 4; p++) {
                int gm = m0 + wr + i * 16 + orow + p;
                int gn = n0 + wc + j * 16 + ocol;
                if (FLAGS & GF_KVSPLIT) {
                    float v = acc[i][j][p] + bias[gn];
                    int bb = gm / HWSZ, n = gm % HWSZ;
                    if (gn < 128)
                        kout[(((size_t)bb * 8 + (gn >> 4)) * HWSZ + n) * 16 + (gn & 15)] = __float2bfloat16(v);
                    else {
                        int hh = (gn - 128) >> 4, dd = (gn - 128) & 15;
                        // V stored TRANSPOSED: [bh][d][pos]
                        vout[(((size_t)bb * 8 + hh) * 16 + dd) * HWSZ + n] = __float2bfloat16(v);
                    }
                } else if (FLAGS & GF_DUAL) {
                    if (gn < N1) {
                        float v = acc[i][j][p] + bias[gn];
                        stf(C, (size_t)gm * ldc + gn, v);
                    } else {
                        float v = acc[i][j][p] + bias2[gn - N1];
                        stf(C2, (size_t)gm * ldc2 + (gn - N1), v);
                    }
                } else {
                    float v = acc[i][j][p] + bias[gn];
                    if (FLAGS & GF_MUL) v *= __bfloat162float(mul[(size_t)gm * mulld + gn]);
                    stf(C, (size_t)gm * ldc + gn, v);
                }
            }
        }
    }
}

// ---------------- fp32 vector GEMM (small q projection only) ----------------
__global__ __launch_bounds__(256) void gemm_k(
    const float* __restrict__ A, int lda,
    const float* __restrict__ Wt, const float* __restrict__ bias,
    float* __restrict__ Cc, int ldc, int M, int K, int Nc)
{
    __shared__ float As[16][68];
    __shared__ float Ws[16][64];
    int ntile = Nc >> 6;
    int tile_n = blockIdx.x % ntile;
    int tile_m = blockIdx.x / ntile;
    int m0 = tile_m * 64, n0 = tile_n * 64;
    int tid = threadIdx.x;
    int tx = tid & 15, ty = tid >> 4;
    float acc[4][4] = {};
    for (int k0 = 0; k0 < K; k0 += 16) {
        int ks = tid & 15, ms = tid >> 4;
        #pragma unroll
        for (int i = 0; i < 4; i++) {
            int gm = m0 + ms + i * 16;
            As[ks][ms + i * 16] = (gm < M) ? A[(size_t)gm * lda + k0 + ks] : 0.f;
        }
        #pragma unroll
        for (int j = 0; j < 4; j++) {
            int k = (tid >> 6) * 4 + j;
            Ws[k][tid & 63] = Wt[(size_t)(k0 + k) * Nc + n0 + (tid & 63)];
        }
        __syncthreads();
        #pragma unroll
        for (int k = 0; k < 16; k++) {
            float a[4], w[4];
            #pragma unroll
            for (int i = 0; i < 4; i++) a[i] = As[k][ty * 4 + i];
            #pragma unroll
            for (int j = 0; j < 4; j++) w[j] = Ws[k][tx * 4 + j];
            #pragma unroll
            for (int i = 0; i < 4; i++)
                #pragma unroll
                for (int j = 0; j < 4; j++)
                    acc[i][j] += a[i] * w[j];
        }
        __syncthreads();
    }
    #pragma unroll
    for (int i = 0; i < 4; i++) {
        int gm = m0 + ty * 4 + i;
        if (gm >= M) continue;
        #pragma unroll
        for (int j = 0; j < 4; j++) {
            int gn = n0 + tx * 4 + j;
            Cc[(size_t)gm * ldc + gn] = acc[i][j] + bias[gn];
        }
    }
}

// ---------------- direct-global depthwise 7x7 conv with x-register reuse ----------------
// Thread: 4 consecutive x positions x 8 channels, one (b,y) row.
// Per ky: load 10 overlapping 16B cells once, convert to f32 once,
// feed all 7 kx taps x 4 outputs from registers.
// Swizzle: grid 1568 = 8 x 196; each XCD gets a contiguous run of 196 blocks
// (= 2 whole batch images) so y-halo re-reads hit its private L2.
__global__ __launch_bounds__(256) void dwconv_reg(const bf16* __restrict__ in,
    bf16* __restrict__ out,
    const float* __restrict__ w0, const float* __restrict__ b0,
    const float* __restrict__ w1, const float* __restrict__ b1, int split)
{
    int tid = threadIdx.x;
    int chg = tid & 31;                      // 8-channel group
    int bsw = (blockIdx.x & 7) * 196 + (blockIdx.x >> 3);  // bijective XCD remap
    int pg  = bsw * 8 + (tid >> 5);          // pos-group = 4 consecutive x
    int xg = pg % 14;
    int y  = (pg / 14) % 56;
    int b  = pg / (14 * 56);
    int c0 = chg * 8;
    int x0 = xg * 4;

    const float* wp; const float* bp; int ws, cw;
    if (c0 < split) { wp = w0; bp = b0; ws = split;       cw = c0; }
    else            { wp = w1; bp = b1; ws = 256 - split; cw = c0 - split; }

    float acc[4][8];
    #pragma unroll
    for (int o = 0; o < 4; o++)
        #pragma unroll
        for (int e = 0; e < 8; e++) acc[o][e] = 0.f;

    const bf16* base = in + (size_t)b * HWSZ * 256 + c0;
    const float* wbase = wp + cw;
    #pragma unroll
    for (int ky = 0; ky < 7; ky++) {
        int gy = y + ky - 3;
        if (gy < 0 || gy >= 56) continue;
        const bf16* rowp = base + (size_t)gy * 56 * 256;
        float cf[10][8];
        #pragma unroll
        for (int j = 0; j < 10; j++) {
            int gx = x0 + j - 3;
            bf16x8 v = {0, 0, 0, 0, 0, 0, 0, 0};
            if ((unsigned)gx < 56u)
                v = *reinterpret_cast<const bf16x8*>(rowp + (size_t)gx * 256);
            #pragma unroll
            for (int e = 0; e < 8; e++) cf[j][e] = bu2f((unsigned short)v[e]);
        }
        const float* wrow = wbase + ky * 7 * ws;
        #pragma unroll
        for (int kx = 0; kx < 7; kx++) {
            float4 wa = *reinterpret_cast<const float4*>(wrow + kx * ws);
            float4 wb = *reinterpret_cast<const float4*>(wrow + kx * ws + 4);
            #pragma unroll
            for (int o = 0; o < 4; o++) {
                acc[o][0] += cf[o + kx][0] * wa.x;
                acc[o][1] += cf[o + kx][1] * wa.y;
                acc[o][2] += cf[o + kx][2] * wa.z;
                acc[o][3] += cf[o + kx][3] * wa.w;
                acc[o][4] += cf[o + kx][4] * wb.x;
                acc[o][5] += cf[o + kx][5] * wb.y;
                acc[o][6] += cf[o + kx][6] * wb.z;
                acc[o][7] += cf[o + kx][7] * wb.w;
            }
        }
    }

    float4 ba = *reinterpret_cast<const float4*>(bp + cw);
    float4 bb = *reinterpret_cast<const float4*>(bp + cw + 4);
    bf16* obase = out + (((size_t)b * HWSZ + (size_t)y * 56 + x0) * 256) + c0;
    #pragma unroll
    for (int o = 0; o < 4; o++) {
        bf16x8 ov;
        ov[0] = (short)f2bu(acc[o][0] + ba.x);
        ov[1] = (short)f2bu(acc[o][1] + ba.y);
        ov[2] = (short)f2bu(acc[o][2] + ba.z);
        ov[3] = (short)f2bu(acc[o][3] + ba.w);
        ov[4] = (short)f2bu(acc[o][4] + bb.x);
        ov[5] = (short)f2bu(acc[o][5] + bb.y);
        ov[6] = (short)f2bu(acc[o][6] + bb.z);
        ov[7] = (short)f2bu(acc[o][7] + bb.w);
        *reinterpret_cast<bf16x8*>(obase + (size_t)o * 256) = ov;
    }
}

// ---------------- rgb/t elementwise -> codin[N,256] ----------------
__global__ void rgbt_k(const bf16* __restrict__ rgb, const bf16* __restrict__ t,
                       bf16* __restrict__ codin, int total /* N*128 */)
{
    int i = blockIdx.x * blockDim.x + threadIdx.x;
    if (i >= total) return;
    int n = i >> 7, c = i & 127;
    float a = __bfloat162float(rgb[i]), bb = __bfloat162float(t[i]);
    codin[(size_t)n * 256 + c] = __float2bfloat16(a * bb);
    codin[(size_t)n * 256 + 128 + c] = __float2bfloat16(fabsf(a - bb));
}

// ---------------- cosine-gate partial reductions ----------------
__global__ __launch_bounds__(256) void cosred_k(const bf16* __restrict__ codi,
    float* __restrict__ part)   // [B][64][513]
{
    int b = blockIdx.x >> 4;
    int bi = blockIdx.x & 15;
    int wave = threadIdx.x >> 6, lane = threadIdx.x & 63;
    int slot = bi * 4 + wave;
    float dloc[4] = {0,0,0,0}, n2loc[4] = {0,0,0,0};
    float n1loc = 0.f;
    for (int i = 0; i < 49; i++) {
        int p = slot * 49 + i;
        const bf16* row = codi + ((size_t)b * HWSZ + p) * 256;
        float v[4]; float sum = 0.f;
        #pragma unroll
        for (int j = 0; j < 4; j++) { v[j] = __bfloat162float(row[lane + 64 * j]); sum += v[j]; }
        for (int off = 32; off; off >>= 1) sum += __shfl_xor(sum, off, 64);
        float amap = sum * (1.f / 256.f);
        #pragma unroll
        for (int j = 0; j < 4; j++) { dloc[j] += amap * v[j]; n2loc[j] += v[j] * v[j]; }
        n1loc += amap * amap;
    }
    float* dst = part + ((size_t)b * 64 + slot) * 513;
    #pragma unroll
    for (int j = 0; j < 4; j++) {
        dst[lane + 64 * j] = dloc[j];
        dst[256 + lane + 64 * j] = n2loc[j];
    }
    if (lane == 0) dst[512] = n1loc;
}

// ---------------- cos_sim + MLP + sigmoid -> attn_c[B,256] fp32 ----------------
__global__ __launch_bounds__(256) void mlp_kernel(const float* __restrict__ part,
    const float* __restrict__ fc1w, const float* __restrict__ fc2w,
    float* __restrict__ attnc)
{
    int b = blockIdx.x;
    int tid = threadIdx.x;
    __shared__ float cosb[256];
    __shared__ float hbuf[32];
    const float* pb = part + (size_t)b * 64 * 513;
    float dot = 0.f, n2 = 0.f, n1 = 0.f;
    for (int s = 0; s < 64; s++) {
        dot += pb[s * 513 + tid];
        n2  += pb[s * 513 + 256 + tid];
        n1  += pb[s * 513 + 512];
    }
    float cs = dot / (sqrtf(n1) * sqrtf(n2) + 1e-6f);
    cosb[tid] = cs;
    __syncthreads();
    if (tid < 32) {
        float h = 0.f;
        for (int c = 0; c < 256; c++) h += cosb[c] * fc1w[c * 32 + tid];
        h = 0.5f * h * (1.f + erff(h * 0.70710678f));
        hbuf[tid] = h;
    }
    __syncthreads();
    float o = 0.f;
    for (int j = 0; j < 32; j++) o += hbuf[j] * fc2w[j * 256 + tid];
    attnc[b * 256 + tid] = 1.f / (1.f + expf(-o));
}

// ---------------- 8x8 mean-pool of concat(xn, xen) -> rx_pool[B,49,384] fp32 ----------------
__global__ __launch_bounds__(384) void pool_kernel(const bf16* __restrict__ xn,
    const bf16* __restrict__ xen, float* __restrict__ rxpool)
{
    int bij = blockIdx.x;
    int b = bij / 49; int ij = bij % 49; int i = ij / 7, j = ij % 7;
    int c = threadIdx.x;
    float s = 0.f;
    for (int dy = 0; dy < 8; dy++)
        for (int dx = 0; dx < 8; dx++) {
            size_t n = ((size_t)b * 56 + (i * 8 + dy)) * 56 + (j * 8 + dx);
            s += (c < 256) ? __bfloat162float(xn[n * 256 + c])
                           : __bfloat162float(xen[n * 128 + (c - 256)]);
        }
    rxpool[(size_t)bij * 384 + c] = s * (1.f / 64.f);
}

// ---------------- MFMA flash attention over pooled q ----------------
#define NSPLIT 14
#define POSB   224   // 3136/14, multiple of 32
__global__ __launch_bounds__(256) void attn_mfma(const float* __restrict__ qbuf,
    const bf16* __restrict__ kbuf, const bf16* __restrict__ vtbuf,
    float* __restrict__ osplit, float* __restrict__ mlbuf)
{
    int bh = blockIdx.x & 127;
    int split = blockIdx.x >> 7;
    int b = bh >> 3, h = bh & 7;
    int tid = threadIdx.x;
    int qt = tid >> 6;
    int lane = tid & 63;
    int lo = lane & 15, hi = lane >> 4;

    bf16x8 qf = {0, 0, 0, 0, 0, 0, 0, 0};
    int q = qt * 16 + lo;
    if (hi < 2 && q < 49) {
        const float* qp = qbuf + ((size_t)b * 49 + q) * 128 + h * 16 + hi * 8;
        #pragma unroll
        for (int j = 0; j < 8; j++) qf[j] = (short)f2bu(qp[j] * 0.25f);
    }
    const bf16* kbase = kbuf + (size_t)bh * HWSZ * 16;
    const bf16* vbase = vtbuf + ((size_t)bh * 16 + lo) * HWSZ;

    float m_run = -1e30f, l_run = 0.f;
    f32x4 oacc = {0.f, 0.f, 0.f, 0.f};
    int pos1 = 8 * (lo >> 2) + (lo & 3);
    const f32x4 zz = {0.f, 0.f, 0.f, 0.f};

    for (int t = 0; t < POSB / 32; t++) {
        int base = split * POSB + t * 32;
        bf16x8 kf1 = {0, 0, 0, 0, 0, 0, 0, 0}, kf2 = kf1;
        if (hi < 2) {
            kf1 = *reinterpret_cast<const bf16x8*>(kbase + (size_t)(base + pos1) * 16 + hi * 8);
            kf2 = *reinterpret_cast<const bf16x8*>(kbase + (size_t)(base + pos1 + 4) * 16 + hi * 8);
        }
        bf16x8 vf = *reinterpret_cast<const bf16x8*>(vbase + base + hi * 8);
        f32x4 s1 = __builtin_amdgcn_mfma_f32_16x16x32_bf16(kf1, qf, zz, 0, 0, 0);
        f32x4 s2 = __builtin_amdgcn_mfma_f32_16x16x32_bf16(kf2, qf, zz, 0, 0, 0);
        float pmax = fmaxf(fmaxf(fmaxf(s1[0], s1[1]), fmaxf(s1[2], s1[3])),
                           fmaxf(fmaxf(s2[0], s2[1]), fmaxf(s2[2], s2[3])));
        pmax = fmaxf(pmax, __shfl_xor(pmax, 16, 64));
        pmax = fmaxf(pmax, __shfl_xor(pmax, 32, 64));
        float mnew = fmaxf(m_run, pmax);
        float esc = __expf(m_run - mnew);
        l_run *= esc;
        float e0 = __shfl(esc, 4 * hi + 0, 64);
        float e1 = __shfl(esc, 4 * hi + 1, 64);
        float e2 = __shfl(esc, 4 * hi + 2, 64);
        float e3 = __shfl(esc, 4 * hi + 3, 64);
        oacc[0] *= e0; oacc[1] *= e1; oacc[2] *= e2; oacc[3] *= e3;
        float p0 = __expf(s1[0] - mnew), p1 = __expf(s1[1] - mnew);
        float p2 = __expf(s1[2] - mnew), p3 = __expf(s1[3] - mnew);
        float p4 = __expf(s2[0] - mnew), p5 = __expf(s2[1] - mnew);
        float p6 = __expf(s2[2] - mnew), p7 = __expf(s2[3] - mnew);
        float rs = ((p0 + p1) + (p2 + p3)) + ((p4 + p5) + (p6 + p7));
        rs += __shfl_xor(rs, 16, 64);
        rs += __shfl_xor(rs, 32, 64);
        l_run += rs;
        m_run = mnew;
        bf16x8 pf;
        pf[0] = (short)f2bu(p0); pf[1] = (short)f2bu(p1);
        pf[2] = (short)f2bu(p2); pf[3] = (short)f2bu(p3);
        pf[4] = (short)f2bu(p4); pf[5] = (short)f2bu(p5);
        pf[6] = (short)f2bu(p6); pf[7] = (short)f2bu(p7);
        oacc = __builtin_amdgcn_mfma_f32_16x16x32_bf16(pf, vf, oacc, 0, 0, 0);
    }

    float* ob = osplit + ((size_t)bh * NSPLIT + split) * 64 * 16;
    #pragma unroll
    for (int r = 0; r < 4; r++) {
        int qq = qt * 16 + 4 * hi + r;
        ob[(size_t)qq * 16 + lo] = oacc[r];
    }
    if (hi == 0) {
        float* mlb = mlbuf + (((size_t)bh * NSPLIT + split) * 64 + qt * 16 + lo) * 2;
        mlb[0] = m_run; mlb[1] = l_run;
    }
}

// ---------------- merge split partials -> gs[bh][49][16] ----------------
__global__ __launch_bounds__(256) void attn_combine(const float* __restrict__ osplit,
    const float* __restrict__ mlbuf, float* __restrict__ gs)
{
    int idx = blockIdx.x * 256 + threadIdx.x;   // over 128*49*16
    if (idx >= 128 * 49 * 16) return;
    int d = idx & 15;
    int pq = idx >> 4;
    int bh = pq / 49, q = pq % 49;
    float m[NSPLIT], l[NSPLIT];
    float M = -1e30f;
    #pragma unroll
    for (int s = 0; s < NSPLIT; s++) {
        const float* mlb = mlbuf + (((size_t)bh * NSPLIT + s) * 64 + q) * 2;
        m[s] = mlb[0]; l[s] = mlb[1];
        M = fmaxf(M, m[s]);
    }
    float L = 0.f, O = 0.f;
    #pragma unroll
    for (int s = 0; s < NSPLIT; s++) {
        float e = __expf(m[s] - M);
        L += l[s] * e;
        O += osplit[(((size_t)bh * NSPLIT + s) * 64 + q) * 16 + d] * e;
    }
    gs[(size_t)pq * 16 + d] = O / L;
}

// ---------------- bilinear 7->56 upsample into cat[:, 384:512] ----------------
__global__ void upsample_kernel(const float* __restrict__ gs, bf16* __restrict__ cat)
{
    int idx = blockIdx.x * blockDim.x + threadIdx.x;  // over N*128
    if (idx >= N_TOK * 128) return;
    int c = idx & 127;
    int pos = idx >> 7;
    int h = c >> 4, d = c & 15;
    int x = pos % 56;
    int y = (pos / 56) % 56;
    int b = pos / HWSZ;
    float sy = (y + 0.5f) * 0.125f - 0.5f;
    float sx = (x + 0.5f) * 0.125f - 0.5f;
    int y0f = (int)floorf(sy); float wy = sy - (float)y0f;
    int x0f = (int)floorf(sx); float wx = sx - (float)x0f;
    int y0 = max(0, min(6, y0f)), y1 = max(0, min(6, y0f + 1));
    int x0 = max(0, min(6, x0f)), x1 = max(0, min(6, x0f + 1));
    const float* g0 = gs + ((size_t)(b * 8 + h) * 49) * 16 + d;
    float v00 = g0[(y0 * 7 + x0) * 16], v01 = g0[(y0 * 7 + x1) * 16];
    float v10 = g0[(y1 * 7 + x0) * 16], v11 = g0[(y1 * 7 + x1) * 16];
    float v0 = v00 + (v01 - v00) * wx;
    float v1 = v10 + (v11 - v10) * wx;
    float v = v0 + (v1 - v0) * wy;
    cat[(size_t)pos * 512 + 384 + c] = __float2bfloat16(v);
}

extern "C" void kernel_launch(void* const* d_in, const int* in_sizes, int n_in,
                              void* d_out, int out_size, void* d_ws, size_t ws_size,
                              hipStream_t stream)
{
    const float* x      = (const float*)d_in[0];
    const float* x_e    = (const float*)d_in[1];
    const float* norm_w = (const float*)d_in[2];
    const float* norm_b = (const float*)d_in[3];
    const float* norme_w= (const float*)d_in[4];
    const float* norme_b= (const float*)d_in[5];
    const float* rr1_w  = (const float*)d_in[6];
    const float* rr1_b  = (const float*)d_in[7];
    const float* rr2_w  = (const float*)d_in[8];
    const float* rr2_b  = (const float*)d_in[9];
    const float* rr3_w  = (const float*)d_in[10];
    const float* rr3_b  = (const float*)d_in[11];
    const float* conv_w = (const float*)d_in[12];
    const float* conv_b = (const float*)d_in[13];
    const float* l1_w   = (const float*)d_in[14];
    const float* l1_b   = (const float*)d_in[15];
    const float* l2_w   = (const float*)d_in[16];
    const float* l2_b   = (const float*)d_in[17];
    const float* c1_w   = (const float*)d_in[18];
    const float* c1_b   = (const float*)d_in[19];
    const float* c2_w   = (const float*)d_in[20];
    const float* c2_b   = (const float*)d_in[21];
    const float* fc1_w  = (const float*)d_in[22];
    const float* fc2_w  = (const float*)d_in[23];
    const float* l3_w   = (const float*)d_in[24];
    const float* l3_b   = (const float*)d_in[25];
    const float* kv_w   = (const float*)d_in[26];
    const float* kv_b   = (const float*)d_in[27];
    const float* q_w    = (const float*)d_in[28];
    const float* q_b    = (const float*)d_in[29];
    const float* proj_w = (const float*)d_in[30];
    const float* proj_b = (const float*)d_in[31];
    const float* proje_w= (const float*)d_in[32];
    const float* proje_b= (const float*)d_in[33];

    // ---- workspace: fp32 smalls, bf16 transposed weights, bf16 slabs ----
    float* part   = (float*)d_ws;                 // 16*64*513
    float* attnc  = part   + (size_t)525312;      // 16*256
    float* gs     = attnc  + 4096;                // 16*8*49*16
    float* rxpool = gs     + 100352;              // 784*384
    float* qbuf   = rxpool + 301056;              // 784*128
    bf16* wt      = (bf16*)(qbuf + 100352);
    bf16* rr1_t  = wt;              // 256x256
    bf16* rr2_t  = rr1_t + 65536;   // 256x256 (contiguous after rr1_t -> fused [512][256])
    bf16* rr3_t  = rr2_t + 65536;
    bf16* kv_t   = rr3_t + 65536;
    bf16* l1_t   = kv_t  + 65536;   // 128x256
    bf16* l2_t   = l1_t  + 32768;   // 128x128
    bf16* l3_t   = l2_t  + 16384;   // 128x256
    bf16* proj_t = l3_t  + 32768;   // 256x512
    bf16* proje_t= proj_t + 131072; // 128x512 (contiguous after proj_t -> fused [384][512])
    bf16* xn     = proje_t + 65536;
    bf16* xen    = xn   + (size_t)N_TOK * 256;
    bf16* bufC   = xen  + (size_t)N_TOK * 128;   // rr1 / codin / K|V head-major
    bf16* bufD   = bufC + (size_t)N_TOK * 256;   // rr2pre / rgb|t / attn partials
    bf16* bufE   = bufD + (size_t)N_TOK * 256;   // conv out / co_di
    bf16* cat    = bufE + (size_t)N_TOK * 256;   // [N,512]
    size_t need = (size_t)((char*)(cat + (size_t)N_TOK * 512) - (char*)d_ws);
    if (ws_size < need) return;

    bf16* kbuf = bufC;                       // [B*8][HWSZ][16]
    bf16* vbuf = bufC + (size_t)N_TOK * 128; // [B*8][16][HWSZ] (transposed)

    // attn split partials live in bufD (free during phase 4): 8.26 MB
    float* osplit = (float*)bufD;                          // [128][NSPLIT][64][16]
    float* mlbuf  = osplit + (size_t)128 * NSPLIT * 64 * 16; // [128][NSPLIT][64][2]

    float* xout  = (float*)d_out;
    float* xeout = xout + (size_t)N_TOK * 256;

    const int nthr = 256;
    auto mgrid = [](int M, int N) { return dim3((M / 128) * (N / 128)); };

    // 0. weight prep (one launch)
    {
        WtrPack p;
        const float* srcs[9] = {rr1_w, rr2_w, rr3_w, kv_w, l1_w, l2_w, l3_w, proj_w, proje_w};
        bf16* dsts[9] = {rr1_t, rr2_t, rr3_t, kv_t, l1_t, l2_t, l3_t, proj_t, proje_t};
        int Ks[9] = {256, 256, 256, 256, 256, 128, 256, 512, 512};
        int Ns[9] = {256, 256, 256, 256, 128, 128, 128, 256, 128};
        int off = 0;
        for (int s = 0; s < 9; s++) {
            p.d[s] = {srcs[s], dsts[s], Ks[s], Ns[s], off};
            off += Ks[s] * Ns[s];
        }
        p.total = off;
        wtr_all<<<dim3((off + 255) / 256), dim3(256), 0, stream>>>(p);
    }

    // 1. LayerNorms
    ln_kernel<<<dim3(N_TOK / 4), dim3(nthr), 0, stream>>>(x, norm_w, norm_b, xn, N_TOK, 256);
    ln_kernel<<<dim3(N_TOK / 4), dim3(nthr), 0, stream>>>(x_e, norme_w, norme_b, xen, N_TOK, 128);

    // 2. local_rr -> cat[:, 0:256]   (rr1+rr2 FUSED: one A-pass, N=512)
    gemm_mfma<GF_DUAL, bf16><<<mgrid(N_TOK, 512), dim3(nthr), 0, stream>>>(
        xn, 256, rr1_t, rr1_b, bufC, 256, N_TOK, 256, 512, nullptr, 0, nullptr, nullptr, nullptr,
        bufD, 256, rr2_b, 256);
    dwconv_reg<<<dim3(N_TOK / 32), dim3(nthr), 0, stream>>>(
        bufD, bufE, conv_w, conv_b, conv_w, conv_b, 256);
    gemm_mfma<GF_MUL, bf16><<<mgrid(N_TOK, 256), dim3(nthr), 0, stream>>>(
        bufE, 256, rr3_t, rr3_b, cat, 512, N_TOK, 256, 256, bufC, 256, nullptr, nullptr, nullptr,
        nullptr, 0, nullptr, 0);

    // 3. LocalAttentionRGBT -> cat[:, 256:384]
    gemm_mfma<0, bf16><<<mgrid(N_TOK, 128), dim3(nthr), 0, stream>>>(
        xn, 256, l1_t, l1_b, bufD, 128, N_TOK, 256, 128, nullptr, 0, nullptr, nullptr, nullptr,
        nullptr, 0, nullptr, 0);
    gemm_mfma<0, bf16><<<mgrid(N_TOK, 128), dim3(nthr), 0, stream>>>(
        xen, 128, l2_t, l2_b, bufD + (size_t)N_TOK * 128, 128, N_TOK, 128, 128, nullptr, 0, nullptr, nullptr, nullptr,
        nullptr, 0, nullptr, 0);
    rgbt_k<<<dim3((N_TOK * 128) / nthr), dim3(nthr), 0, stream>>>(
        bufD, bufD + (size_t)N_TOK * 128, bufC, N_TOK * 128);
    dwconv_reg<<<dim3(N_TOK / 32), dim3(nthr), 0, stream>>>(
        bufC, bufE, c1_w, c1_b, c2_w, c2_b, 128);
    cosred_k<<<dim3(BATCH * 16), dim3(nthr), 0, stream>>>(bufE, part);
    mlp_kernel<<<dim3(BATCH), dim3(nthr), 0, stream>>>(part, fc1_w, fc2_w, attnc);
    gemm_mfma<GF_ASCALE, bf16><<<mgrid(N_TOK, 128), dim3(nthr), 0, stream>>>(
        bufE, 256, l3_t, l3_b, cat + 256, 512, N_TOK, 256, 128, nullptr, 0, attnc, nullptr, nullptr,
        nullptr, 0, nullptr, 0);

    // 4. global pooled attention -> cat[:, 384:512]
    gemm_mfma<GF_KVSPLIT, bf16><<<mgrid(N_TOK, 256), dim3(nthr), 0, stream>>>(
        xn, 256, kv_t, kv_b, (bf16*)nullptr, 0, N_TOK, 256, 256, nullptr, 0, nullptr, kbuf, vbuf,
        nullptr, 0, nullptr, 0);
    pool_kernel<<<dim3(BATCH * 49), dim3(384), 0, stream>>>(xn, xen, rxpool);
    gemm_k<<<dim3(((784 + 63) / 64) * 2), dim3(nthr), 0, stream>>>(
        rxpool, 384, q_w, q_b, qbuf, 128, 784, 384, 128);
    attn_mfma<<<dim3(128 * NSPLIT), dim3(nthr), 0, stream>>>(qbuf, kbuf, vbuf, osplit, mlbuf);
    attn_combine<<<dim3(392), dim3(nthr), 0, stream>>>(osplit, mlbuf, gs);
    upsample_kernel<<<dim3((N_TOK * 128) / nthr), dim3(nthr), 0, stream>>>(gs, cat);

    // 5. output projections (proj+proje FUSED: one cat-pass, N=384, fp32 out)
    gemm_mfma<GF_DUAL, float><<<mgrid(N_TOK, 384), dim3(nthr), 0, stream>>>(
        cat, 512, proj_t, proj_b, xout, 256, N_TOK, 512, 384, nullptr, 0, nullptr, nullptr, nullptr,
        xeout, 128, proje_b, 256);
}

// Round 8
// 433.922 us; speedup vs baseline: 1.2316x; 1.0397x over previous
//
#include <hip/hip_runtime.h>
#include <hip/hip_bf16.h>
#include <cstdint>
#include <cstddef>

#define N_TOK 50176      // B*H*W
#define HWSZ  3136       // 56*56
#define BATCH 16

#define GF_MUL     1
#define GF_ASCALE  2
#define GF_KVSPLIT 4
#define GF_DUAL    8

typedef __hip_bfloat16 bf16;
typedef __attribute__((ext_vector_type(8))) short bf16x8;
typedef __attribute__((ext_vector_type(4))) float f32x4;
typedef __attribute__((ext_vector_type(4))) unsigned short u16x4;

__device__ __forceinline__ void  stf(float* p, size_t i, float v) { p[i] = v; }
__device__ __forceinline__ void  stf(bf16* p, size_t i, float v) { p[i] = __float2bfloat16(v); }
__device__ __forceinline__ float bu2f(unsigned short u) {
    unsigned int x = ((unsigned int)u) << 16; float f; __builtin_memcpy(&f, &x, 4); return f;
}
__device__ __forceinline__ unsigned short f2bu(float f) {
    bf16 t = __float2bfloat16(f); unsigned short u; __builtin_memcpy(&u, &t, 2); return u;
}

// ---------------- batched weight prep: W[K][N] fp32 -> WT[N][K] bf16 (9 mats, 1 launch) ----------------
struct WtrDesc { const float* src; bf16* dst; int K; int N; int off; };
struct WtrPack { WtrDesc d[9]; int total; };
__global__ __launch_bounds__(256) void wtr_all(WtrPack p)
{
    int idx = blockIdx.x * 256 + threadIdx.x;
    if (idx >= p.total) return;
    #pragma unroll
    for (int s = 0; s < 9; s++) {
        int lo = p.d[s].off, hi = lo + p.d[s].K * p.d[s].N;
        if (idx >= lo && idx < hi) {
            int j = idx - lo;
            int k = j / p.d[s].N, n = j % p.d[s].N;
            p.d[s].dst[(size_t)n * p.d[s].K + k] = __float2bfloat16(p.d[s].src[j]);
        }
    }
}

// ---------------- LayerNorm: one wave per row (fp32 in -> bf16 out) ----------------
__global__ __launch_bounds__(256) void ln_kernel(const float* __restrict__ in,
    const float* __restrict__ w, const float* __restrict__ b,
    bf16* __restrict__ out, int rows, int Cdim)
{
    int wave = threadIdx.x >> 6, lane = threadIdx.x & 63;
    int row = blockIdx.x * 4 + wave;
    if (row >= rows) return;
    const float* p = in + (size_t)row * Cdim;
    int nj = Cdim >> 6;
    float v[4];
    float s = 0.f;
    for (int j = 0; j < nj; j++) { v[j] = p[lane + 64 * j]; s += v[j]; }
    for (int off = 32; off; off >>= 1) s += __shfl_xor(s, off, 64);
    float mean = s / (float)Cdim;
    float vs = 0.f;
    for (int j = 0; j < nj; j++) { float d = v[j] - mean; vs += d * d; }
    for (int off = 32; off; off >>= 1) vs += __shfl_xor(vs, off, 64);
    float rstd = 1.f / sqrtf(vs / (float)Cdim + 1e-6f);
    bf16* q = out + (size_t)row * Cdim;
    for (int j = 0; j < nj; j++) {
        int c = lane + 64 * j;
        q[c] = __float2bfloat16((v[j] - mean) * rstd * w[c] + b[c]);
    }
}

// ---------------- MFMA GEMM: C = A[M,K](bf16) @ WT[N,K]^T(bf16) + bias ----------------
// 64x128 tile (fine-grained for grid parallelism), BK=32, 256 threads = 4 waves,
// wave w owns 64 rows x 32 cols (acc[4][2]). Software-pipelined staging; XCD-swizzled
// blockIdx (all grids are multiples of 8) so same-m blocks share A via one XCD's L2.
// GF_DUAL: N-range [0,N1) -> C/bias, [N1,N) -> C2/bias2 (fused shared-A GEMMs).
#define LDT 56   // padded LDS K-stride (112B: 16B-aligned, 2-way banks)
template<int FLAGS, typename OT>
__global__ __launch_bounds__(256) void gemm_mfma(
    const bf16* __restrict__ A, int lda,
    const bf16* __restrict__ WT,           // [N][K]
    const float* __restrict__ bias,
    OT* __restrict__ C, int ldc,
    int M, int K, int N,
    const bf16* __restrict__ mul, int mulld,
    const float* __restrict__ ascale,      // [BATCH][K]
    bf16* __restrict__ kout, bf16* __restrict__ vout,
    OT* __restrict__ C2, int ldc2, const float* __restrict__ bias2, int N1)
{
    __shared__ bf16 As[64][LDT];
    __shared__ bf16 Bs[128][LDT];
    int ntile = N >> 7;
    int bid = blockIdx.x;
    bid = (bid & 7) * (gridDim.x >> 3) + (bid >> 3);   // bijective XCD remap (grid%8==0)
    int m0 = (bid / ntile) * 64;
    int n0 = (bid % ntile) * 128;
    int tid = threadIdx.x;
    int lane = tid & 63, wid = tid >> 6;
    int wc = wid * 32;
    int lrow = lane & 15, lko = (lane >> 4) * 8;
    int sr = tid >> 2, sko = (tid & 3) * 8;

    f32x4 acc[4][2];
    #pragma unroll
    for (int i = 0; i < 4; i++)
        #pragma unroll
        for (int j = 0; j < 2; j++)
            acc[i][j] = (f32x4){0.f, 0.f, 0.f, 0.f};

    // prologue: load tile 0 into regs (A: 1 chunk, B: 2 chunks per thread)
    bf16x8 ra, rb[2];
    {
        bf16x8 v = *reinterpret_cast<const bf16x8*>(A + (size_t)(m0 + sr) * lda + sko);
        if (FLAGS & GF_ASCALE) {
            int bidx = (m0 + sr) / HWSZ;
            const float* as = ascale + (size_t)bidx * K + sko;
            #pragma unroll
            for (int e = 0; e < 8; e++)
                v[e] = (short)f2bu(bu2f((unsigned short)v[e]) * as[e]);
        }
        ra = v;
        rb[0] = *reinterpret_cast<const bf16x8*>(WT + (size_t)(n0 + sr) * K + sko);
        rb[1] = *reinterpret_cast<const bf16x8*>(WT + (size_t)(n0 + sr + 64) * K + sko);
    }

    for (int k0 = 0; k0 < K; k0 += 32) {
        *reinterpret_cast<bf16x8*>(&As[sr][sko]) = ra;
        *reinterpret_cast<bf16x8*>(&Bs[sr][sko]) = rb[0];
        *reinterpret_cast<bf16x8*>(&Bs[sr + 64][sko]) = rb[1];
        __syncthreads();
        int kn = k0 + 32;
        if (kn < K) {
            bf16x8 v = *reinterpret_cast<const bf16x8*>(A + (size_t)(m0 + sr) * lda + kn + sko);
            if (FLAGS & GF_ASCALE) {
                int bidx = (m0 + sr) / HWSZ;
                const float* as = ascale + (size_t)bidx * K + kn + sko;
                #pragma unroll
                for (int e = 0; e < 8; e++)
                    v[e] = (short)f2bu(bu2f((unsigned short)v[e]) * as[e]);
            }
            ra = v;
            rb[0] = *reinterpret_cast<const bf16x8*>(WT + (size_t)(n0 + sr) * K + kn + sko);
            rb[1] = *reinterpret_cast<const bf16x8*>(WT + (size_t)(n0 + sr + 64) * K + kn + sko);
        }
        bf16x8 af[4], br[2];
        #pragma unroll
        for (int i = 0; i < 4; i++)
            af[i] = *reinterpret_cast<const bf16x8*>(&As[i * 16 + lrow][lko]);
        #pragma unroll
        for (int j = 0; j < 2; j++)
            br[j] = *reinterpret_cast<const bf16x8*>(&Bs[wc + j * 16 + lrow][lko]);
        #pragma unroll
        for (int i = 0; i < 4; i++)
            #pragma unroll
            for (int j = 0; j < 2; j++)
                acc[i][j] = __builtin_amdgcn_mfma_f32_16x16x32_bf16(af[i], br[j], acc[i][j], 0, 0, 0);
        __syncthreads();
    }

    int orow = (lane >> 4) * 4;
    int ocol = lane & 15;
    #pragma unroll
    for (int i = 0; i < 4; i++) {
        #pragma unroll
        for (int j = 0; j < 2; j++) {
            #pragma unroll
            for (int p = 0; p < 4; p++) {
                int gm = m0 + i * 16 + orow + p;
                int gn = n0 + wc + j * 16 + ocol;
                if (FLAGS & GF_KVSPLIT) {
                    float v = acc[i][j][p] + bias[gn];
                    int bb = gm / HWSZ, n = gm % HWSZ;
                    if (gn < 128)
                        kout[(((size_t)bb * 8 + (gn >> 4)) * HWSZ + n) * 16 + (gn & 15)] = __float2bfloat16(v);
                    else {
                        int hh = (gn - 128) >> 4, dd = (gn - 128) & 15;
                        // V stored TRANSPOSED: [bh][d][pos]
                        vout[(((size_t)bb * 8 + hh) * 16 + dd) * HWSZ + n] = __float2bfloat16(v);
                    }
                } else if (FLAGS & GF_DUAL) {
                    if (gn < N1) {
                        float v = acc[i][j][p] + bias[gn];
                        stf(C, (size_t)gm * ldc + gn, v);
                    } else {
                        float v = acc[i][j][p] + bias2[gn - N1];
                        stf(C2, (size_t)gm * ldc2 + (gn - N1), v);
                    }
                } else {
                    float v = acc[i][j][p] + bias[gn];
                    if (FLAGS & GF_MUL) v *= __bfloat162float(mul[(size_t)gm * mulld + gn]);
                    stf(C, (size_t)gm * ldc + gn, v);
                }
            }
        }
    }
}

// ---------------- fp32 vector GEMM (small q projection only) ----------------
__global__ __launch_bounds__(256) void gemm_k(
    const float* __restrict__ A, int lda,
    const float* __restrict__ Wt, const float* __restrict__ bias,
    float* __restrict__ Cc, int ldc, int M, int K, int Nc)
{
    __shared__ float As[16][68];
    __shared__ float Ws[16][64];
    int ntile = Nc >> 6;
    int tile_n = blockIdx.x % ntile;
    int tile_m = blockIdx.x / ntile;
    int m0 = tile_m * 64, n0 = tile_n * 64;
    int tid = threadIdx.x;
    int tx = tid & 15, ty = tid >> 4;
    float acc[4][4] = {};
    for (int k0 = 0; k0 < K; k0 += 16) {
        int ks = tid & 15, ms = tid >> 4;
        #pragma unroll
        for (int i = 0; i < 4; i++) {
            int gm = m0 + ms + i * 16;
            As[ks][ms + i * 16] = (gm < M) ? A[(size_t)gm * lda + k0 + ks] : 0.f;
        }
        #pragma unroll
        for (int j = 0; j < 4; j++) {
            int k = (tid >> 6) * 4 + j;
            Ws[k][tid & 63] = Wt[(size_t)(k0 + k) * Nc + n0 + (tid & 63)];
        }
        __syncthreads();
        #pragma unroll
        for (int k = 0; k < 16; k++) {
            float a[4], w[4];
            #pragma unroll
            for (int i = 0; i < 4; i++) a[i] = As[k][ty * 4 + i];
            #pragma unroll
            for (int j = 0; j < 4; j++) w[j] = Ws[k][tx * 4 + j];
            #pragma unroll
            for (int i = 0; i < 4; i++)
                #pragma unroll
                for (int j = 0; j < 4; j++)
                    acc[i][j] += a[i] * w[j];
        }
        __syncthreads();
    }
    #pragma unroll
    for (int i = 0; i < 4; i++) {
        int gm = m0 + ty * 4 + i;
        if (gm >= M) continue;
        #pragma unroll
        for (int j = 0; j < 4; j++) {
            int gn = n0 + tx * 4 + j;
            Cc[(size_t)gm * ldc + gn] = acc[i][j] + bias[gn];
        }
    }
}

// ---------------- direct-global depthwise 7x7 conv with x-register reuse ----------------
// Thread: 4 consecutive x positions x 8 channels, one (b,y) row.
// Per ky: load 10 overlapping 16B cells once, convert to f32 once,
// feed all 7 kx taps x 4 outputs from registers.
// Swizzle: grid 1568 = 8 x 196; each XCD gets a contiguous run of 196 blocks
// (= 2 whole batch images) so y-halo re-reads hit its private L2.
__global__ __launch_bounds__(256) void dwconv_reg(const bf16* __restrict__ in,
    bf16* __restrict__ out,
    const float* __restrict__ w0, const float* __restrict__ b0,
    const float* __restrict__ w1, const float* __restrict__ b1, int split)
{
    int tid = threadIdx.x;
    int chg = tid & 31;                      // 8-channel group
    int bsw = (blockIdx.x & 7) * 196 + (blockIdx.x >> 3);  // bijective XCD remap
    int pg  = bsw * 8 + (tid >> 5);          // pos-group = 4 consecutive x
    int xg = pg % 14;
    int y  = (pg / 14) % 56;
    int b  = pg / (14 * 56);
    int c0 = chg * 8;
    int x0 = xg * 4;

    const float* wp; const float* bp; int ws, cw;
    if (c0 < split) { wp = w0; bp = b0; ws = split;       cw = c0; }
    else            { wp = w1; bp = b1; ws = 256 - split; cw = c0 - split; }

    float acc[4][8];
    #pragma unroll
    for (int o = 0; o < 4; o++)
        #pragma unroll
        for (int e = 0; e < 8; e++) acc[o][e] = 0.f;

    const bf16* base = in + (size_t)b * HWSZ * 256 + c0;
    const float* wbase = wp + cw;
    #pragma unroll
    for (int ky = 0; ky < 7; ky++) {
        int gy = y + ky - 3;
        if (gy < 0 || gy >= 56) continue;
        const bf16* rowp = base + (size_t)gy * 56 * 256;
        float cf[10][8];
        #pragma unroll
        for (int j = 0; j < 10; j++) {
            int gx = x0 + j - 3;
            bf16x8 v = {0, 0, 0, 0, 0, 0, 0, 0};
            if ((unsigned)gx < 56u)
                v = *reinterpret_cast<const bf16x8*>(rowp + (size_t)gx * 256);
            #pragma unroll
            for (int e = 0; e < 8; e++) cf[j][e] = bu2f((unsigned short)v[e]);
        }
        const float* wrow = wbase + ky * 7 * ws;
        #pragma unroll
        for (int kx = 0; kx < 7; kx++) {
            float4 wa = *reinterpret_cast<const float4*>(wrow + kx * ws);
            float4 wb = *reinterpret_cast<const float4*>(wrow + kx * ws + 4);
            #pragma unroll
            for (int o = 0; o < 4; o++) {
                acc[o][0] += cf[o + kx][0] * wa.x;
                acc[o][1] += cf[o + kx][1] * wa.y;
                acc[o][2] += cf[o + kx][2] * wa.z;
                acc[o][3] += cf[o + kx][3] * wa.w;
                acc[o][4] += cf[o + kx][4] * wb.x;
                acc[o][5] += cf[o + kx][5] * wb.y;
                acc[o][6] += cf[o + kx][6] * wb.z;
                acc[o][7] += cf[o + kx][7] * wb.w;
            }
        }
    }

    float4 ba = *reinterpret_cast<const float4*>(bp + cw);
    float4 bb = *reinterpret_cast<const float4*>(bp + cw + 4);
    bf16* obase = out + (((size_t)b * HWSZ + (size_t)y * 56 + x0) * 256) + c0;
    #pragma unroll
    for (int o = 0; o < 4; o++) {
        bf16x8 ov;
        ov[0] = (short)f2bu(acc[o][0] + ba.x);
        ov[1] = (short)f2bu(acc[o][1] + ba.y);
        ov[2] = (short)f2bu(acc[o][2] + ba.z);
        ov[3] = (short)f2bu(acc[o][3] + ba.w);
        ov[4] = (short)f2bu(acc[o][4] + bb.x);
        ov[5] = (short)f2bu(acc[o][5] + bb.y);
        ov[6] = (short)f2bu(acc[o][6] + bb.z);
        ov[7] = (short)f2bu(acc[o][7] + bb.w);
        *reinterpret_cast<bf16x8*>(obase + (size_t)o * 256) = ov;
    }
}

// ---------------- rgb/t elementwise -> codin[N,256] ----------------
__global__ void rgbt_k(const bf16* __restrict__ rgb, const bf16* __restrict__ t,
                       bf16* __restrict__ codin, int total /* N*128 */)
{
    int i = blockIdx.x * blockDim.x + threadIdx.x;
    if (i >= total) return;
    int n = i >> 7, c = i & 127;
    float a = __bfloat162float(rgb[i]), bb = __bfloat162float(t[i]);
    codin[(size_t)n * 256 + c] = __float2bfloat16(a * bb);
    codin[(size_t)n * 256 + 128 + c] = __float2bfloat16(fabsf(a - bb));
}

// ---------------- cosine-gate partial reductions ----------------
__global__ __launch_bounds__(256) void cosred_k(const bf16* __restrict__ codi,
    float* __restrict__ part)   // [B][64][513]
{
    int b = blockIdx.x >> 4;
    int bi = blockIdx.x & 15;
    int wave = threadIdx.x >> 6, lane = threadIdx.x & 63;
    int slot = bi * 4 + wave;
    float dloc[4] = {0,0,0,0}, n2loc[4] = {0,0,0,0};
    float n1loc = 0.f;
    for (int i = 0; i < 49; i++) {
        int p = slot * 49 + i;
        const bf16* row = codi + ((size_t)b * HWSZ + p) * 256;
        float v[4]; float sum = 0.f;
        #pragma unroll
        for (int j = 0; j < 4; j++) { v[j] = __bfloat162float(row[lane + 64 * j]); sum += v[j]; }
        for (int off = 32; off; off >>= 1) sum += __shfl_xor(sum, off, 64);
        float amap = sum * (1.f / 256.f);
        #pragma unroll
        for (int j = 0; j < 4; j++) { dloc[j] += amap * v[j]; n2loc[j] += v[j] * v[j]; }
        n1loc += amap * amap;
    }
    float* dst = part + ((size_t)b * 64 + slot) * 513;
    #pragma unroll
    for (int j = 0; j < 4; j++) {
        dst[lane + 64 * j] = dloc[j];
        dst[256 + lane + 64 * j] = n2loc[j];
    }
    if (lane == 0) dst[512] = n1loc;
}

// ---------------- cos_sim + MLP + sigmoid -> attn_c[B,256] fp32 ----------------
__global__ __launch_bounds__(256) void mlp_kernel(const float* __restrict__ part,
    const float* __restrict__ fc1w, const float* __restrict__ fc2w,
    float* __restrict__ attnc)
{
    int b = blockIdx.x;
    int tid = threadIdx.x;
    __shared__ float cosb[256];
    __shared__ float hbuf[32];
    const float* pb = part + (size_t)b * 64 * 513;
    float dot = 0.f, n2 = 0.f, n1 = 0.f;
    for (int s = 0; s < 64; s++) {
        dot += pb[s * 513 + tid];
        n2  += pb[s * 513 + 256 + tid];
        n1  += pb[s * 513 + 512];
    }
    float cs = dot / (sqrtf(n1) * sqrtf(n2) + 1e-6f);
    cosb[tid] = cs;
    __syncthreads();
    if (tid < 32) {
        float h = 0.f;
        for (int c = 0; c < 256; c++) h += cosb[c] * fc1w[c * 32 + tid];
        h = 0.5f * h * (1.f + erff(h * 0.70710678f));
        hbuf[tid] = h;
    }
    __syncthreads();
    float o = 0.f;
    for (int j = 0; j < 32; j++) o += hbuf[j] * fc2w[j * 256 + tid];
    attnc[b * 256 + tid] = 1.f / (1.f + expf(-o));
}

// ---------------- 8x8 mean-pool of concat(xn, xen) -> rx_pool[B,49,384] fp32 ----------------
__global__ __launch_bounds__(384) void pool_kernel(const bf16* __restrict__ xn,
    const bf16* __restrict__ xen, float* __restrict__ rxpool)
{
    int bij = blockIdx.x;
    int b = bij / 49; int ij = bij % 49; int i = ij / 7, j = ij % 7;
    int c = threadIdx.x;
    float s = 0.f;
    for (int dy = 0; dy < 8; dy++)
        for (int dx = 0; dx < 8; dx++) {
            size_t n = ((size_t)b * 56 + (i * 8 + dy)) * 56 + (j * 8 + dx);
            s += (c < 256) ? __bfloat162float(xn[n * 256 + c])
                           : __bfloat162float(xen[n * 128 + (c - 256)]);
        }
    rxpool[(size_t)bij * 384 + c] = s * (1.f / 64.f);
}

// ---------------- MFMA flash attention over pooled q ----------------
#define NSPLIT 14
#define POSB   224   // 3136/14, multiple of 32
__global__ __launch_bounds__(256) void attn_mfma(const float* __restrict__ qbuf,
    const bf16* __restrict__ kbuf, const bf16* __restrict__ vtbuf,
    float* __restrict__ osplit, float* __restrict__ mlbuf)
{
    int bh = blockIdx.x & 127;
    int split = blockIdx.x >> 7;
    int b = bh >> 3, h = bh & 7;
    int tid = threadIdx.x;
    int qt = tid >> 6;
    int lane = tid & 63;
    int lo = lane & 15, hi = lane >> 4;

    bf16x8 qf = {0, 0, 0, 0, 0, 0, 0, 0};
    int q = qt * 16 + lo;
    if (hi < 2 && q < 49) {
        const float* qp = qbuf + ((size_t)b * 49 + q) * 128 + h * 16 + hi * 8;
        #pragma unroll
        for (int j = 0; j < 8; j++) qf[j] = (short)f2bu(qp[j] * 0.25f);
    }
    const bf16* kbase = kbuf + (size_t)bh * HWSZ * 16;
    const bf16* vbase = vtbuf + ((size_t)bh * 16 + lo) * HWSZ;

    float m_run = -1e30f, l_run = 0.f;
    f32x4 oacc = {0.f, 0.f, 0.f, 0.f};
    int pos1 = 8 * (lo >> 2) + (lo & 3);
    const f32x4 zz = {0.f, 0.f, 0.f, 0.f};

    for (int t = 0; t < POSB / 32; t++) {
        int base = split * POSB + t * 32;
        bf16x8 kf1 = {0, 0, 0, 0, 0, 0, 0, 0}, kf2 = kf1;
        if (hi < 2) {
            kf1 = *reinterpret_cast<const bf16x8*>(kbase + (size_t)(base + pos1) * 16 + hi * 8);
            kf2 = *reinterpret_cast<const bf16x8*>(kbase + (size_t)(base + pos1 + 4) * 16 + hi * 8);
        }
        bf16x8 vf = *reinterpret_cast<const bf16x8*>(vbase + base + hi * 8);
        f32x4 s1 = __builtin_amdgcn_mfma_f32_16x16x32_bf16(kf1, qf, zz, 0, 0, 0);
        f32x4 s2 = __builtin_amdgcn_mfma_f32_16x16x32_bf16(kf2, qf, zz, 0, 0, 0);
        float pmax = fmaxf(fmaxf(fmaxf(s1[0], s1[1]), fmaxf(s1[2], s1[3])),
                           fmaxf(fmaxf(s2[0], s2[1]), fmaxf(s2[2], s2[3])));
        pmax = fmaxf(pmax, __shfl_xor(pmax, 16, 64));
        pmax = fmaxf(pmax, __shfl_xor(pmax, 32, 64));
        float mnew = fmaxf(m_run, pmax);
        float esc = __expf(m_run - mnew);
        l_run *= esc;
        float e0 = __shfl(esc, 4 * hi + 0, 64);
        float e1 = __shfl(esc, 4 * hi + 1, 64);
        float e2 = __shfl(esc, 4 * hi + 2, 64);
        float e3 = __shfl(esc, 4 * hi + 3, 64);
        oacc[0] *= e0; oacc[1] *= e1; oacc[2] *= e2; oacc[3] *= e3;
        float p0 = __expf(s1[0] - mnew), p1 = __expf(s1[1] - mnew);
        float p2 = __expf(s1[2] - mnew), p3 = __expf(s1[3] - mnew);
        float p4 = __expf(s2[0] - mnew), p5 = __expf(s2[1] - mnew);
        float p6 = __expf(s2[2] - mnew), p7 = __expf(s2[3] - mnew);
        float rs = ((p0 + p1) + (p2 + p3)) + ((p4 + p5) + (p6 + p7));
        rs += __shfl_xor(rs, 16, 64);
        rs += __shfl_xor(rs, 32, 64);
        l_run += rs;
        m_run = mnew;
        bf16x8 pf;
        pf[0] = (short)f2bu(p0); pf[1] = (short)f2bu(p1);
        pf[2] = (short)f2bu(p2); pf[3] = (short)f2bu(p3);
        pf[4] = (short)f2bu(p4); pf[5] = (short)f2bu(p5);
        pf[6] = (short)f2bu(p6); pf[7] = (short)f2bu(p7);
        oacc = __builtin_amdgcn_mfma_f32_16x16x32_bf16(pf, vf, oacc, 0, 0, 0);
    }

    float* ob = osplit + ((size_t)bh * NSPLIT + split) * 64 * 16;
    #pragma unroll
    for (int r = 0; r < 4; r++) {
        int qq = qt * 16 + 4 * hi + r;
        ob[(size_t)qq * 16 + lo] = oacc[r];
    }
    if (hi == 0) {
        float* mlb = mlbuf + (((size_t)bh * NSPLIT + split) * 64 + qt * 16 + lo) * 2;
        mlb[0] = m_run; mlb[1] = l_run;
    }
}

// ---------------- merge split partials -> gs[bh][49][16] ----------------
__global__ __launch_bounds__(256) void attn_combine(const float* __restrict__ osplit,
    const float* __restrict__ mlbuf, float* __restrict__ gs)
{
    int idx = blockIdx.x * 256 + threadIdx.x;   // over 128*49*16
    if (idx >= 128 * 49 * 16) return;
    int d = idx & 15;
    int pq = idx >> 4;
    int bh = pq / 49, q = pq % 49;
    float m[NSPLIT], l[NSPLIT];
    float M = -1e30f;
    #pragma unroll
    for (int s = 0; s < NSPLIT; s++) {
        const float* mlb = mlbuf + (((size_t)bh * NSPLIT + s) * 64 + q) * 2;
        m[s] = mlb[0]; l[s] = mlb[1];
        M = fmaxf(M, m[s]);
    }
    float L = 0.f, O = 0.f;
    #pragma unroll
    for (int s = 0; s < NSPLIT; s++) {
        float e = __expf(m[s] - M);
        L += l[s] * e;
        O += osplit[(((size_t)bh * NSPLIT + s) * 64 + q) * 16 + d] * e;
    }
    gs[(size_t)pq * 16 + d] = O / L;
}

// ---------------- bilinear 7->56 upsample into cat[:, 384:512] ----------------
__global__ void upsample_kernel(const float* __restrict__ gs, bf16* __restrict__ cat)
{
    int idx = blockIdx.x * blockDim.x + threadIdx.x;  // over N*128
    if (idx >= N_TOK * 128) return;
    int c = idx & 127;
    int pos = idx >> 7;
    int h = c >> 4, d = c & 15;
    int x = pos % 56;
    int y = (pos / 56) % 56;
    int b = pos / HWSZ;
    float sy = (y + 0.5f) * 0.125f - 0.5f;
    float sx = (x + 0.5f) * 0.125f - 0.5f;
    int y0f = (int)floorf(sy); float wy = sy - (float)y0f;
    int x0f = (int)floorf(sx); float wx = sx - (float)x0f;
    int y0 = max(0, min(6, y0f)), y1 = max(0, min(6, y0f + 1));
    int x0 = max(0, min(6, x0f)), x1 = max(0, min(6, x0f + 1));
    const float* g0 = gs + ((size_t)(b * 8 + h) * 49) * 16 + d;
    float v00 = g0[(y0 * 7 + x0) * 16], v01 = g0[(y0 * 7 + x1) * 16];
    float v10 = g0[(y1 * 7 + x0) * 16], v11 = g0[(y1 * 7 + x1) * 16];
    float v0 = v00 + (v01 - v00) * wx;
    float v1 = v10 + (v11 - v10) * wx;
    float v = v0 + (v1 - v0) * wy;
    cat[(size_t)pos * 512 + 384 + c] = __float2bfloat16(v);
}

extern "C" void kernel_launch(void* const* d_in, const int* in_sizes, int n_in,
                              void* d_out, int out_size, void* d_ws, size_t ws_size,
                              hipStream_t stream)
{
    const float* x      = (const float*)d_in[0];
    const float* x_e    = (const float*)d_in[1];
    const float* norm_w = (const float*)d_in[2];
    const float* norm_b = (const float*)d_in[3];
    const float* norme_w= (const float*)d_in[4];
    const float* norme_b= (const float*)d_in[5];
    const float* rr1_w  = (const float*)d_in[6];
    const float* rr1_b  = (const float*)d_in[7];
    const float* rr2_w  = (const float*)d_in[8];
    const float* rr2_b  = (const float*)d_in[9];
    const float* rr3_w  = (const float*)d_in[10];
    const float* rr3_b  = (const float*)d_in[11];
    const float* conv_w = (const float*)d_in[12];
    const float* conv_b = (const float*)d_in[13];
    const float* l1_w   = (const float*)d_in[14];
    const float* l1_b   = (const float*)d_in[15];
    const float* l2_w   = (const float*)d_in[16];
    const float* l2_b   = (const float*)d_in[17];
    const float* c1_w   = (const float*)d_in[18];
    const float* c1_b   = (const float*)d_in[19];
    const float* c2_w   = (const float*)d_in[20];
    const float* c2_b   = (const float*)d_in[21];
    const float* fc1_w  = (const float*)d_in[22];
    const float* fc2_w  = (const float*)d_in[23];
    const float* l3_w   = (const float*)d_in[24];
    const float* l3_b   = (const float*)d_in[25];
    const float* kv_w   = (const float*)d_in[26];
    const float* kv_b   = (const float*)d_in[27];
    const float* q_w    = (const float*)d_in[28];
    const float* q_b    = (const float*)d_in[29];
    const float* proj_w = (const float*)d_in[30];
    const float* proj_b = (const float*)d_in[31];
    const float* proje_w= (const float*)d_in[32];
    const float* proje_b= (const float*)d_in[33];

    // ---- workspace: fp32 smalls, bf16 transposed weights, bf16 slabs ----
    float* part   = (float*)d_ws;                 // 16*64*513
    float* attnc  = part   + (size_t)525312;      // 16*256
    float* gs     = attnc  + 4096;                // 16*8*49*16
    float* rxpool = gs     + 100352;              // 784*384
    float* qbuf   = rxpool + 301056;              // 784*128
    bf16* wt      = (bf16*)(qbuf + 100352);
    bf16* rr1_t  = wt;              // 256x256
    bf16* rr2_t  = rr1_t + 65536;   // 256x256 (contiguous after rr1_t -> fused [512][256])
    bf16* rr3_t  = rr2_t + 65536;
    bf16* kv_t   = rr3_t + 65536;
    bf16* l1_t   = kv_t  + 65536;   // 128x256
    bf16* l2_t   = l1_t  + 32768;   // 128x128
    bf16* l3_t   = l2_t  + 16384;   // 128x256
    bf16* proj_t = l3_t  + 32768;   // 256x512
    bf16* proje_t= proj_t + 131072; // 128x512 (contiguous after proj_t -> fused [384][512])
    bf16* xn     = proje_t + 65536;
    bf16* xen    = xn   + (size_t)N_TOK * 256;
    bf16* bufC   = xen  + (size_t)N_TOK * 128;   // rr1 / codin / K|V head-major
    bf16* bufD   = bufC + (size_t)N_TOK * 256;   // rr2pre / rgb|t / attn partials
    bf16* bufE   = bufD + (size_t)N_TOK * 256;   // conv out / co_di
    bf16* cat    = bufE + (size_t)N_TOK * 256;   // [N,512]
    size_t need = (size_t)((char*)(cat + (size_t)N_TOK * 512) - (char*)d_ws);
    if (ws_size < need) return;

    bf16* kbuf = bufC;                       // [B*8][HWSZ][16]
    bf16* vbuf = bufC + (size_t)N_TOK * 128; // [B*8][16][HWSZ] (transposed)

    // attn split partials live in bufD (free during phase 4): 8.26 MB
    float* osplit = (float*)bufD;                          // [128][NSPLIT][64][16]
    float* mlbuf  = osplit + (size_t)128 * NSPLIT * 64 * 16; // [128][NSPLIT][64][2]

    float* xout  = (float*)d_out;
    float* xeout = xout + (size_t)N_TOK * 256;

    const int nthr = 256;
    auto mgrid = [](int M, int N) { return dim3((M / 64) * (N / 128)); };

    // 0. weight prep (one launch)
    {
        WtrPack p;
        const float* srcs[9] = {rr1_w, rr2_w, rr3_w, kv_w, l1_w, l2_w, l3_w, proj_w, proje_w};
        bf16* dsts[9] = {rr1_t, rr2_t, rr3_t, kv_t, l1_t, l2_t, l3_t, proj_t, proje_t};
        int Ks[9] = {256, 256, 256, 256, 256, 128, 256, 512, 512};
        int Ns[9] = {256, 256, 256, 256, 128, 128, 128, 256, 128};
        int off = 0;
        for (int s = 0; s < 9; s++) {
            p.d[s] = {srcs[s], dsts[s], Ks[s], Ns[s], off};
            off += Ks[s] * Ns[s];
        }
        p.total = off;
        wtr_all<<<dim3((off + 255) / 256), dim3(256), 0, stream>>>(p);
    }

    // 1. LayerNorms
    ln_kernel<<<dim3(N_TOK / 4), dim3(nthr), 0, stream>>>(x, norm_w, norm_b, xn, N_TOK, 256);
    ln_kernel<<<dim3(N_TOK / 4), dim3(nthr), 0, stream>>>(x_e, norme_w, norme_b, xen, N_TOK, 128);

    // 2. local_rr -> cat[:, 0:256]   (rr1+rr2 FUSED: one A-pass, N=512)
    gemm_mfma<GF_DUAL, bf16><<<mgrid(N_TOK, 512), dim3(nthr), 0, stream>>>(
        xn, 256, rr1_t, rr1_b, bufC, 256, N_TOK, 256, 512, nullptr, 0, nullptr, nullptr, nullptr,
        bufD, 256, rr2_b, 256);
    dwconv_reg<<<dim3(N_TOK / 32), dim3(nthr), 0, stream>>>(
        bufD, bufE, conv_w, conv_b, conv_w, conv_b, 256);
    gemm_mfma<GF_MUL, bf16><<<mgrid(N_TOK, 256), dim3(nthr), 0, stream>>>(
        bufE, 256, rr3_t, rr3_b, cat, 512, N_TOK, 256, 256, bufC, 256, nullptr, nullptr, nullptr,
        nullptr, 0, nullptr, 0);

    // 3. LocalAttentionRGBT -> cat[:, 256:384]
    gemm_mfma<0, bf16><<<mgrid(N_TOK, 128), dim3(nthr), 0, stream>>>(
        xn, 256, l1_t, l1_b, bufD, 128, N_TOK, 256, 128, nullptr, 0, nullptr, nullptr, nullptr,
        nullptr, 0, nullptr, 0);
    gemm_mfma<0, bf16><<<mgrid(N_TOK, 128), dim3(nthr), 0, stream>>>(
        xen, 128, l2_t, l2_b, bufD + (size_t)N_TOK * 128, 128, N_TOK, 128, 128, nullptr, 0, nullptr, nullptr, nullptr,
        nullptr, 0, nullptr, 0);
    rgbt_k<<<dim3((N_TOK * 128) / nthr), dim3(nthr), 0, stream>>>(
        bufD, bufD + (size_t)N_TOK * 128, bufC, N_TOK * 128);
    dwconv_reg<<<dim3(N_TOK / 32), dim3(nthr), 0, stream>>>(
        bufC, bufE, c1_w, c1_b, c2_w, c2_b, 128);
    cosred_k<<<dim3(BATCH * 16), dim3(nthr), 0, stream>>>(bufE, part);
    mlp_kernel<<<dim3(BATCH), dim3(nthr), 0, stream>>>(part, fc1_w, fc2_w, attnc);
    gemm_mfma<GF_ASCALE, bf16><<<mgrid(N_TOK, 128), dim3(nthr), 0, stream>>>(
        bufE, 256, l3_t, l3_b, cat + 256, 512, N_TOK, 256, 128, nullptr, 0, attnc, nullptr, nullptr,
        nullptr, 0, nullptr, 0);

    // 4. global pooled attention -> cat[:, 384:512]
    gemm_mfma<GF_KVSPLIT, bf16><<<mgrid(N_TOK, 256), dim3(nthr), 0, stream>>>(
        xn, 256, kv_t, kv_b, (bf16*)nullptr, 0, N_TOK, 256, 256, nullptr, 0, nullptr, kbuf, vbuf,
        nullptr, 0, nullptr, 0);
    pool_kernel<<<dim3(BATCH * 49), dim3(384), 0, stream>>>(xn, xen, rxpool);
    gemm_k<<<dim3(((784 + 63) / 64) * 2), dim3(nthr), 0, stream>>>(
        rxpool, 384, q_w, q_b, qbuf, 128, 784, 384, 128);
    attn_mfma<<<dim3(128 * NSPLIT), dim3(nthr), 0, stream>>>(qbuf, kbuf, vbuf, osplit, mlbuf);
    attn_combine<<<dim3(392), dim3(nthr), 0, stream>>>(osplit, mlbuf, gs);
    upsample_kernel<<<dim3((N_TOK * 128) / nthr), dim3(nthr), 0, stream>>>(gs, cat);

    // 5. output projections (proj+proje FUSED: one cat-pass, N=384, fp32 out)
    gemm_mfma<GF_DUAL, float><<<mgrid(N_TOK, 384), dim3(nthr), 0, stream>>>(
        cat, 512, proj_t, proj_b, xout, 256, N_TOK, 512, 384, nullptr, 0, nullptr, nullptr, nullptr,
        xeout, 128, proje_b, 256);
}

// Round 9
// 428.098 us; speedup vs baseline: 1.2483x; 1.0136x over previous
//
#include <hip/hip_runtime.h>
#include <hip/hip_bf16.h>
#include <cstdint>
#include <cstddef>

#define N_TOK 50176      // B*H*W
#define HWSZ  3136       // 56*56
#define BATCH 16

#define GF_MUL     1
#define GF_ASCALE  2
#define GF_KVSPLIT 4
#define GF_DUAL    8

typedef __hip_bfloat16 bf16;
typedef __attribute__((ext_vector_type(8))) short bf16x8;
typedef __attribute__((ext_vector_type(4))) float f32x4;
typedef __attribute__((ext_vector_type(4))) unsigned short u16x4;

__device__ __forceinline__ void  stf(float* p, size_t i, float v) { p[i] = v; }
__device__ __forceinline__ void  stf(bf16* p, size_t i, float v) { p[i] = __float2bfloat16(v); }
__device__ __forceinline__ float bu2f(unsigned short u) {
    unsigned int x = ((unsigned int)u) << 16; float f; __builtin_memcpy(&f, &x, 4); return f;
}
__device__ __forceinline__ unsigned short f2bu(float f) {
    bf16 t = __float2bfloat16(f); unsigned short u; __builtin_memcpy(&u, &t, 2); return u;
}

// ---------------- batched weight prep: W[K][N] fp32 -> WT[N][K] bf16 (9 mats, 1 launch) ----------------
struct WtrDesc { const float* src; bf16* dst; int K; int N; int off; };
struct WtrPack { WtrDesc d[9]; int total; };
__global__ __launch_bounds__(256) void wtr_all(WtrPack p)
{
    int idx = blockIdx.x * 256 + threadIdx.x;
    if (idx >= p.total) return;
    #pragma unroll
    for (int s = 0; s < 9; s++) {
        int lo = p.d[s].off, hi = lo + p.d[s].K * p.d[s].N;
        if (idx >= lo && idx < hi) {
            int j = idx - lo;
            int k = j / p.d[s].N, n = j % p.d[s].N;
            p.d[s].dst[(size_t)n * p.d[s].K + k] = __float2bfloat16(p.d[s].src[j]);
        }
    }
}

// ---------------- LayerNorm: one wave per row (fp32 in -> bf16 out) ----------------
__global__ __launch_bounds__(256) void ln_kernel(const float* __restrict__ in,
    const float* __restrict__ w, const float* __restrict__ b,
    bf16* __restrict__ out, int rows, int Cdim)
{
    int wave = threadIdx.x >> 6, lane = threadIdx.x & 63;
    int row = blockIdx.x * 4 + wave;
    if (row >= rows) return;
    const float* p = in + (size_t)row * Cdim;
    int nj = Cdim >> 6;
    float v[4];
    float s = 0.f;
    for (int j = 0; j < nj; j++) { v[j] = p[lane + 64 * j]; s += v[j]; }
    for (int off = 32; off; off >>= 1) s += __shfl_xor(s, off, 64);
    float mean = s / (float)Cdim;
    float vs = 0.f;
    for (int j = 0; j < nj; j++) { float d = v[j] - mean; vs += d * d; }
    for (int off = 32; off; off >>= 1) vs += __shfl_xor(vs, off, 64);
    float rstd = 1.f / sqrtf(vs / (float)Cdim + 1e-6f);
    bf16* q = out + (size_t)row * Cdim;
    for (int j = 0; j < nj; j++) {
        int c = lane + 64 * j;
        q[c] = __float2bfloat16((v[j] - mean) * rstd * w[c] + b[c]);
    }
}

// ---------------- MFMA GEMM: C = A[M,K](bf16) @ WT[N,K]^T(bf16) + bias ----------------
// 64x128 tile, BK=32, 256 threads = 4 waves, wave w owns 64 rows x 32 cols (acc[4][2]).
// 2-deep double-buffered pipeline (loads for step k+2 issued while step k computes),
// ONE barrier per phase (dbuf epoch argument makes WAR safe). LDT=40 (80B stride =
// 20 banks): write/read bank patterns exactly uniform -> ~zero conflicts.
// XCD-swizzled blockIdx (all grids multiples of 8). GF_DUAL: split-N epilogue.
#define LDT 40
template<int FLAGS, typename OT>
__global__ __launch_bounds__(256) void gemm_mfma(
    const bf16* __restrict__ A, int lda,
    const bf16* __restrict__ WT,           // [N][K]
    const float* __restrict__ bias,
    OT* __restrict__ C, int ldc,
    int M, int K, int N,
    const bf16* __restrict__ mul, int mulld,
    const float* __restrict__ ascale,      // [BATCH][K]
    bf16* __restrict__ kout, bf16* __restrict__ vout,
    OT* __restrict__ C2, int ldc2, const float* __restrict__ bias2, int N1)
{
    __shared__ bf16 As[2][64][LDT];
    __shared__ bf16 Bs[2][128][LDT];
    int ntile = N >> 7;
    int bid = blockIdx.x;
    bid = (bid & 7) * (gridDim.x >> 3) + (bid >> 3);   // bijective XCD remap (grid%8==0)
    int m0 = (bid / ntile) * 64;
    int n0 = (bid % ntile) * 128;
    int tid = threadIdx.x;
    int lane = tid & 63, wid = tid >> 6;
    int wc = wid * 32;
    int lrow = lane & 15, lko = (lane >> 4) * 8;
    int sr = tid >> 2, sko = (tid & 3) * 8;

    f32x4 acc[4][2];
    #pragma unroll
    for (int i = 0; i < 4; i++)
        #pragma unroll
        for (int j = 0; j < 2; j++)
            acc[i][j] = (f32x4){0.f, 0.f, 0.f, 0.f};

#define GLOAD(RA, RB0, RB1, KOFF) do {                                                        \
    bf16x8 v_ = *reinterpret_cast<const bf16x8*>(A + (size_t)(m0 + sr) * lda + (KOFF) + sko); \
    if (FLAGS & GF_ASCALE) {                                                                  \
        int bidx_ = (m0 + sr) / HWSZ;                                                         \
        const float* as_ = ascale + (size_t)bidx_ * K + (KOFF) + sko;                         \
        for (int e_ = 0; e_ < 8; e_++)                                                        \
            v_[e_] = (short)f2bu(bu2f((unsigned short)v_[e_]) * as_[e_]);                     \
    }                                                                                         \
    RA = v_;                                                                                  \
    RB0 = *reinterpret_cast<const bf16x8*>(WT + (size_t)(n0 + sr) * K + (KOFF) + sko);        \
    RB1 = *reinterpret_cast<const bf16x8*>(WT + (size_t)(n0 + sr + 64) * K + (KOFF) + sko);   \
} while (0)

#define GWRITE(P, RA, RB0, RB1) do {                                   \
    *reinterpret_cast<bf16x8*>(&As[P][sr][sko]) = RA;                  \
    *reinterpret_cast<bf16x8*>(&Bs[P][sr][sko]) = RB0;                 \
    *reinterpret_cast<bf16x8*>(&Bs[P][sr + 64][sko]) = RB1;            \
} while (0)

#define GCOMP(P) do {                                                                         \
    bf16x8 af_[4], br_[2];                                                                    \
    for (int i_ = 0; i_ < 4; i_++)                                                            \
        af_[i_] = *reinterpret_cast<const bf16x8*>(&As[P][i_ * 16 + lrow][lko]);              \
    for (int j_ = 0; j_ < 2; j_++)                                                            \
        br_[j_] = *reinterpret_cast<const bf16x8*>(&Bs[P][wc + j_ * 16 + lrow][lko]);         \
    for (int i_ = 0; i_ < 4; i_++)                                                            \
        for (int j_ = 0; j_ < 2; j_++)                                                        \
            acc[i_][j_] = __builtin_amdgcn_mfma_f32_16x16x32_bf16(af_[i_], br_[j_], acc[i_][j_], 0, 0, 0); \
} while (0)

    // prologue: 2 tile-steps in flight (K is always a multiple of 64 -> nst even)
    bf16x8 ra0, rb00, rb01, ra1, rb10, rb11;
    GLOAD(ra0, rb00, rb01, 0);
    GLOAD(ra1, rb10, rb11, 32);
    int nst = K >> 5;
    for (int s = 0; s < nst; s += 2) {
        // phase 0
        GWRITE(0, ra0, rb00, rb01);
        if (s + 2 < nst) GLOAD(ra0, rb00, rb01, (s + 2) * 32);
        __syncthreads();
        GCOMP(0);
        // phase 1
        GWRITE(1, ra1, rb10, rb11);
        if (s + 3 < nst) GLOAD(ra1, rb10, rb11, (s + 3) * 32);
        __syncthreads();
        GCOMP(1);
    }
#undef GLOAD
#undef GWRITE
#undef GCOMP

    int orow = (lane >> 4) * 4;
    int ocol = lane & 15;
    #pragma unroll
    for (int i = 0; i < 4; i++) {
        #pragma unroll
        for (int j = 0; j < 2; j++) {
            #pragma unroll
            for (int p = 0; p < 4; p++) {
                int gm = m0 + i * 16 + orow + p;
                int gn = n0 + wc + j * 16 + ocol;
                if (FLAGS & GF_KVSPLIT) {
                    float v = acc[i][j][p] + bias[gn];
                    int bb = gm / HWSZ, n = gm % HWSZ;
                    if (gn < 128)
                        kout[(((size_t)bb * 8 + (gn >> 4)) * HWSZ + n) * 16 + (gn & 15)] = __float2bfloat16(v);
                    else {
                        int hh = (gn - 128) >> 4, dd = (gn - 128) & 15;
                        // V stored TRANSPOSED: [bh][d][pos]
                        vout[(((size_t)bb * 8 + hh) * 16 + dd) * HWSZ + n] = __float2bfloat16(v);
                    }
                } else if (FLAGS & GF_DUAL) {
                    if (gn < N1) {
                        float v = acc[i][j][p] + bias[gn];
                        stf(C, (size_t)gm * ldc + gn, v);
                    } else {
                        float v = acc[i][j][p] + bias2[gn - N1];
                        stf(C2, (size_t)gm * ldc2 + (gn - N1), v);
                    }
                } else {
                    float v = acc[i][j][p] + bias[gn];
                    if (FLAGS & GF_MUL) v *= __bfloat162float(mul[(size_t)gm * mulld + gn]);
                    stf(C, (size_t)gm * ldc + gn, v);
                }
            }
        }
    }
}

// ---------------- fp32 vector GEMM (small q projection only) ----------------
__global__ __launch_bounds__(256) void gemm_k(
    const float* __restrict__ A, int lda,
    const float* __restrict__ Wt, const float* __restrict__ bias,
    float* __restrict__ Cc, int ldc, int M, int K, int Nc)
{
    __shared__ float As[16][68];
    __shared__ float Ws[16][64];
    int ntile = Nc >> 6;
    int tile_n = blockIdx.x % ntile;
    int tile_m = blockIdx.x / ntile;
    int m0 = tile_m * 64, n0 = tile_n * 64;
    int tid = threadIdx.x;
    int tx = tid & 15, ty = tid >> 4;
    float acc[4][4] = {};
    for (int k0 = 0; k0 < K; k0 += 16) {
        int ks = tid & 15, ms = tid >> 4;
        #pragma unroll
        for (int i = 0; i < 4; i++) {
            int gm = m0 + ms + i * 16;
            As[ks][ms + i * 16] = (gm < M) ? A[(size_t)gm * lda + k0 + ks] : 0.f;
        }
        #pragma unroll
        for (int j = 0; j < 4; j++) {
            int k = (tid >> 6) * 4 + j;
            Ws[k][tid & 63] = Wt[(size_t)(k0 + k) * Nc + n0 + (tid & 63)];
        }
        __syncthreads();
        #pragma unroll
        for (int k = 0; k < 16; k++) {
            float a[4], w[4];
            #pragma unroll
            for (int i = 0; i < 4; i++) a[i] = As[k][ty * 4 + i];
            #pragma unroll
            for (int j = 0; j < 4; j++) w[j] = Ws[k][tx * 4 + j];
            #pragma unroll
            for (int i = 0; i < 4; i++)
                #pragma unroll
                for (int j = 0; j < 4; j++)
                    acc[i][j] += a[i] * w[j];
        }
        __syncthreads();
    }
    #pragma unroll
    for (int i = 0; i < 4; i++) {
        int gm = m0 + ty * 4 + i;
        if (gm >= M) continue;
        #pragma unroll
        for (int j = 0; j < 4; j++) {
            int gn = n0 + tx * 4 + j;
            Cc[(size_t)gm * ldc + gn] = acc[i][j] + bias[gn];
        }
    }
}

// ---------------- direct-global depthwise 7x7 conv with x-register reuse ----------------
// Thread: 4 consecutive x positions x 8 channels, one (b,y) row.
// Per ky: load 10 overlapping 16B cells once, convert to f32 once,
// feed all 7 kx taps x 4 outputs from registers.
// Swizzle: grid 1568 = 8 x 196; each XCD gets a contiguous run of 196 blocks
// (= 2 whole batch images) so y-halo re-reads hit its private L2.
__global__ __launch_bounds__(256) void dwconv_reg(const bf16* __restrict__ in,
    bf16* __restrict__ out,
    const float* __restrict__ w0, const float* __restrict__ b0,
    const float* __restrict__ w1, const float* __restrict__ b1, int split)
{
    int tid = threadIdx.x;
    int chg = tid & 31;                      // 8-channel group
    int bsw = (blockIdx.x & 7) * 196 + (blockIdx.x >> 3);  // bijective XCD remap
    int pg  = bsw * 8 + (tid >> 5);          // pos-group = 4 consecutive x
    int xg = pg % 14;
    int y  = (pg / 14) % 56;
    int b  = pg / (14 * 56);
    int c0 = chg * 8;
    int x0 = xg * 4;

    const float* wp; const float* bp; int ws, cw;
    if (c0 < split) { wp = w0; bp = b0; ws = split;       cw = c0; }
    else            { wp = w1; bp = b1; ws = 256 - split; cw = c0 - split; }

    float acc[4][8];
    #pragma unroll
    for (int o = 0; o < 4; o++)
        #pragma unroll
        for (int e = 0; e < 8; e++) acc[o][e] = 0.f;

    const bf16* base = in + (size_t)b * HWSZ * 256 + c0;
    const float* wbase = wp + cw;
    #pragma unroll
    for (int ky = 0; ky < 7; ky++) {
        int gy = y + ky - 3;
        if (gy < 0 || gy >= 56) continue;
        const bf16* rowp = base + (size_t)gy * 56 * 256;
        float cf[10][8];
        #pragma unroll
        for (int j = 0; j < 10; j++) {
            int gx = x0 + j - 3;
            bf16x8 v = {0, 0, 0, 0, 0, 0, 0, 0};
            if ((unsigned)gx < 56u)
                v = *reinterpret_cast<const bf16x8*>(rowp + (size_t)gx * 256);
            #pragma unroll
            for (int e = 0; e < 8; e++) cf[j][e] = bu2f((unsigned short)v[e]);
        }
        const float* wrow = wbase + ky * 7 * ws;
        #pragma unroll
        for (int kx = 0; kx < 7; kx++) {
            float4 wa = *reinterpret_cast<const float4*>(wrow + kx * ws);
            float4 wb = *reinterpret_cast<const float4*>(wrow + kx * ws + 4);
            #pragma unroll
            for (int o = 0; o < 4; o++) {
                acc[o][0] += cf[o + kx][0] * wa.x;
                acc[o][1] += cf[o + kx][1] * wa.y;
                acc[o][2] += cf[o + kx][2] * wa.z;
                acc[o][3] += cf[o + kx][3] * wa.w;
                acc[o][4] += cf[o + kx][4] * wb.x;
                acc[o][5] += cf[o + kx][5] * wb.y;
                acc[o][6] += cf[o + kx][6] * wb.z;
                acc[o][7] += cf[o + kx][7] * wb.w;
            }
        }
    }

    float4 ba = *reinterpret_cast<const float4*>(bp + cw);
    float4 bb = *reinterpret_cast<const float4*>(bp + cw + 4);
    bf16* obase = out + (((size_t)b * HWSZ + (size_t)y * 56 + x0) * 256) + c0;
    #pragma unroll
    for (int o = 0; o < 4; o++) {
        bf16x8 ov;
        ov[0] = (short)f2bu(acc[o][0] + ba.x);
        ov[1] = (short)f2bu(acc[o][1] + ba.y);
        ov[2] = (short)f2bu(acc[o][2] + ba.z);
        ov[3] = (short)f2bu(acc[o][3] + ba.w);
        ov[4] = (short)f2bu(acc[o][4] + bb.x);
        ov[5] = (short)f2bu(acc[o][5] + bb.y);
        ov[6] = (short)f2bu(acc[o][6] + bb.z);
        ov[7] = (short)f2bu(acc[o][7] + bb.w);
        *reinterpret_cast<bf16x8*>(obase + (size_t)o * 256) = ov;
    }
}

// ---------------- rgb/t elementwise -> codin[N,256] ----------------
__global__ void rgbt_k(const bf16* __restrict__ rgb, const bf16* __restrict__ t,
                       bf16* __restrict__ codin, int total /* N*128 */)
{
    int i = blockIdx.x * blockDim.x + threadIdx.x;
    if (i >= total) return;
    int n = i >> 7, c = i & 127;
    float a = __bfloat162float(rgb[i]), bb = __bfloat162float(t[i]);
    codin[(size_t)n * 256 + c] = __float2bfloat16(a * bb);
    codin[(size_t)n * 256 + 128 + c] = __float2bfloat16(fabsf(a - bb));
}

// ---------------- cosine-gate partial reductions ----------------
__global__ __launch_bounds__(256) void cosred_k(const bf16* __restrict__ codi,
    float* __restrict__ part)   // [B][64][513]
{
    int b = blockIdx.x >> 4;
    int bi = blockIdx.x & 15;
    int wave = threadIdx.x >> 6, lane = threadIdx.x & 63;
    int slot = bi * 4 + wave;
    float dloc[4] = {0,0,0,0}, n2loc[4] = {0,0,0,0};
    float n1loc = 0.f;
    for (int i = 0; i < 49; i++) {
        int p = slot * 49 + i;
        const bf16* row = codi + ((size_t)b * HWSZ + p) * 256;
        float v[4]; float sum = 0.f;
        #pragma unroll
        for (int j = 0; j < 4; j++) { v[j] = __bfloat162float(row[lane + 64 * j]); sum += v[j]; }
        for (int off = 32; off; off >>= 1) sum += __shfl_xor(sum, off, 64);
        float amap = sum * (1.f / 256.f);
        #pragma unroll
        for (int j = 0; j < 4; j++) { dloc[j] += amap * v[j]; n2loc[j] += v[j] * v[j]; }
        n1loc += amap * amap;
    }
    float* dst = part + ((size_t)b * 64 + slot) * 513;
    #pragma unroll
    for (int j = 0; j < 4; j++) {
        dst[lane + 64 * j] = dloc[j];
        dst[256 + lane + 64 * j] = n2loc[j];
    }
    if (lane == 0) dst[512] = n1loc;
}

// ---------------- cos_sim + MLP + sigmoid -> attn_c[B,256] fp32 ----------------
__global__ __launch_bounds__(256) void mlp_kernel(const float* __restrict__ part,
    const float* __restrict__ fc1w, const float* __restrict__ fc2w,
    float* __restrict__ attnc)
{
    int b = blockIdx.x;
    int tid = threadIdx.x;
    __shared__ float cosb[256];
    __shared__ float hbuf[32];
    const float* pb = part + (size_t)b * 64 * 513;
    float dot = 0.f, n2 = 0.f, n1 = 0.f;
    for (int s = 0; s < 64; s++) {
        dot += pb[s * 513 + tid];
        n2  += pb[s * 513 + 256 + tid];
        n1  += pb[s * 513 + 512];
    }
    float cs = dot / (sqrtf(n1) * sqrtf(n2) + 1e-6f);
    cosb[tid] = cs;
    __syncthreads();
    if (tid < 32) {
        float h = 0.f;
        for (int c = 0; c < 256; c++) h += cosb[c] * fc1w[c * 32 + tid];
        h = 0.5f * h * (1.f + erff(h * 0.70710678f));
        hbuf[tid] = h;
    }
    __syncthreads();
    float o = 0.f;
    for (int j = 0; j < 32; j++) o += hbuf[j] * fc2w[j * 256 + tid];
    attnc[b * 256 + tid] = 1.f / (1.f + expf(-o));
}

// ---------------- 8x8 mean-pool of concat(xn, xen) -> rx_pool[B,49,384] fp32 ----------------
__global__ __launch_bounds__(384) void pool_kernel(const bf16* __restrict__ xn,
    const bf16* __restrict__ xen, float* __restrict__ rxpool)
{
    int bij = blockIdx.x;
    int b = bij / 49; int ij = bij % 49; int i = ij / 7, j = ij % 7;
    int c = threadIdx.x;
    float s = 0.f;
    for (int dy = 0; dy < 8; dy++)
        for (int dx = 0; dx < 8; dx++) {
            size_t n = ((size_t)b * 56 + (i * 8 + dy)) * 56 + (j * 8 + dx);
            s += (c < 256) ? __bfloat162float(xn[n * 256 + c])
                           : __bfloat162float(xen[n * 128 + (c - 256)]);
        }
    rxpool[(size_t)bij * 384 + c] = s * (1.f / 64.f);
}

// ---------------- MFMA flash attention over pooled q ----------------
#define NSPLIT 14
#define POSB   224   // 3136/14, multiple of 32
__global__ __launch_bounds__(256) void attn_mfma(const float* __restrict__ qbuf,
    const bf16* __restrict__ kbuf, const bf16* __restrict__ vtbuf,
    float* __restrict__ osplit, float* __restrict__ mlbuf)
{
    int bh = blockIdx.x & 127;
    int split = blockIdx.x >> 7;
    int b = bh >> 3, h = bh & 7;
    int tid = threadIdx.x;
    int qt = tid >> 6;
    int lane = tid & 63;
    int lo = lane & 15, hi = lane >> 4;

    bf16x8 qf = {0, 0, 0, 0, 0, 0, 0, 0};
    int q = qt * 16 + lo;
    if (hi < 2 && q < 49) {
        const float* qp = qbuf + ((size_t)b * 49 + q) * 128 + h * 16 + hi * 8;
        #pragma unroll
        for (int j = 0; j < 8; j++) qf[j] = (short)f2bu(qp[j] * 0.25f);
    }
    const bf16* kbase = kbuf + (size_t)bh * HWSZ * 16;
    const bf16* vbase = vtbuf + ((size_t)bh * 16 + lo) * HWSZ;

    float m_run = -1e30f, l_run = 0.f;
    f32x4 oacc = {0.f, 0.f, 0.f, 0.f};
    int pos1 = 8 * (lo >> 2) + (lo & 3);
    const f32x4 zz = {0.f, 0.f, 0.f, 0.f};

    for (int t = 0; t < POSB / 32; t++) {
        int base = split * POSB + t * 32;
        bf16x8 kf1 = {0, 0, 0, 0, 0, 0, 0, 0}, kf2 = kf1;
        if (hi < 2) {
            kf1 = *reinterpret_cast<const bf16x8*>(kbase + (size_t)(base + pos1) * 16 + hi * 8);
            kf2 = *reinterpret_cast<const bf16x8*>(kbase + (size_t)(base + pos1 + 4) * 16 + hi * 8);
        }
        bf16x8 vf = *reinterpret_cast<const bf16x8*>(vbase + base + hi * 8);
        f32x4 s1 = __builtin_amdgcn_mfma_f32_16x16x32_bf16(kf1, qf, zz, 0, 0, 0);
        f32x4 s2 = __builtin_amdgcn_mfma_f32_16x16x32_bf16(kf2, qf, zz, 0, 0, 0);
        float pmax = fmaxf(fmaxf(fmaxf(s1[0], s1[1]), fmaxf(s1[2], s1[3])),
                           fmaxf(fmaxf(s2[0], s2[1]), fmaxf(s2[2], s2[3])));
        pmax = fmaxf(pmax, __shfl_xor(pmax, 16, 64));
        pmax = fmaxf(pmax, __shfl_xor(pmax, 32, 64));
        float mnew = fmaxf(m_run, pmax);
        float esc = __expf(m_run - mnew);
        l_run *= esc;
        float e0 = __shfl(esc, 4 * hi + 0, 64);
        float e1 = __shfl(esc, 4 * hi + 1, 64);
        float e2 = __shfl(esc, 4 * hi + 2, 64);
        float e3 = __shfl(esc, 4 * hi + 3, 64);
        oacc[0] *= e0; oacc[1] *= e1; oacc[2] *= e2; oacc[3] *= e3;
        float p0 = __expf(s1[0] - mnew), p1 = __expf(s1[1] - mnew);
        float p2 = __expf(s1[2] - mnew), p3 = __expf(s1[3] - mnew);
        float p4 = __expf(s2[0] - mnew), p5 = __expf(s2[1] - mnew);
        float p6 = __expf(s2[2] - mnew), p7 = __expf(s2[3] - mnew);
        float rs = ((p0 + p1) + (p2 + p3)) + ((p4 + p5) + (p6 + p7));
        rs += __shfl_xor(rs, 16, 64);
        rs += __shfl_xor(rs, 32, 64);
        l_run += rs;
        m_run = mnew;
        bf16x8 pf;
        pf[0] = (short)f2bu(p0); pf[1] = (short)f2bu(p1);
        pf[2] = (short)f2bu(p2); pf[3] = (short)f2bu(p3);
        pf[4] = (short)f2bu(p4); pf[5] = (short)f2bu(p5);
        pf[6] = (short)f2bu(p6); pf[7] = (short)f2bu(p7);
        oacc = __builtin_amdgcn_mfma_f32_16x16x32_bf16(pf, vf, oacc, 0, 0, 0);
    }

    float* ob = osplit + ((size_t)bh * NSPLIT + split) * 64 * 16;
    #pragma unroll
    for (int r = 0; r < 4; r++) {
        int qq = qt * 16 + 4 * hi + r;
        ob[(size_t)qq * 16 + lo] = oacc[r];
    }
    if (hi == 0) {
        float* mlb = mlbuf + (((size_t)bh * NSPLIT + split) * 64 + qt * 16 + lo) * 2;
        mlb[0] = m_run; mlb[1] = l_run;
    }
}

// ---------------- merge split partials -> gs[bh][49][16] ----------------
__global__ __launch_bounds__(256) void attn_combine(const float* __restrict__ osplit,
    const float* __restrict__ mlbuf, float* __restrict__ gs)
{
    int idx = blockIdx.x * 256 + threadIdx.x;   // over 128*49*16
    if (idx >= 128 * 49 * 16) return;
    int d = idx & 15;
    int pq = idx >> 4;
    int bh = pq / 49, q = pq % 49;
    float m[NSPLIT], l[NSPLIT];
    float M = -1e30f;
    #pragma unroll
    for (int s = 0; s < NSPLIT; s++) {
        const float* mlb = mlbuf + (((size_t)bh * NSPLIT + s) * 64 + q) * 2;
        m[s] = mlb[0]; l[s] = mlb[1];
        M = fmaxf(M, m[s]);
    }
    float L = 0.f, O = 0.f;
    #pragma unroll
    for (int s = 0; s < NSPLIT; s++) {
        float e = __expf(m[s] - M);
        L += l[s] * e;
        O += osplit[(((size_t)bh * NSPLIT + s) * 64 + q) * 16 + d] * e;
    }
    gs[(size_t)pq * 16 + d] = O / L;
}

// ---------------- bilinear 7->56 upsample into cat[:, 384:512] ----------------
__global__ void upsample_kernel(const float* __restrict__ gs, bf16* __restrict__ cat)
{
    int idx = blockIdx.x * blockDim.x + threadIdx.x;  // over N*128
    if (idx >= N_TOK * 128) return;
    int c = idx & 127;
    int pos = idx >> 7;
    int h = c >> 4, d = c & 15;
    int x = pos % 56;
    int y = (pos / 56) % 56;
    int b = pos / HWSZ;
    float sy = (y + 0.5f) * 0.125f - 0.5f;
    float sx = (x + 0.5f) * 0.125f - 0.5f;
    int y0f = (int)floorf(sy); float wy = sy - (float)y0f;
    int x0f = (int)floorf(sx); float wx = sx - (float)x0f;
    int y0 = max(0, min(6, y0f)), y1 = max(0, min(6, y0f + 1));
    int x0 = max(0, min(6, x0f)), x1 = max(0, min(6, x0f + 1));
    const float* g0 = gs + ((size_t)(b * 8 + h) * 49) * 16 + d;
    float v00 = g0[(y0 * 7 + x0) * 16], v01 = g0[(y0 * 7 + x1) * 16];
    float v10 = g0[(y1 * 7 + x0) * 16], v11 = g0[(y1 * 7 + x1) * 16];
    float v0 = v00 + (v01 - v00) * wx;
    float v1 = v10 + (v11 - v10) * wx;
    float v = v0 + (v1 - v0) * wy;
    cat[(size_t)pos * 512 + 384 + c] = __float2bfloat16(v);
}

extern "C" void kernel_launch(void* const* d_in, const int* in_sizes, int n_in,
                              void* d_out, int out_size, void* d_ws, size_t ws_size,
                              hipStream_t stream)
{
    const float* x      = (const float*)d_in[0];
    const float* x_e    = (const float*)d_in[1];
    const float* norm_w = (const float*)d_in[2];
    const float* norm_b = (const float*)d_in[3];
    const float* norme_w= (const float*)d_in[4];
    const float* norme_b= (const float*)d_in[5];
    const float* rr1_w  = (const float*)d_in[6];
    const float* rr1_b  = (const float*)d_in[7];
    const float* rr2_w  = (const float*)d_in[8];
    const float* rr2_b  = (const float*)d_in[9];
    const float* rr3_w  = (const float*)d_in[10];
    const float* rr3_b  = (const float*)d_in[11];
    const float* conv_w = (const float*)d_in[12];
    const float* conv_b = (const float*)d_in[13];
    const float* l1_w   = (const float*)d_in[14];
    const float* l1_b   = (const float*)d_in[15];
    const float* l2_w   = (const float*)d_in[16];
    const float* l2_b   = (const float*)d_in[17];
    const float* c1_w   = (const float*)d_in[18];
    const float* c1_b   = (const float*)d_in[19];
    const float* c2_w   = (const float*)d_in[20];
    const float* c2_b   = (const float*)d_in[21];
    const float* fc1_w  = (const float*)d_in[22];
    const float* fc2_w  = (const float*)d_in[23];
    const float* l3_w   = (const float*)d_in[24];
    const float* l3_b   = (const float*)d_in[25];
    const float* kv_w   = (const float*)d_in[26];
    const float* kv_b   = (const float*)d_in[27];
    const float* q_w    = (const float*)d_in[28];
    const float* q_b    = (const float*)d_in[29];
    const float* proj_w = (const float*)d_in[30];
    const float* proj_b = (const float*)d_in[31];
    const float* proje_w= (const float*)d_in[32];
    const float* proje_b= (const float*)d_in[33];

    // ---- workspace: fp32 smalls, bf16 transposed weights, bf16 slabs ----
    float* part   = (float*)d_ws;                 // 16*64*513
    float* attnc  = part   + (size_t)525312;      // 16*256
    float* gs     = attnc  + 4096;                // 16*8*49*16
    float* rxpool = gs     + 100352;              // 784*384
    float* qbuf   = rxpool + 301056;              // 784*128
    bf16* wt      = (bf16*)(qbuf + 100352);
    bf16* rr1_t  = wt;              // 256x256
    bf16* rr2_t  = rr1_t + 65536;   // 256x256 (contiguous after rr1_t -> fused [512][256])
    bf16* rr3_t  = rr2_t + 65536;
    bf16* kv_t   = rr3_t + 65536;
    bf16* l1_t   = kv_t  + 65536;   // 128x256
    bf16* l2_t   = l1_t  + 32768;   // 128x128
    bf16* l3_t   = l2_t  + 16384;   // 128x256
    bf16* proj_t = l3_t  + 32768;   // 256x512
    bf16* proje_t= proj_t + 131072; // 128x512 (contiguous after proj_t -> fused [384][512])
    bf16* xn     = proje_t + 65536;
    bf16* xen    = xn   + (size_t)N_TOK * 256;
    bf16* bufC   = xen  + (size_t)N_TOK * 128;   // rr1 / codin / K|V head-major
    bf16* bufD   = bufC + (size_t)N_TOK * 256;   // rr2pre / rgb|t / attn partials
    bf16* bufE   = bufD + (size_t)N_TOK * 256;   // conv out / co_di
    bf16* cat    = bufE + (size_t)N_TOK * 256;   // [N,512]
    size_t need = (size_t)((char*)(cat + (size_t)N_TOK * 512) - (char*)d_ws);
    if (ws_size < need) return;

    bf16* kbuf = bufC;                       // [B*8][HWSZ][16]
    bf16* vbuf = bufC + (size_t)N_TOK * 128; // [B*8][16][HWSZ] (transposed)

    // attn split partials live in bufD (free during phase 4): 8.26 MB
    float* osplit = (float*)bufD;                          // [128][NSPLIT][64][16]
    float* mlbuf  = osplit + (size_t)128 * NSPLIT * 64 * 16; // [128][NSPLIT][64][2]

    float* xout  = (float*)d_out;
    float* xeout = xout + (size_t)N_TOK * 256;

    const int nthr = 256;
    auto mgrid = [](int M, int N) { return dim3((M / 64) * (N / 128)); };

    // 0. weight prep (one launch)
    {
        WtrPack p;
        const float* srcs[9] = {rr1_w, rr2_w, rr3_w, kv_w, l1_w, l2_w, l3_w, proj_w, proje_w};
        bf16* dsts[9] = {rr1_t, rr2_t, rr3_t, kv_t, l1_t, l2_t, l3_t, proj_t, proje_t};
        int Ks[9] = {256, 256, 256, 256, 256, 128, 256, 512, 512};
        int Ns[9] = {256, 256, 256, 256, 128, 128, 128, 256, 128};
        int off = 0;
        for (int s = 0; s < 9; s++) {
            p.d[s] = {srcs[s], dsts[s], Ks[s], Ns[s], off};
            off += Ks[s] * Ns[s];
        }
        p.total = off;
        wtr_all<<<dim3((off + 255) / 256), dim3(256), 0, stream>>>(p);
    }

    // 1. LayerNorms
    ln_kernel<<<dim3(N_TOK / 4), dim3(nthr), 0, stream>>>(x, norm_w, norm_b, xn, N_TOK, 256);
    ln_kernel<<<dim3(N_TOK / 4), dim3(nthr), 0, stream>>>(x_e, norme_w, norme_b, xen, N_TOK, 128);

    // 2. local_rr -> cat[:, 0:256]   (rr1+rr2 FUSED: one A-pass, N=512)
    gemm_mfma<GF_DUAL, bf16><<<mgrid(N_TOK, 512), dim3(nthr), 0, stream>>>(
        xn, 256, rr1_t, rr1_b, bufC, 256, N_TOK, 256, 512, nullptr, 0, nullptr, nullptr, nullptr,
        bufD, 256, rr2_b, 256);
    dwconv_reg<<<dim3(N_TOK / 32), dim3(nthr), 0, stream>>>(
        bufD, bufE, conv_w, conv_b, conv_w, conv_b, 256);
    gemm_mfma<GF_MUL, bf16><<<mgrid(N_TOK, 256), dim3(nthr), 0, stream>>>(
        bufE, 256, rr3_t, rr3_b, cat, 512, N_TOK, 256, 256, bufC, 256, nullptr, nullptr, nullptr,
        nullptr, 0, nullptr, 0);

    // 3. LocalAttentionRGBT -> cat[:, 256:384]
    gemm_mfma<0, bf16><<<mgrid(N_TOK, 128), dim3(nthr), 0, stream>>>(
        xn, 256, l1_t, l1_b, bufD, 128, N_TOK, 256, 128, nullptr, 0, nullptr, nullptr, nullptr,
        nullptr, 0, nullptr, 0);
    gemm_mfma<0, bf16><<<mgrid(N_TOK, 128), dim3(nthr), 0, stream>>>(
        xen, 128, l2_t, l2_b, bufD + (size_t)N_TOK * 128, 128, N_TOK, 128, 128, nullptr, 0, nullptr, nullptr, nullptr,
        nullptr, 0, nullptr, 0);
    rgbt_k<<<dim3((N_TOK * 128) / nthr), dim3(nthr), 0, stream>>>(
        bufD, bufD + (size_t)N_TOK * 128, bufC, N_TOK * 128);
    dwconv_reg<<<dim3(N_TOK / 32), dim3(nthr), 0, stream>>>(
        bufC, bufE, c1_w, c1_b, c2_w, c2_b, 128);
    cosred_k<<<dim3(BATCH * 16), dim3(nthr), 0, stream>>>(bufE, part);
    mlp_kernel<<<dim3(BATCH), dim3(nthr), 0, stream>>>(part, fc1_w, fc2_w, attnc);
    gemm_mfma<GF_ASCALE, bf16><<<mgrid(N_TOK, 128), dim3(nthr), 0, stream>>>(
        bufE, 256, l3_t, l3_b, cat + 256, 512, N_TOK, 256, 128, nullptr, 0, attnc, nullptr, nullptr,
        nullptr, 0, nullptr, 0);

    // 4. global pooled attention -> cat[:, 384:512]
    gemm_mfma<GF_KVSPLIT, bf16><<<mgrid(N_TOK, 256), dim3(nthr), 0, stream>>>(
        xn, 256, kv_t, kv_b, (bf16*)nullptr, 0, N_TOK, 256, 256, nullptr, 0, nullptr, kbuf, vbuf,
        nullptr, 0, nullptr, 0);
    pool_kernel<<<dim3(BATCH * 49), dim3(384), 0, stream>>>(xn, xen, rxpool);
    gemm_k<<<dim3(((784 + 63) / 64) * 2), dim3(nthr), 0, stream>>>(
        rxpool, 384, q_w, q_b, qbuf, 128, 784, 384, 128);
    attn_mfma<<<dim3(128 * NSPLIT), dim3(nthr), 0, stream>>>(qbuf, kbuf, vbuf, osplit, mlbuf);
    attn_combine<<<dim3(392), dim3(nthr), 0, stream>>>(osplit, mlbuf, gs);
    upsample_kernel<<<dim3((N_TOK * 128) / nthr), dim3(nthr), 0, stream>>>(gs, cat);

    // 5. output projections (proj+proje FUSED: one cat-pass, N=384, fp32 out)
    gemm_mfma<GF_DUAL, float><<<mgrid(N_TOK, 384), dim3(nthr), 0, stream>>>(
        cat, 512, proj_t, proj_b, xout, 256, N_TOK, 512, 384, nullptr, 0, nullptr, nullptr, nullptr,
        xeout, 128, proje_b, 256);
}

// Round 10
// 423.020 us; speedup vs baseline: 1.2633x; 1.0120x over previous
//
#include <hip/hip_runtime.h>
#include <hip/hip_bf16.h>
#include <cstdint>
#include <cstddef>

#define N_TOK 50176      // B*H*W
#define HWSZ  3136       // 56*56
#define BATCH 16

#define GF_MUL     1
#define GF_ASCALE  2
#define GF_KVSPLIT 4
#define GF_DUAL    8
#define GF_TRI     16
#define GF_RGBT    32

typedef __hip_bfloat16 bf16;
typedef __attribute__((ext_vector_type(8))) short bf16x8;
typedef __attribute__((ext_vector_type(4))) float f32x4;
typedef __attribute__((ext_vector_type(4))) unsigned short u16x4;

__device__ __forceinline__ void  stf(float* p, size_t i, float v) { p[i] = v; }
__device__ __forceinline__ void  stf(bf16* p, size_t i, float v) { p[i] = __float2bfloat16(v); }
__device__ __forceinline__ float bu2f(unsigned short u) {
    unsigned int x = ((unsigned int)u) << 16; float f; __builtin_memcpy(&f, &x, 4); return f;
}
__device__ __forceinline__ unsigned short f2bu(float f) {
    bf16 t = __float2bfloat16(f); unsigned short u; __builtin_memcpy(&u, &t, 2); return u;
}

// ---------------- batched weight prep: W[K][N] fp32 -> WT[N][K] bf16 (9 mats, 1 launch) ----------------
struct WtrDesc { const float* src; bf16* dst; int K; int N; int off; };
struct WtrPack { WtrDesc d[9]; int total; };
__global__ __launch_bounds__(256) void wtr_all(WtrPack p)
{
    int idx = blockIdx.x * 256 + threadIdx.x;
    if (idx >= p.total) return;
    #pragma unroll
    for (int s = 0; s < 9; s++) {
        int lo = p.d[s].off, hi = lo + p.d[s].K * p.d[s].N;
        if (idx >= lo && idx < hi) {
            int j = idx - lo;
            int k = j / p.d[s].N, n = j % p.d[s].N;
            p.d[s].dst[(size_t)n * p.d[s].K + k] = __float2bfloat16(p.d[s].src[j]);
        }
    }
}

// ---------------- LayerNorm: one wave per row (fp32 in -> bf16 out) ----------------
__global__ __launch_bounds__(256) void ln_kernel(const float* __restrict__ in,
    const float* __restrict__ w, const float* __restrict__ b,
    bf16* __restrict__ out, int rows, int Cdim)
{
    int wave = threadIdx.x >> 6, lane = threadIdx.x & 63;
    int row = blockIdx.x * 4 + wave;
    if (row >= rows) return;
    const float* p = in + (size_t)row * Cdim;
    int nj = Cdim >> 6;
    float v[4];
    float s = 0.f;
    for (int j = 0; j < nj; j++) { v[j] = p[lane + 64 * j]; s += v[j]; }
    for (int off = 32; off; off >>= 1) s += __shfl_xor(s, off, 64);
    float mean = s / (float)Cdim;
    float vs = 0.f;
    for (int j = 0; j < nj; j++) { float d = v[j] - mean; vs += d * d; }
    for (int off = 32; off; off >>= 1) vs += __shfl_xor(vs, off, 64);
    float rstd = 1.f / sqrtf(vs / (float)Cdim + 1e-6f);
    bf16* q = out + (size_t)row * Cdim;
    for (int j = 0; j < nj; j++) {
        int c = lane + 64 * j;
        q[c] = __float2bfloat16((v[j] - mean) * rstd * w[c] + b[c]);
    }
}

// ---------------- MFMA GEMM: C = A[M,K](bf16) @ WT[N,K]^T(bf16) + bias ----------------
// 64x128 tile, BK=32, 256 threads = 4 waves, wave w owns 64 rows x 32 cols (acc[4][2]).
// 2-deep double-buffered pipeline, one barrier per phase. LDT=40. XCD-swizzled blockIdx.
// GF_DUAL: 2-way split-N epilogue. GF_TRI: rr1/rr2/kv 3-way (kv bias passed via ascale).
// GF_RGBT: codin epilogue (rgb from mul; writes prod and absdiff into C at +0/+128).
#define LDT 40
template<int FLAGS, typename OT>
__global__ __launch_bounds__(256) void gemm_mfma(
    const bf16* __restrict__ A, int lda,
    const bf16* __restrict__ WT,           // [N][K]
    const float* __restrict__ bias,
    OT* __restrict__ C, int ldc,
    int M, int K, int N,
    const bf16* __restrict__ mul, int mulld,
    const float* __restrict__ ascale,      // [BATCH][K] (ASCALE) or kv bias (TRI)
    bf16* __restrict__ kout, bf16* __restrict__ vout,
    OT* __restrict__ C2, int ldc2, const float* __restrict__ bias2, int N1)
{
    __shared__ bf16 As[2][64][LDT];
    __shared__ bf16 Bs[2][128][LDT];
    int ntile = N >> 7;
    int bid = blockIdx.x;
    bid = (bid & 7) * (gridDim.x >> 3) + (bid >> 3);   // bijective XCD remap (grid%8==0)
    int m0 = (bid / ntile) * 64;
    int n0 = (bid % ntile) * 128;
    int tid = threadIdx.x;
    int lane = tid & 63, wid = tid >> 6;
    int wc = wid * 32;
    int lrow = lane & 15, lko = (lane >> 4) * 8;
    int sr = tid >> 2, sko = (tid & 3) * 8;

    f32x4 acc[4][2];
    #pragma unroll
    for (int i = 0; i < 4; i++)
        #pragma unroll
        for (int j = 0; j < 2; j++)
            acc[i][j] = (f32x4){0.f, 0.f, 0.f, 0.f};

#define GLOAD(RA, RB0, RB1, KOFF) do {                                                        \
    bf16x8 v_ = *reinterpret_cast<const bf16x8*>(A + (size_t)(m0 + sr) * lda + (KOFF) + sko); \
    if (FLAGS & GF_ASCALE) {                                                                  \
        int bidx_ = (m0 + sr) / HWSZ;                                                         \
        const float* as_ = ascale + (size_t)bidx_ * K + (KOFF) + sko;                         \
        for (int e_ = 0; e_ < 8; e_++)                                                        \
            v_[e_] = (short)f2bu(bu2f((unsigned short)v_[e_]) * as_[e_]);                     \
    }                                                                                         \
    RA = v_;                                                                                  \
    RB0 = *reinterpret_cast<const bf16x8*>(WT + (size_t)(n0 + sr) * K + (KOFF) + sko);        \
    RB1 = *reinterpret_cast<const bf16x8*>(WT + (size_t)(n0 + sr + 64) * K + (KOFF) + sko);   \
} while (0)

#define GWRITE(P, RA, RB0, RB1) do {                                   \
    *reinterpret_cast<bf16x8*>(&As[P][sr][sko]) = RA;                  \
    *reinterpret_cast<bf16x8*>(&Bs[P][sr][sko]) = RB0;                 \
    *reinterpret_cast<bf16x8*>(&Bs[P][sr + 64][sko]) = RB1;            \
} while (0)

#define GCOMP(P) do {                                                                         \
    bf16x8 af_[4], br_[2];                                                                    \
    for (int i_ = 0; i_ < 4; i_++)                                                            \
        af_[i_] = *reinterpret_cast<const bf16x8*>(&As[P][i_ * 16 + lrow][lko]);              \
    for (int j_ = 0; j_ < 2; j_++)                                                            \
        br_[j_] = *reinterpret_cast<const bf16x8*>(&Bs[P][wc + j_ * 16 + lrow][lko]);         \
    for (int i_ = 0; i_ < 4; i_++)                                                            \
        for (int j_ = 0; j_ < 2; j_++)                                                        \
            acc[i_][j_] = __builtin_amdgcn_mfma_f32_16x16x32_bf16(af_[i_], br_[j_], acc[i_][j_], 0, 0, 0); \
} while (0)

    // prologue: 2 tile-steps in flight (K is always a multiple of 64 -> nst even)
    bf16x8 ra0, rb00, rb01, ra1, rb10, rb11;
    GLOAD(ra0, rb00, rb01, 0);
    GLOAD(ra1, rb10, rb11, 32);
    int nst = K >> 5;
    for (int s = 0; s < nst; s += 2) {
        // phase 0
        GWRITE(0, ra0, rb00, rb01);
        if (s + 2 < nst) GLOAD(ra0, rb00, rb01, (s + 2) * 32);
        __syncthreads();
        GCOMP(0);
        // phase 1
        GWRITE(1, ra1, rb10, rb11);
        if (s + 3 < nst) GLOAD(ra1, rb10, rb11, (s + 3) * 32);
        __syncthreads();
        GCOMP(1);
    }
#undef GLOAD
#undef GWRITE
#undef GCOMP

    int orow = (lane >> 4) * 4;
    int ocol = lane & 15;
    #pragma unroll
    for (int i = 0; i < 4; i++) {
        #pragma unroll
        for (int j = 0; j < 2; j++) {
            #pragma unroll
            for (int p = 0; p < 4; p++) {
                int gm = m0 + i * 16 + orow + p;
                int gn = n0 + wc + j * 16 + ocol;
                if (FLAGS & GF_TRI) {
                    // rr1 -> C, rr2 -> C2, kv -> kout/vout (kv bias in ascale)
                    if (gn < 256) {
                        stf(C, (size_t)gm * ldc + gn, acc[i][j][p] + bias[gn]);
                    } else if (gn < 512) {
                        stf(C2, (size_t)gm * ldc2 + (gn - 256), acc[i][j][p] + bias2[gn - 256]);
                    } else {
                        int g3 = gn - 512;
                        float v = acc[i][j][p] + ascale[g3];
                        int bb = gm / HWSZ, n = gm % HWSZ;
                        if (g3 < 128)
                            kout[(((size_t)bb * 8 + (g3 >> 4)) * HWSZ + n) * 16 + (g3 & 15)] = __float2bfloat16(v);
                        else {
                            int hh = (g3 - 128) >> 4, dd = (g3 - 128) & 15;
                            // V stored TRANSPOSED: [bh][d][pos]
                            vout[(((size_t)bb * 8 + hh) * 16 + dd) * HWSZ + n] = __float2bfloat16(v);
                        }
                    }
                } else if (FLAGS & GF_RGBT) {
                    float t = acc[i][j][p] + bias[gn];
                    float rgb = __bfloat162float(mul[(size_t)gm * mulld + gn]);
                    stf(C, (size_t)gm * ldc + gn, rgb * t);
                    stf(C, (size_t)gm * ldc + 128 + gn, fabsf(rgb - t));
                } else if (FLAGS & GF_KVSPLIT) {
                    float v = acc[i][j][p] + bias[gn];
                    int bb = gm / HWSZ, n = gm % HWSZ;
                    if (gn < 128)
                        kout[(((size_t)bb * 8 + (gn >> 4)) * HWSZ + n) * 16 + (gn & 15)] = __float2bfloat16(v);
                    else {
                        int hh = (gn - 128) >> 4, dd = (gn - 128) & 15;
                        vout[(((size_t)bb * 8 + hh) * 16 + dd) * HWSZ + n] = __float2bfloat16(v);
                    }
                } else if (FLAGS & GF_DUAL) {
                    if (gn < N1) {
                        float v = acc[i][j][p] + bias[gn];
                        stf(C, (size_t)gm * ldc + gn, v);
                    } else {
                        float v = acc[i][j][p] + bias2[gn - N1];
                        stf(C2, (size_t)gm * ldc2 + (gn - N1), v);
                    }
                } else {
                    float v = acc[i][j][p] + bias[gn];
                    if (FLAGS & GF_MUL) v *= __bfloat162float(mul[(size_t)gm * mulld + gn]);
                    stf(C, (size_t)gm * ldc + gn, v);
                }
            }
        }
    }
}

// ---------------- fp32 vector GEMM (small q projection only) ----------------
__global__ __launch_bounds__(256) void gemm_k(
    const float* __restrict__ A, int lda,
    const float* __restrict__ Wt, const float* __restrict__ bias,
    float* __restrict__ Cc, int ldc, int M, int K, int Nc)
{
    __shared__ float As[16][68];
    __shared__ float Ws[16][64];
    int ntile = Nc >> 6;
    int tile_n = blockIdx.x % ntile;
    int tile_m = blockIdx.x / ntile;
    int m0 = tile_m * 64, n0 = tile_n * 64;
    int tid = threadIdx.x;
    int tx = tid & 15, ty = tid >> 4;
    float acc[4][4] = {};
    for (int k0 = 0; k0 < K; k0 += 16) {
        int ks = tid & 15, ms = tid >> 4;
        #pragma unroll
        for (int i = 0; i < 4; i++) {
            int gm = m0 + ms + i * 16;
            As[ks][ms + i * 16] = (gm < M) ? A[(size_t)gm * lda + k0 + ks] : 0.f;
        }
        #pragma unroll
        for (int j = 0; j < 4; j++) {
            int k = (tid >> 6) * 4 + j;
            Ws[k][tid & 63] = Wt[(size_t)(k0 + k) * Nc + n0 + (tid & 63)];
        }
        __syncthreads();
        #pragma unroll
        for (int k = 0; k < 16; k++) {
            float a[4], w[4];
            #pragma unroll
            for (int i = 0; i < 4; i++) a[i] = As[k][ty * 4 + i];
            #pragma unroll
            for (int j = 0; j < 4; j++) w[j] = Ws[k][tx * 4 + j];
            #pragma unroll
            for (int i = 0; i < 4; i++)
                #pragma unroll
                for (int j = 0; j < 4; j++)
                    acc[i][j] += a[i] * w[j];
        }
        __syncthreads();
    }
    #pragma unroll
    for (int i = 0; i < 4; i++) {
        int gm = m0 + ty * 4 + i;
        if (gm >= M) continue;
        #pragma unroll
        for (int j = 0; j < 4; j++) {
            int gn = n0 + tx * 4 + j;
            Cc[(size_t)gm * ldc + gn] = acc[i][j] + bias[gn];
        }
    }
}

// ---------------- direct-global depthwise 7x7 conv with x-register reuse ----------------
__global__ __launch_bounds__(256) void dwconv_reg(const bf16* __restrict__ in,
    bf16* __restrict__ out,
    const float* __restrict__ w0, const float* __restrict__ b0,
    const float* __restrict__ w1, const float* __restrict__ b1, int split)
{
    int tid = threadIdx.x;
    int chg = tid & 31;                      // 8-channel group
    int bsw = (blockIdx.x & 7) * 196 + (blockIdx.x >> 3);  // bijective XCD remap
    int pg  = bsw * 8 + (tid >> 5);          // pos-group = 4 consecutive x
    int xg = pg % 14;
    int y  = (pg / 14) % 56;
    int b  = pg / (14 * 56);
    int c0 = chg * 8;
    int x0 = xg * 4;

    const float* wp; const float* bp; int ws, cw;
    if (c0 < split) { wp = w0; bp = b0; ws = split;       cw = c0; }
    else            { wp = w1; bp = b1; ws = 256 - split; cw = c0 - split; }

    float acc[4][8];
    #pragma unroll
    for (int o = 0; o < 4; o++)
        #pragma unroll
        for (int e = 0; e < 8; e++) acc[o][e] = 0.f;

    const bf16* base = in + (size_t)b * HWSZ * 256 + c0;
    const float* wbase = wp + cw;
    #pragma unroll
    for (int ky = 0; ky < 7; ky++) {
        int gy = y + ky - 3;
        if (gy < 0 || gy >= 56) continue;
        const bf16* rowp = base + (size_t)gy * 56 * 256;
        float cf[10][8];
        #pragma unroll
        for (int j = 0; j < 10; j++) {
            int gx = x0 + j - 3;
            bf16x8 v = {0, 0, 0, 0, 0, 0, 0, 0};
            if ((unsigned)gx < 56u)
                v = *reinterpret_cast<const bf16x8*>(rowp + (size_t)gx * 256);
            #pragma unroll
            for (int e = 0; e < 8; e++) cf[j][e] = bu2f((unsigned short)v[e]);
        }
        const float* wrow = wbase + ky * 7 * ws;
        #pragma unroll
        for (int kx = 0; kx < 7; kx++) {
            float4 wa = *reinterpret_cast<const float4*>(wrow + kx * ws);
            float4 wb = *reinterpret_cast<const float4*>(wrow + kx * ws + 4);
            #pragma unroll
            for (int o = 0; o < 4; o++) {
                acc[o][0] += cf[o + kx][0] * wa.x;
                acc[o][1] += cf[o + kx][1] * wa.y;
                acc[o][2] += cf[o + kx][2] * wa.z;
                acc[o][3] += cf[o + kx][3] * wa.w;
                acc[o][4] += cf[o + kx][4] * wb.x;
                acc[o][5] += cf[o + kx][5] * wb.y;
                acc[o][6] += cf[o + kx][6] * wb.z;
                acc[o][7] += cf[o + kx][7] * wb.w;
            }
        }
    }

    float4 ba = *reinterpret_cast<const float4*>(bp + cw);
    float4 bb = *reinterpret_cast<const float4*>(bp + cw + 4);
    bf16* obase = out + (((size_t)b * HWSZ + (size_t)y * 56 + x0) * 256) + c0;
    #pragma unroll
    for (int o = 0; o < 4; o++) {
        bf16x8 ov;
        ov[0] = (short)f2bu(acc[o][0] + ba.x);
        ov[1] = (short)f2bu(acc[o][1] + ba.y);
        ov[2] = (short)f2bu(acc[o][2] + ba.z);
        ov[3] = (short)f2bu(acc[o][3] + ba.w);
        ov[4] = (short)f2bu(acc[o][4] + bb.x);
        ov[5] = (short)f2bu(acc[o][5] + bb.y);
        ov[6] = (short)f2bu(acc[o][6] + bb.z);
        ov[7] = (short)f2bu(acc[o][7] + bb.w);
        *reinterpret_cast<bf16x8*>(obase + (size_t)o * 256) = ov;
    }
}

// ---------------- cosine-gate partial reductions ----------------
__global__ __launch_bounds__(256) void cosred_k(const bf16* __restrict__ codi,
    float* __restrict__ part)   // [B][64][513]
{
    int b = blockIdx.x >> 4;
    int bi = blockIdx.x & 15;
    int wave = threadIdx.x >> 6, lane = threadIdx.x & 63;
    int slot = bi * 4 + wave;
    float dloc[4] = {0,0,0,0}, n2loc[4] = {0,0,0,0};
    float n1loc = 0.f;
    for (int i = 0; i < 49; i++) {
        int p = slot * 49 + i;
        const bf16* row = codi + ((size_t)b * HWSZ + p) * 256;
        float v[4]; float sum = 0.f;
        #pragma unroll
        for (int j = 0; j < 4; j++) { v[j] = __bfloat162float(row[lane + 64 * j]); sum += v[j]; }
        for (int off = 32; off; off >>= 1) sum += __shfl_xor(sum, off, 64);
        float amap = sum * (1.f / 256.f);
        #pragma unroll
        for (int j = 0; j < 4; j++) { dloc[j] += amap * v[j]; n2loc[j] += v[j] * v[j]; }
        n1loc += amap * amap;
    }
    float* dst = part + ((size_t)b * 64 + slot) * 513;
    #pragma unroll
    for (int j = 0; j < 4; j++) {
        dst[lane + 64 * j] = dloc[j];
        dst[256 + lane + 64 * j] = n2loc[j];
    }
    if (lane == 0) dst[512] = n1loc;
}

// ---------------- cos_sim + MLP + sigmoid -> attn_c[B,256] fp32 ----------------
__global__ __launch_bounds__(256) void mlp_kernel(const float* __restrict__ part,
    const float* __restrict__ fc1w, const float* __restrict__ fc2w,
    float* __restrict__ attnc)
{
    int b = blockIdx.x;
    int tid = threadIdx.x;
    __shared__ float cosb[256];
    __shared__ float hbuf[32];
    const float* pb = part + (size_t)b * 64 * 513;
    float dot = 0.f, n2 = 0.f, n1 = 0.f;
    for (int s = 0; s < 64; s++) {
        dot += pb[s * 513 + tid];
        n2  += pb[s * 513 + 256 + tid];
        n1  += pb[s * 513 + 512];
    }
    float cs = dot / (sqrtf(n1) * sqrtf(n2) + 1e-6f);
    cosb[tid] = cs;
    __syncthreads();
    if (tid < 32) {
        float h = 0.f;
        for (int c = 0; c < 256; c++) h += cosb[c] * fc1w[c * 32 + tid];
        h = 0.5f * h * (1.f + erff(h * 0.70710678f));
        hbuf[tid] = h;
    }
    __syncthreads();
    float o = 0.f;
    for (int j = 0; j < 32; j++) o += hbuf[j] * fc2w[j * 256 + tid];
    attnc[b * 256 + tid] = 1.f / (1.f + expf(-o));
}

// ---------------- 8x8 mean-pool of concat(xn, xen) -> rx_pool[B,49,384] fp32 ----------------
__global__ __launch_bounds__(384) void pool_kernel(const bf16* __restrict__ xn,
    const bf16* __restrict__ xen, float* __restrict__ rxpool)
{
    int bij = blockIdx.x;
    int b = bij / 49; int ij = bij % 49; int i = ij / 7, j = ij % 7;
    int c = threadIdx.x;
    float s = 0.f;
    for (int dy = 0; dy < 8; dy++)
        for (int dx = 0; dx < 8; dx++) {
            size_t n = ((size_t)b * 56 + (i * 8 + dy)) * 56 + (j * 8 + dx);
            s += (c < 256) ? __bfloat162float(xn[n * 256 + c])
                           : __bfloat162float(xen[n * 128 + (c - 256)]);
        }
    rxpool[(size_t)bij * 384 + c] = s * (1.f / 64.f);
}

// ---------------- MFMA flash attention over pooled q ----------------
#define NSPLIT 14
#define POSB   224   // 3136/14, multiple of 32
__global__ __launch_bounds__(256) void attn_mfma(const float* __restrict__ qbuf,
    const bf16* __restrict__ kbuf, const bf16* __restrict__ vtbuf,
    float* __restrict__ osplit, float* __restrict__ mlbuf)
{
    int bh = blockIdx.x & 127;
    int split = blockIdx.x >> 7;
    int b = bh >> 3, h = bh & 7;
    int tid = threadIdx.x;
    int qt = tid >> 6;
    int lane = tid & 63;
    int lo = lane & 15, hi = lane >> 4;

    bf16x8 qf = {0, 0, 0, 0, 0, 0, 0, 0};
    int q = qt * 16 + lo;
    if (hi < 2 && q < 49) {
        const float* qp = qbuf + ((size_t)b * 49 + q) * 128 + h * 16 + hi * 8;
        #pragma unroll
        for (int j = 0; j < 8; j++) qf[j] = (short)f2bu(qp[j] * 0.25f);
    }
    const bf16* kbase = kbuf + (size_t)bh * HWSZ * 16;
    const bf16* vbase = vtbuf + ((size_t)bh * 16 + lo) * HWSZ;

    float m_run = -1e30f, l_run = 0.f;
    f32x4 oacc = {0.f, 0.f, 0.f, 0.f};
    int pos1 = 8 * (lo >> 2) + (lo & 3);
    const f32x4 zz = {0.f, 0.f, 0.f, 0.f};

    for (int t = 0; t < POSB / 32; t++) {
        int base = split * POSB + t * 32;
        bf16x8 kf1 = {0, 0, 0, 0, 0, 0, 0, 0}, kf2 = kf1;
        if (hi < 2) {
            kf1 = *reinterpret_cast<const bf16x8*>(kbase + (size_t)(base + pos1) * 16 + hi * 8);
            kf2 = *reinterpret_cast<const bf16x8*>(kbase + (size_t)(base + pos1 + 4) * 16 + hi * 8);
        }
        bf16x8 vf = *reinterpret_cast<const bf16x8*>(vbase + base + hi * 8);
        f32x4 s1 = __builtin_amdgcn_mfma_f32_16x16x32_bf16(kf1, qf, zz, 0, 0, 0);
        f32x4 s2 = __builtin_amdgcn_mfma_f32_16x16x32_bf16(kf2, qf, zz, 0, 0, 0);
        float pmax = fmaxf(fmaxf(fmaxf(s1[0], s1[1]), fmaxf(s1[2], s1[3])),
                           fmaxf(fmaxf(s2[0], s2[1]), fmaxf(s2[2], s2[3])));
        pmax = fmaxf(pmax, __shfl_xor(pmax, 16, 64));
        pmax = fmaxf(pmax, __shfl_xor(pmax, 32, 64));
        float mnew = fmaxf(m_run, pmax);
        float esc = __expf(m_run - mnew);
        l_run *= esc;
        float e0 = __shfl(esc, 4 * hi + 0, 64);
        float e1 = __shfl(esc, 4 * hi + 1, 64);
        float e2 = __shfl(esc, 4 * hi + 2, 64);
        float e3 = __shfl(esc, 4 * hi + 3, 64);
        oacc[0] *= e0; oacc[1] *= e1; oacc[2] *= e2; oacc[3] *= e3;
        float p0 = __expf(s1[0] - mnew), p1 = __expf(s1[1] - mnew);
        float p2 = __expf(s1[2] - mnew), p3 = __expf(s1[3] - mnew);
        float p4 = __expf(s2[0] - mnew), p5 = __expf(s2[1] - mnew);
        float p6 = __expf(s2[2] - mnew), p7 = __expf(s2[3] - mnew);
        float rs = ((p0 + p1) + (p2 + p3)) + ((p4 + p5) + (p6 + p7));
        rs += __shfl_xor(rs, 16, 64);
        rs += __shfl_xor(rs, 32, 64);
        l_run += rs;
        m_run = mnew;
        bf16x8 pf;
        pf[0] = (short)f2bu(p0); pf[1] = (short)f2bu(p1);
        pf[2] = (short)f2bu(p2); pf[3] = (short)f2bu(p3);
        pf[4] = (short)f2bu(p4); pf[5] = (short)f2bu(p5);
        pf[6] = (short)f2bu(p6); pf[7] = (short)f2bu(p7);
        oacc = __builtin_amdgcn_mfma_f32_16x16x32_bf16(pf, vf, oacc, 0, 0, 0);
    }

    float* ob = osplit + ((size_t)bh * NSPLIT + split) * 64 * 16;
    #pragma unroll
    for (int r = 0; r < 4; r++) {
        int qq = qt * 16 + 4 * hi + r;
        ob[(size_t)qq * 16 + lo] = oacc[r];
    }
    if (hi == 0) {
        float* mlb = mlbuf + (((size_t)bh * NSPLIT + split) * 64 + qt * 16 + lo) * 2;
        mlb[0] = m_run; mlb[1] = l_run;
    }
}

// ---------------- merge split partials -> gs[bh][49][16] ----------------
__global__ __launch_bounds__(256) void attn_combine(const float* __restrict__ osplit,
    const float* __restrict__ mlbuf, float* __restrict__ gs)
{
    int idx = blockIdx.x * 256 + threadIdx.x;   // over 128*49*16
    if (idx >= 128 * 49 * 16) return;
    int d = idx & 15;
    int pq = idx >> 4;
    int bh = pq / 49, q = pq % 49;
    float m[NSPLIT], l[NSPLIT];
    float M = -1e30f;
    #pragma unroll
    for (int s = 0; s < NSPLIT; s++) {
        const float* mlb = mlbuf + (((size_t)bh * NSPLIT + s) * 64 + q) * 2;
        m[s] = mlb[0]; l[s] = mlb[1];
        M = fmaxf(M, m[s]);
    }
    float L = 0.f, O = 0.f;
    #pragma unroll
    for (int s = 0; s < NSPLIT; s++) {
        float e = __expf(m[s] - M);
        L += l[s] * e;
        O += osplit[(((size_t)bh * NSPLIT + s) * 64 + q) * 16 + d] * e;
    }
    gs[(size_t)pq * 16 + d] = O / L;
}

// ---------------- bilinear 7->56 upsample into cat[:, 384:512] ----------------
__global__ void upsample_kernel(const float* __restrict__ gs, bf16* __restrict__ cat)
{
    int idx = blockIdx.x * blockDim.x + threadIdx.x;  // over N*128
    if (idx >= N_TOK * 128) return;
    int c = idx & 127;
    int pos = idx >> 7;
    int h = c >> 4, d = c & 15;
    int x = pos % 56;
    int y = (pos / 56) % 56;
    int b = pos / HWSZ;
    float sy = (y + 0.5f) * 0.125f - 0.5f;
    float sx = (x + 0.5f) * 0.125f - 0.5f;
    int y0f = (int)floorf(sy); float wy = sy - (float)y0f;
    int x0f = (int)floorf(sx); float wx = sx - (float)x0f;
    int y0 = max(0, min(6, y0f)), y1 = max(0, min(6, y0f + 1));
    int x0 = max(0, min(6, x0f)), x1 = max(0, min(6, x0f + 1));
    const float* g0 = gs + ((size_t)(b * 8 + h) * 49) * 16 + d;
    float v00 = g0[(y0 * 7 + x0) * 16], v01 = g0[(y0 * 7 + x1) * 16];
    float v10 = g0[(y1 * 7 + x0) * 16], v11 = g0[(y1 * 7 + x1) * 16];
    float v0 = v00 + (v01 - v00) * wx;
    float v1 = v10 + (v11 - v10) * wx;
    float v = v0 + (v1 - v0) * wy;
    cat[(size_t)pos * 512 + 384 + c] = __float2bfloat16(v);
}

extern "C" void kernel_launch(void* const* d_in, const int* in_sizes, int n_in,
                              void* d_out, int out_size, void* d_ws, size_t ws_size,
                              hipStream_t stream)
{
    const float* x      = (const float*)d_in[0];
    const float* x_e    = (const float*)d_in[1];
    const float* norm_w = (const float*)d_in[2];
    const float* norm_b = (const float*)d_in[3];
    const float* norme_w= (const float*)d_in[4];
    const float* norme_b= (const float*)d_in[5];
    const float* rr1_w  = (const float*)d_in[6];
    const float* rr1_b  = (const float*)d_in[7];
    const float* rr2_w  = (const float*)d_in[8];
    const float* rr2_b  = (const float*)d_in[9];
    const float* rr3_w  = (const float*)d_in[10];
    const float* rr3_b  = (const float*)d_in[11];
    const float* conv_w = (const float*)d_in[12];
    const float* conv_b = (const float*)d_in[13];
    const float* l1_w   = (const float*)d_in[14];
    const float* l1_b   = (const float*)d_in[15];
    const float* l2_w   = (const float*)d_in[16];
    const float* l2_b   = (const float*)d_in[17];
    const float* c1_w   = (const float*)d_in[18];
    const float* c1_b   = (const float*)d_in[19];
    const float* c2_w   = (const float*)d_in[20];
    const float* c2_b   = (const float*)d_in[21];
    const float* fc1_w  = (const float*)d_in[22];
    const float* fc2_w  = (const float*)d_in[23];
    const float* l3_w   = (const float*)d_in[24];
    const float* l3_b   = (const float*)d_in[25];
    const float* kv_w   = (const float*)d_in[26];
    const float* kv_b   = (const float*)d_in[27];
    const float* q_w    = (const float*)d_in[28];
    const float* q_b    = (const float*)d_in[29];
    const float* proj_w = (const float*)d_in[30];
    const float* proj_b = (const float*)d_in[31];
    const float* proje_w= (const float*)d_in[32];
    const float* proje_b= (const float*)d_in[33];

    // ---- workspace: fp32 smalls, bf16 transposed weights, bf16 slabs ----
    float* part   = (float*)d_ws;                 // 16*64*513
    float* attnc  = part   + (size_t)525312;      // 16*256
    float* gs     = attnc  + 4096;                // 16*8*49*16
    float* rxpool = gs     + 100352;              // 784*384
    float* qbuf   = rxpool + 301056;              // 784*128
    bf16* wt      = (bf16*)(qbuf + 100352);
    bf16* rr1_t  = wt;              // 256x256  } fused TRI slab [768][256]
    bf16* rr2_t  = rr1_t + 65536;   // 256x256  }
    bf16* kv_t   = rr2_t + 65536;   // 256x256  }
    bf16* rr3_t  = kv_t  + 65536;   // 256x256
    bf16* l1_t   = rr3_t + 65536;   // 128x256
    bf16* l2_t   = l1_t  + 32768;   // 128x128
    bf16* l3_t   = l2_t  + 16384;   // 128x256
    bf16* proj_t = l3_t  + 32768;   // 256x512
    bf16* proje_t= proj_t + 131072; // 128x512 (contiguous after proj_t -> fused [384][512])
    bf16* xn     = proje_t + 65536;
    bf16* xen    = xn   + (size_t)N_TOK * 256;
    bf16* bufC   = xen  + (size_t)N_TOK * 128;   // rr1 / codin
    bf16* bufD   = bufC + (size_t)N_TOK * 256;   // rr2pre / rgb / attn partials
    bf16* bufE   = bufD + (size_t)N_TOK * 256;   // conv out / co_di
    bf16* cat    = bufE + (size_t)N_TOK * 256;   // [N,512]
    bf16* kvbuf  = cat  + (size_t)N_TOK * 512;   // K [B*8][HWSZ][16] + V^T [B*8][16][HWSZ]
    size_t need = (size_t)((char*)(kvbuf + (size_t)N_TOK * 256) - (char*)d_ws);
    if (ws_size < need) return;

    bf16* kbuf = kvbuf;
    bf16* vbuf = kvbuf + (size_t)N_TOK * 128;

    // attn split partials live in bufD (free during phase 4): 8.26 MB
    float* osplit = (float*)bufD;                          // [128][NSPLIT][64][16]
    float* mlbuf  = osplit + (size_t)128 * NSPLIT * 64 * 16; // [128][NSPLIT][64][2]

    float* xout  = (float*)d_out;
    float* xeout = xout + (size_t)N_TOK * 256;

    const int nthr = 256;
    auto mgrid = [](int M, int N) { return dim3((M / 64) * (N / 128)); };

    // 0. weight prep (one launch)
    {
        WtrPack p;
        const float* srcs[9] = {rr1_w, rr2_w, kv_w, rr3_w, l1_w, l2_w, l3_w, proj_w, proje_w};
        bf16* dsts[9] = {rr1_t, rr2_t, kv_t, rr3_t, l1_t, l2_t, l3_t, proj_t, proje_t};
        int Ks[9] = {256, 256, 256, 256, 256, 128, 256, 512, 512};
        int Ns[9] = {256, 256, 256, 256, 128, 128, 128, 256, 128};
        int off = 0;
        for (int s = 0; s < 9; s++) {
            p.d[s] = {srcs[s], dsts[s], Ks[s], Ns[s], off};
            off += Ks[s] * Ns[s];
        }
        p.total = off;
        wtr_all<<<dim3((off + 255) / 256), dim3(256), 0, stream>>>(p);
    }

    // 1. LayerNorms
    ln_kernel<<<dim3(N_TOK / 4), dim3(nthr), 0, stream>>>(x, norm_w, norm_b, xn, N_TOK, 256);
    ln_kernel<<<dim3(N_TOK / 4), dim3(nthr), 0, stream>>>(x_e, norme_w, norme_b, xen, N_TOK, 128);

    // 2. rr1+rr2+kv TRI-FUSED (one xn pass, N=768): rr1->bufC, rr2->bufD, kv->kbuf/vbuf
    gemm_mfma<GF_TRI, bf16><<<mgrid(N_TOK, 768), dim3(nthr), 0, stream>>>(
        xn, 256, rr1_t, rr1_b, bufC, 256, N_TOK, 256, 768, nullptr, 0, kv_b, kbuf, vbuf,
        bufD, 256, rr2_b, 0);
    dwconv_reg<<<dim3(N_TOK / 32), dim3(nthr), 0, stream>>>(
        bufD, bufE, conv_w, conv_b, conv_w, conv_b, 256);
    gemm_mfma<GF_MUL, bf16><<<mgrid(N_TOK, 256), dim3(nthr), 0, stream>>>(
        bufE, 256, rr3_t, rr3_b, cat, 512, N_TOK, 256, 256, bufC, 256, nullptr, nullptr, nullptr,
        nullptr, 0, nullptr, 0);

    // 3. LocalAttentionRGBT -> cat[:, 256:384]
    gemm_mfma<0, bf16><<<mgrid(N_TOK, 128), dim3(nthr), 0, stream>>>(
        xn, 256, l1_t, l1_b, bufD, 128, N_TOK, 256, 128, nullptr, 0, nullptr, nullptr, nullptr,
        nullptr, 0, nullptr, 0);
    // l2 + rgbt fused: codin written directly into bufC (rgb read from bufD)
    gemm_mfma<GF_RGBT, bf16><<<mgrid(N_TOK, 128), dim3(nthr), 0, stream>>>(
        xen, 128, l2_t, l2_b, bufC, 256, N_TOK, 128, 128, bufD, 128, nullptr, nullptr, nullptr,
        nullptr, 0, nullptr, 0);
    dwconv_reg<<<dim3(N_TOK / 32), dim3(nthr), 0, stream>>>(
        bufC, bufE, c1_w, c1_b, c2_w, c2_b, 128);
    cosred_k<<<dim3(BATCH * 16), dim3(nthr), 0, stream>>>(bufE, part);
    mlp_kernel<<<dim3(BATCH), dim3(nthr), 0, stream>>>(part, fc1_w, fc2_w, attnc);
    gemm_mfma<GF_ASCALE, bf16><<<mgrid(N_TOK, 128), dim3(nthr), 0, stream>>>(
        bufE, 256, l3_t, l3_b, cat + 256, 512, N_TOK, 256, 128, nullptr, 0, attnc, nullptr, nullptr,
        nullptr, 0, nullptr, 0);

    // 4. global pooled attention -> cat[:, 384:512] (K/V already produced in phase 2)
    pool_kernel<<<dim3(BATCH * 49), dim3(384), 0, stream>>>(xn, xen, rxpool);
    gemm_k<<<dim3(((784 + 63) / 64) * 2), dim3(nthr), 0, stream>>>(
        rxpool, 384, q_w, q_b, qbuf, 128, 784, 384, 128);
    attn_mfma<<<dim3(128 * NSPLIT), dim3(nthr), 0, stream>>>(qbuf, kbuf, vbuf, osplit, mlbuf);
    attn_combine<<<dim3(392), dim3(nthr), 0, stream>>>(osplit, mlbuf, gs);
    upsample_kernel<<<dim3((N_TOK * 128) / nthr), dim3(nthr), 0, stream>>>(gs, cat);

    // 5. output projections (proj+proje FUSED: one cat-pass, N=384, fp32 out)
    gemm_mfma<GF_DUAL, float><<<mgrid(N_TOK, 384), dim3(nthr), 0, stream>>>(
        cat, 512, proj_t, proj_b, xout, 256, N_TOK, 512, 384, nullptr, 0, nullptr, nullptr, nullptr,
        xeout, 128, proje_b, 256);
}